// Round 9
// baseline (10232.273 us; speedup 1.0000x reference)
//
#include <hip/hip_runtime.h>
#include <hip/hip_bf16.h>
#include <cstddef>
#include <cstdint>

#define BB 64
#define HH 32
#define WW_ 32
#define CC 96
#define WS 8
#define NH 6
#define NL 4            // !! 4 layers (was wrongly 6 through R8)
#define ND 6            // 6 swin blocks per layer
#define T_TOK (BB*HH*WW_)      // 65536 tokens
#define TC ((size_t)T_TOK*CC)  // 6291456 floats

typedef long long ll;

// Harness-named kernel symbol (kept from the round-0 template).
__global__ void JNetSwinIR_41034117546277_kernel() {}

// ---------------------------------------------------------------- diagnostic fill
__global__ __launch_bounds__(256) void fill_kernel(float* p, float v, int n)
{
  const int idx = blockIdx.x * 256 + threadIdx.x;
  if (idx < n) p[idx] = v;
}

// ---------------------------------------------------------------- LayerNorm
// shift = -1 -> identity token mapping; shift >= 0 -> window partition of
// rolled image. Reads x at GLOBAL token (t0 + local), writes out at LOCAL.
__global__ __launch_bounds__(256) void ln_kernel(
    const float* __restrict__ x, const float* __restrict__ gamma,
    const float* __restrict__ beta, float* __restrict__ out, int shift, int t0)
{
  const int wave = threadIdx.x >> 6;
  const int lane = threadIdx.x & 63;
  const int lt = blockIdx.x * 4 + wave;
  const int ot = t0 + lt;
  int st;
  if (shift < 0) {
    st = ot;
  } else {
    const int widx = ot >> 6, n = ot & 63;
    const int b = widx >> 4, wimg = widx & 15;
    const int wh = wimg >> 2, ww = wimg & 3;
    const int r = wh * 8 + (n >> 3), c = ww * 8 + (n & 7);
    const int p = (r + shift) & 31, q = (c + shift) & 31;
    st = (b << 10) + (p << 5) + q;
  }
  const float* xp = x + (size_t)st * CC;
  const float v0 = xp[lane];
  const float v1 = (lane < 32) ? xp[64 + lane] : 0.f;
  float s = v0 + v1, s2 = v0 * v0 + v1 * v1;
  #pragma unroll
  for (int off = 32; off; off >>= 1) {
    s  += __shfl_xor(s,  off);
    s2 += __shfl_xor(s2, off);
  }
  const float mean = s * (1.f / 96.f);
  const float var  = s2 * (1.f / 96.f) - mean * mean;
  const float inv  = rsqrtf(var + 1e-5f);
  float* op = out + (size_t)lt * CC;
  op[lane] = (v0 - mean) * inv * gamma[lane] + beta[lane];
  if (lane < 32)
    op[64 + lane] = (v1 - mean) * inv * gamma[64 + lane] + beta[64 + lane];
}

// ---------------------------------------------------------------- GEMM
// C[M,N] = A[M,K] @ B[K,N] (+bias) (opt GELU).  M%64==0, N%32==0, K%32==0.
__global__ __launch_bounds__(128) void gemm_kernel(
    const float* __restrict__ A, const float* __restrict__ Bw,
    const float* __restrict__ bias, float* __restrict__ C,
    int N, int K, int do_gelu)
{
  __shared__ float As[32][68];   // [k][m], padded
  __shared__ float Bs[32][36];   // [k][n], padded
  const int tid = threadIdx.x;
  const int m0 = blockIdx.x * 64;
  const int n0 = blockIdx.y * 32;
  const int ty = tid >> 3, tx = tid & 7;
  float acc[4][4] = {};
  for (int k0 = 0; k0 < K; k0 += 32) {
    {
      const int row = tid >> 1;
      const int kb = (tid & 1) * 16;
      const float* src = A + (size_t)(m0 + row) * K + k0 + kb;
      #pragma unroll
      for (int i = 0; i < 4; ++i) {
        const float4 v = *(const float4*)(src + i * 4);
        As[kb + i * 4 + 0][row] = v.x;
        As[kb + i * 4 + 1][row] = v.y;
        As[kb + i * 4 + 2][row] = v.z;
        As[kb + i * 4 + 3][row] = v.w;
      }
    }
    {
      #pragma unroll
      for (int i = 0; i < 2; ++i) {
        const int f = tid * 2 + i;
        const int krow = f >> 3, c4 = (f & 7) * 4;
        *(float4*)&Bs[krow][c4] =
            *(const float4*)(Bw + (size_t)(k0 + krow) * N + n0 + c4);
      }
    }
    __syncthreads();
    #pragma unroll
    for (int kk = 0; kk < 32; ++kk) {
      const float4 av = *(const float4*)&As[kk][ty * 4];
      const float4 bv = *(const float4*)&Bs[kk][tx * 4];
      const float a[4] = {av.x, av.y, av.z, av.w};
      const float b[4] = {bv.x, bv.y, bv.z, bv.w};
      #pragma unroll
      for (int i = 0; i < 4; ++i)
        #pragma unroll
        for (int j = 0; j < 4; ++j)
          acc[i][j] = fmaf(a[i], b[j], acc[i][j]);
    }
    __syncthreads();
  }
  #pragma unroll
  for (int i = 0; i < 4; ++i) {
    const int m = m0 + ty * 4 + i;
    float vv[4];
    #pragma unroll
    for (int j = 0; j < 4; ++j) {
      const int n = n0 + tx * 4 + j;
      float v = acc[i][j];
      if (bias) v += bias[n];
      if (do_gelu) v = 0.5f * v * (1.f + erff(v * 0.70710678118f));
      vv[j] = v;
    }
    float4 o; o.x = vv[0]; o.y = vv[1]; o.z = vv[2]; o.w = vv[3];
    *(float4*)&C[(size_t)m * N + n0 + tx * 4] = o;
  }
}

// ---------------------------------------------------------------- Attention
// one wave per (window, head). qkv: [Tc,288]. widx local (whole batches/chunk).
__global__ __launch_bounds__(64) void attn_kernel(
    const float* __restrict__ qkv, const float* __restrict__ rpb_ld,
    float* __restrict__ out, int shift)
{
  const int head = blockIdx.x % NH;
  const int widx = blockIdx.x / NH;
  const int lane = threadIdx.x;
  __shared__ float ks[64][20];
  __shared__ float vs[64][20];
  __shared__ float bias_s[225];
  __shared__ int reg_s[64];
  const float* base = qkv + (size_t)(widx * 64 + lane) * 288 + head * 16;
  float q[16];
  #pragma unroll
  for (int c = 0; c < 16; c += 4) {
    const float4 qv = *(const float4*)(base + c);
    q[c] = qv.x; q[c + 1] = qv.y; q[c + 2] = qv.z; q[c + 3] = qv.w;
    *(float4*)&ks[lane][c] = *(const float4*)(base + 96 + c);
    *(float4*)&vs[lane][c] = *(const float4*)(base + 192 + c);
  }
  for (int i = lane; i < 225; i += 64) bias_s[i] = rpb_ld[i * NH + head];
  {
    const int wimg = widx & 15;
    const int h = (wimg >> 2) * 8 + (lane >> 3);
    const int w = (wimg & 3) * 8 + (lane & 7);
    reg_s[lane] = 3 * (h < 24 ? 0 : (h < 28 ? 1 : 2)) +
                      (w < 24 ? 0 : (w < 28 ? 1 : 2));
  }
  __syncthreads();
  const int ih = lane >> 3, iw = lane & 7;
  const int myreg = reg_s[lane];
  float s[64];
  #pragma unroll
  for (int j = 0; j < 64; ++j) {
    const float4 k0 = *(const float4*)&ks[j][0];
    const float4 k1 = *(const float4*)&ks[j][4];
    const float4 k2 = *(const float4*)&ks[j][8];
    const float4 k3 = *(const float4*)&ks[j][12];
    float acc = 0.f;
    acc = fmaf(q[0],  k0.x, acc); acc = fmaf(q[1],  k0.y, acc);
    acc = fmaf(q[2],  k0.z, acc); acc = fmaf(q[3],  k0.w, acc);
    acc = fmaf(q[4],  k1.x, acc); acc = fmaf(q[5],  k1.y, acc);
    acc = fmaf(q[6],  k1.z, acc); acc = fmaf(q[7],  k1.w, acc);
    acc = fmaf(q[8],  k2.x, acc); acc = fmaf(q[9],  k2.y, acc);
    acc = fmaf(q[10], k2.z, acc); acc = fmaf(q[11], k2.w, acc);
    acc = fmaf(q[12], k3.x, acc); acc = fmaf(q[13], k3.y, acc);
    acc = fmaf(q[14], k3.z, acc); acc = fmaf(q[15], k3.w, acc);
    const int idx = (ih - (j >> 3) + 7) * 15 + (iw - (j & 7) + 7);
    acc = acc * 0.25f + bias_s[idx];
    if (shift && reg_s[j] != myreg) acc -= 100.f;
    s[j] = acc;
  }
  float m = s[0];
  #pragma unroll
  for (int j = 1; j < 64; ++j) m = fmaxf(m, s[j]);
  float sum = 0.f;
  #pragma unroll
  for (int j = 0; j < 64; ++j) { const float p = __expf(s[j] - m); s[j] = p; sum += p; }
  const float inv = 1.f / sum;
  float o[16] = {};
  #pragma unroll
  for (int j = 0; j < 64; ++j) {
    const float p = s[j] * inv;
    const float4 v0 = *(const float4*)&vs[j][0];
    const float4 v1 = *(const float4*)&vs[j][4];
    const float4 v2 = *(const float4*)&vs[j][8];
    const float4 v3 = *(const float4*)&vs[j][12];
    o[0]  = fmaf(p, v0.x, o[0]);  o[1]  = fmaf(p, v0.y, o[1]);
    o[2]  = fmaf(p, v0.z, o[2]);  o[3]  = fmaf(p, v0.w, o[3]);
    o[4]  = fmaf(p, v1.x, o[4]);  o[5]  = fmaf(p, v1.y, o[5]);
    o[6]  = fmaf(p, v1.z, o[6]);  o[7]  = fmaf(p, v1.w, o[7]);
    o[8]  = fmaf(p, v2.x, o[8]);  o[9]  = fmaf(p, v2.y, o[9]);
    o[10] = fmaf(p, v2.z, o[10]); o[11] = fmaf(p, v2.w, o[11]);
    o[12] = fmaf(p, v3.x, o[12]); o[13] = fmaf(p, v3.y, o[13]);
    o[14] = fmaf(p, v3.z, o[14]); o[15] = fmaf(p, v3.w, o[15]);
  }
  float* op = out + (size_t)(widx * 64 + lane) * CC + head * 16;
  #pragma unroll
  for (int c = 0; c < 16; c += 4) {
    float4 v; v.x = o[c]; v.y = o[c + 1]; v.z = o[c + 2]; v.w = o[c + 3];
    *(float4*)(op + c) = v;
  }
}

// ---------------------------------------------------------------- add-backs
__global__ __launch_bounds__(256) void addback_kernel(
    float* __restrict__ x, const float* __restrict__ pout, int shift)
{
  const int idx = blockIdx.x * 256 + threadIdx.x;
  const int c = idx % CC;
  const int t = idx / CC;
  const int q = t & 31, p = (t >> 5) & 31, b = t >> 10;
  const int r  = (p + 32 - shift) & 31;
  const int cc = (q + 32 - shift) & 31;
  const int widx = b * 16 + (r >> 3) * 4 + (cc >> 3);
  const int n = (r & 7) * 8 + (cc & 7);
  x[idx] += pout[(size_t)(widx * 64 + n) * CC + c];
}

__global__ __launch_bounds__(256) void add_bias_kernel(
    float* __restrict__ x, const float* __restrict__ t, const float* __restrict__ bias)
{
  const int idx = blockIdx.x * 256 + threadIdx.x;
  x[idx] += t[idx] + bias[idx % CC];
}

__global__ __launch_bounds__(256) void copy_kernel(
    float* __restrict__ dst, const float* __restrict__ src)
{
  const int idx = blockIdx.x * 256 + threadIdx.x;
  dst[idx] = src[idx];
}

// ---------------------------------------------------------------- conv 3x3 96->96
// resid/out may alias (same-index read->write) — no __restrict__.
__global__ __launch_bounds__(384) void conv96_kernel(
    const float* __restrict__ x, const float* __restrict__ wgt,
    const float* __restrict__ bias, const float* resid, float* out)
{
  const int blk = blockIdx.x;
  const int b = blk >> 4, th = (blk >> 2) & 3, tw = blk & 3;
  const int h0 = th * 8, w0 = tw * 8;
  __shared__ float patch[100][96];
  for (int idx = threadIdx.x; idx < 9600; idx += 384) {
    const int ic = idx % 96, pp = idx / 96;
    const int ph = pp / 10, pw = pp % 10;
    const int hh = h0 + ph - 1, ww = w0 + pw - 1;
    float v = 0.f;
    if ((unsigned)hh < 32u && (unsigned)ww < 32u)
      v = x[(((size_t)b * 32 + hh) * 32 + ww) * 96 + ic];
    patch[pp][ic] = v;
  }
  __syncthreads();
  const int oc = threadIdx.x % 96;
  const int pg = threadIdx.x / 96;
  float acc[16];
  #pragma unroll
  for (int i = 0; i < 16; ++i) acc[i] = bias[oc];
  for (int kh = 0; kh < 3; ++kh)
    for (int kw = 0; kw < 3; ++kw) {
      const float* wcol = wgt + (size_t)((kh * 3 + kw) * 96) * 96 + oc;
      #pragma unroll 4
      for (int ic = 0; ic < 96; ++ic) {
        const float wv = wcol[(size_t)ic * 96];
        #pragma unroll
        for (int i = 0; i < 16; ++i) {
          const int pos = pg * 16 + i;
          const int h = pos >> 3, w = pos & 7;
          acc[i] = fmaf(patch[(h + kh) * 10 + (w + kw)][ic], wv, acc[i]);
        }
      }
    }
  #pragma unroll
  for (int i = 0; i < 16; ++i) {
    const int pos = pg * 16 + i;
    const int h = pos >> 3, w = pos & 7;
    const size_t t = (((size_t)b * 32 + h0 + h) * 32 + (w0 + w));
    const float rr = resid ? resid[t * 96 + oc] : 0.f;
    out[t * 96 + oc] = acc[i] + rr;
  }
}

// ---------------------------------------------------------------- conv stem 4->96
__global__ __launch_bounds__(256) void conv_first_kernel(
    const float* __restrict__ es, const float* __restrict__ jp,
    const float* __restrict__ wgt, const float* __restrict__ bias,
    float* __restrict__ xf)
{
  const int idx = blockIdx.x * 256 + threadIdx.x;
  const int oc = idx % 96;
  const int pos = idx / 96;
  const int w = pos % 32, hp = (pos / 32) % 32, b = pos / 1024;
  float acc = bias[oc];
  for (int kh = 0; kh < 3; ++kh) {
    const int hh = hp + kh - 1;
    if ((unsigned)hh >= 32u) continue;
    for (int kw = 0; kw < 3; ++kw) {
      const int ww = w + kw - 1;
      if ((unsigned)ww >= 32u) continue;
      const size_t sp = ((size_t)b * 2 * 32 + hh) * 32 + ww;
      const float i0 = es[sp];
      const float i1 = es[sp + 1024];
      const float i2 = jp[sp];
      const float i3 = jp[sp + 1024];
      const float* wr = wgt + (size_t)((kh * 3 + kw) * 4) * 96 + oc;
      acc = fmaf(i0, wr[0], acc);
      acc = fmaf(i1, wr[96], acc);
      acc = fmaf(i2, wr[192], acc);
      acc = fmaf(i3, wr[288], acc);
    }
  }
  xf[idx] = acc;
}

// ---------------------------------------------------------------- conv tail 96->2
__global__ __launch_bounds__(256) void conv_last_kernel(
    const float* __restrict__ res, const float* __restrict__ wgt,
    const float* __restrict__ bias, float* __restrict__ out)
{
  const int idx = blockIdx.x * 256 + threadIdx.x;
  const int oc = idx % 2;
  const int pos = idx / 2;
  const int w = pos % 32, hp = (pos / 32) % 32, b = pos / 1024;
  float acc = bias[oc];
  for (int kh = 0; kh < 3; ++kh) {
    const int hh = hp + kh - 1;
    if ((unsigned)hh >= 32u) continue;
    for (int kw = 0; kw < 3; ++kw) {
      const int ww = w + kw - 1;
      if ((unsigned)ww >= 32u) continue;
      const float* pr = res + (((size_t)b * 32 + hh) * 32 + ww) * 96;
      const float* wr = wgt + (size_t)((kh * 3 + kw) * 96) * 2 + oc;
      #pragma unroll 8
      for (int ic = 0; ic < 96; ++ic)
        acc = fmaf(pr[ic], wr[ic * 2], acc);
    }
  }
  out[(((size_t)b * 2 + oc) * 32 + hp) * 32 + w] = acc;
}

// ---------------------------------------------------------------- host
extern "C" void kernel_launch(void* const* d_in, const int* in_sizes, int n_in,
                              void* d_out, int out_size, void* d_ws, size_t ws_size,
                              hipStream_t stream)
{
  const int fill_grid = (out_size + 255) / 256;

  // GUARD 1: input count
  if (n_in != 27) {
    fill_kernel<<<fill_grid, 256, 0, stream>>>((float*)d_out, 200.0f + (float)n_in, out_size);
    return;
  }
  // GUARD 2: per-input sizes (NL=4, ND=6)
  static const int expected_sizes[27] = {
    131072, 131072,        // es, jp
    3456, 96,              // conv_first w,b
    96, 96,                // pe_norm s,b
    2304, 2304,            // n1 s,b           (4*6*96)
    663552, 6912,          // qkv w,b          (4*6*96*288 / 4*6*288)
    221184, 2304,          // proj w,b         (4*6*96*96)
    32400,                 // rpb              (4*6*225*6)
    2304, 2304,            // n2 s,b
    884736, 9216,          // fc1 w,b          (4*6*96*384 / 4*6*384)
    884736, 2304,          // fc2 w,b
    331776, 384,           // rstb conv w,b    (4*9*96*96 / 4*96)
    96, 96,                // normf s,b
    82944, 96,             // body w,b
    1728, 2                // last w,b
  };
  for (int i = 0; i < 27; ++i) {
    if (in_sizes[i] != expected_sizes[i]) {
      fill_kernel<<<fill_grid, 256, 0, stream>>>((float*)d_out, 300.0f + (float)i, out_size);
      return;
    }
  }
  // GUARD 3: output size
  if (out_size != 131072) {
    fill_kernel<<<fill_grid, 256, 0, stream>>>((float*)d_out, 400.0f, out_size);
    return;
  }
  // GUARD 4: workspace floor
  const uintptr_t raw = (uintptr_t)d_ws;
  const uintptr_t alignedp = (raw + 255) & ~(uintptr_t)255;
  const size_t ws_avail_bytes = (ws_size > (alignedp - raw)) ? ws_size - (alignedp - raw) : 0;
  const size_t avail = ws_avail_bytes / 4;
  const size_t floor_need = 2 * TC + (size_t)1024 * 480;
  if (avail < floor_need) {
    fill_kernel<<<fill_grid, 256, 0, stream>>>((float*)d_out,
        100.0f + (float)(ws_size >> 20), out_size);
    return;
  }

  const float* es      = (const float*)d_in[0];
  const float* jp      = (const float*)d_in[1];
  const float* cf_w    = (const float*)d_in[2];
  const float* cf_b    = (const float*)d_in[3];
  const float* pe_s    = (const float*)d_in[4];
  const float* pe_b    = (const float*)d_in[5];
  const float* n1_s    = (const float*)d_in[6];
  const float* n1_b    = (const float*)d_in[7];
  const float* qkv_w   = (const float*)d_in[8];
  const float* qkv_b   = (const float*)d_in[9];
  const float* proj_w  = (const float*)d_in[10];
  const float* proj_b  = (const float*)d_in[11];
  const float* rpb     = (const float*)d_in[12];
  const float* n2_s    = (const float*)d_in[13];
  const float* n2_b    = (const float*)d_in[14];
  const float* fc1_w   = (const float*)d_in[15];
  const float* fc1_b   = (const float*)d_in[16];
  const float* fc2_w   = (const float*)d_in[17];
  const float* fc2_b   = (const float*)d_in[18];
  const float* rstb_w  = (const float*)d_in[19];
  const float* rstb_b  = (const float*)d_in[20];
  const float* nf_s    = (const float*)d_in[21];
  const float* nf_b    = (const float*)d_in[22];
  const float* body_w  = (const float*)d_in[23];
  const float* body_b  = (const float*)d_in[24];
  const float* last_w  = (const float*)d_in[25];
  const float* last_b  = (const float*)d_in[26];

  float* ws = (float*)alignedp;
  float* x  = ws;                  // persistent feature [T,96]
  float* r  = ws + TC;             // layer residual (becomes next x in-place)
  float* sm = ws + 2 * TC;         // chunk small [Tc,96]

  int Tc = T_TOK;
  while (Tc > 1024 && 2 * TC + (size_t)Tc * 480 > avail) Tc >>= 1;
  const int cn = T_TOK / Tc;
  float* big = sm + (size_t)Tc * CC;   // chunk big [Tc,384]

  const int grid_tc = (int)(TC / 256);
  const int grid_ch = (Tc * CC) / 256;
  const int grid_lf = T_TOK / 4;
  const int grid_lc = Tc / 4;

  // stem: x = LN_pe(conv_first(inputs))
  conv_first_kernel<<<grid_tc, 256, 0, stream>>>(es, jp, cf_w, cf_b, x);
  ln_kernel<<<grid_lf, 256, 0, stream>>>(x, pe_s, pe_b, r, -1, 0);
  copy_kernel<<<grid_tc, 256, 0, stream>>>(x, r);

  float* xb = x;
  float* rb = r;
  for (int l = 0; l < NL; ++l) {
    copy_kernel<<<grid_tc, 256, 0, stream>>>(rb, xb);   // save residual
    for (int d = 0; d < ND; ++d) {
      const int ld = l * ND + d;
      const int shift = (d & 1) ? 4 : 0;
      for (int c = 0; c < cn; ++c) {
        const size_t off = (size_t)c * Tc * CC;
        const int t0 = c * Tc;
        // LN1 (+roll+window) -> sm
        ln_kernel<<<grid_lc, 256, 0, stream>>>(xb, n1_s + ld * CC, n1_b + ld * CC,
                                               sm, shift, t0);
        // QKV -> big [Tc,288]
        { dim3 g(Tc / 64, 288 / 32);
          gemm_kernel<<<g, 128, 0, stream>>>(sm, qkv_w + (size_t)ld * CC * 288,
              qkv_b + (size_t)ld * 288, big, 288, CC, 0); }
        // attention -> sm (window order)
        attn_kernel<<<(Tc / 64) * NH, 64, 0, stream>>>(
            big, rpb + (size_t)ld * 225 * NH, sm, shift);
        // proj -> big[0 : Tc*96]
        { dim3 g(Tc / 64, CC / 32);
          gemm_kernel<<<g, 128, 0, stream>>>(sm, proj_w + (size_t)ld * CC * CC,
              proj_b + (size_t)ld * CC, big, CC, CC, 0); }
        // x_chunk += window_reverse(roll_back(proj))
        addback_kernel<<<grid_ch, 256, 0, stream>>>(xb + off, big, shift);
        // LN2 -> sm
        ln_kernel<<<grid_lc, 256, 0, stream>>>(xb, n2_s + ld * CC, n2_b + ld * CC,
                                               sm, -1, t0);
        // fc1 + gelu -> big [Tc,384]
        { dim3 g(Tc / 64, 384 / 32);
          gemm_kernel<<<g, 128, 0, stream>>>(sm, fc1_w + (size_t)ld * CC * 384,
              fc1_b + (size_t)ld * 384, big, 384, CC, 1); }
        // fc2 -> sm
        { dim3 g(Tc / 64, CC / 32);
          gemm_kernel<<<g, 128, 0, stream>>>(big, fc2_w + (size_t)ld * 384 * CC,
              nullptr, sm, CC, 384, 0); }
        // x_chunk += fc2 + bias
        add_bias_kernel<<<grid_ch, 256, 0, stream>>>(xb + off, sm, fc2_b + (size_t)ld * CC);
      }
    }
    // rb = conv(xb) + rb (in-place resid add), then rb becomes x
    conv96_kernel<<<1024, 384, 0, stream>>>(xb, rstb_w + (size_t)l * 9 * CC * CC,
                                            rstb_b + (size_t)l * CC, rb, rb);
    float* sw = xb; xb = rb; rb = sw;
  }
  // tail: rb = LN_f(xb); xb = conv_first (xf recompute); xb = conv_body(rb)+xb
  ln_kernel<<<grid_lf, 256, 0, stream>>>(xb, nf_s, nf_b, rb, -1, 0);
  conv_first_kernel<<<grid_tc, 256, 0, stream>>>(es, jp, cf_w, cf_b, xb);
  conv96_kernel<<<1024, 384, 0, stream>>>(rb, body_w, body_b, xb, xb);
  conv_last_kernel<<<(BB * 32 * 32 * 2) / 256, 256, 0, stream>>>(xb, last_w, last_b, (float*)d_out);
}

// Round 10
// 6984.136 us; speedup vs baseline: 1.4651x; 1.4651x over previous
//
#include <hip/hip_runtime.h>
#include <hip/hip_bf16.h>
#include <cstddef>
#include <cstdint>

#define BB 64
#define HH 32
#define WW_ 32
#define CC 96
#define WS 8
#define NH 6
#define NL 4
#define ND 6
#define T_TOK (BB*HH*WW_)      // 65536 tokens
#define TC ((size_t)T_TOK*CC)  // 6291456 floats

typedef long long ll;
typedef __attribute__((ext_vector_type(8))) short short8;
typedef __attribute__((ext_vector_type(4))) float f32x4;

// Harness-named kernel symbol.
__global__ void JNetSwinIR_41034117546277_kernel() {}

__device__ __forceinline__ unsigned short f2bf(float f) {
  unsigned u = __float_as_uint(f);
  unsigned r = (u + 0x7FFF + ((u >> 16) & 1)) >> 16;
  return (unsigned short)r;
}
__device__ __forceinline__ float bf2f(unsigned short h) {
  return __uint_as_float(((unsigned)h) << 16);
}

// ---------------------------------------------------------------- diagnostic fill
__global__ __launch_bounds__(256) void fill_kernel(float* p, float v, int n)
{
  const int idx = blockIdx.x * 256 + threadIdx.x;
  if (idx < n) p[idx] = v;
}

// ---------------------------------------------------------------- weight fp32->bf16 transpose
// W [24][K][N] fp32 -> Wt [24][N][K] bf16
__global__ __launch_bounds__(256) void wconv_kernel(
    const float* __restrict__ W, unsigned short* __restrict__ Wt, int K, int N)
{
  const int ld = blockIdx.y;
  const int idx = blockIdx.x * 256 + threadIdx.x;
  if (idx >= K * N) return;
  const int k = idx / N, n = idx % N;
  Wt[(size_t)ld * K * N + (size_t)n * K + k] = f2bf(W[(size_t)ld * K * N + idx]);
}

// ---------------------------------------------------------------- LayerNorm (bf16 out)
// shift=-1 identity; shift>=0 roll+window-partition. Reads global token t0+lt.
__global__ __launch_bounds__(256) void ln_kernel(
    const float* __restrict__ x, const float* __restrict__ gamma,
    const float* __restrict__ beta, unsigned short* __restrict__ out,
    int shift, int t0)
{
  const int wave = threadIdx.x >> 6;
  const int lane = threadIdx.x & 63;
  const int lt = blockIdx.x * 4 + wave;
  const int ot = t0 + lt;
  int st;
  if (shift < 0) {
    st = ot;
  } else {
    const int widx = ot >> 6, n = ot & 63;
    const int b = widx >> 4, wimg = widx & 15;
    const int wh = wimg >> 2, ww = wimg & 3;
    const int r = wh * 8 + (n >> 3), c = ww * 8 + (n & 7);
    const int p = (r + shift) & 31, q = (c + shift) & 31;
    st = (b << 10) + (p << 5) + q;
  }
  const float* xp = x + (size_t)st * CC;
  const float v0 = xp[lane];
  const float v1 = (lane < 32) ? xp[64 + lane] : 0.f;
  float s = v0 + v1, s2 = v0 * v0 + v1 * v1;
  #pragma unroll
  for (int off = 32; off; off >>= 1) {
    s  += __shfl_xor(s,  off);
    s2 += __shfl_xor(s2, off);
  }
  const float mean = s * (1.f / 96.f);
  const float var  = s2 * (1.f / 96.f) - mean * mean;
  const float inv  = rsqrtf(var + 1e-5f);
  unsigned short* op = out + (size_t)lt * CC;
  op[lane] = f2bf((v0 - mean) * inv * gamma[lane] + beta[lane]);
  if (lane < 32)
    op[64 + lane] = f2bf((v1 - mean) * inv * gamma[64 + lane] + beta[64 + lane]);
}

// ---------------------------------------------------------------- MFMA GEMM
// C[M,N] = A[M,K](bf16) @ Wt[N,K](bf16)^T (+bias) (opt GELU).
// grid (M/64, N/32), 256 thr = 4 waves; wave w: rows m0+w*16, cols n0..n0+31.
template<int OUT_BF16, int GELU>
__global__ __launch_bounds__(256) void mgemm(
    const unsigned short* __restrict__ A, const unsigned short* __restrict__ Bt,
    const float* __restrict__ bias, float* __restrict__ Cf,
    unsigned short* __restrict__ Cb, int N, int K)
{
  const int wv   = threadIdx.x >> 6;
  const int lane = threadIdx.x & 63;
  const int m0 = blockIdx.x * 64 + wv * 16;
  const int n0 = blockIdx.y * 32;
  const int row = lane & 15;
  const int ko  = (lane >> 4) * 8;
  f32x4 acc0 = {0.f, 0.f, 0.f, 0.f};
  f32x4 acc1 = {0.f, 0.f, 0.f, 0.f};
  const unsigned short* ap  = A  + (size_t)(m0 + row) * K + ko;
  const unsigned short* bp0 = Bt + (size_t)(n0 + row) * K + ko;
  const unsigned short* bp1 = Bt + (size_t)(n0 + 16 + row) * K + ko;
  for (int k0 = 0; k0 < K; k0 += 32) {
    const short8 af  = *(const short8*)(ap + k0);
    const short8 bf0 = *(const short8*)(bp0 + k0);
    const short8 bf1 = *(const short8*)(bp1 + k0);
    acc0 = __builtin_amdgcn_mfma_f32_16x16x32_bf16(af, bf0, acc0, 0, 0, 0);
    acc1 = __builtin_amdgcn_mfma_f32_16x16x32_bf16(af, bf1, acc1, 0, 0, 0);
  }
  // C/D: col = lane&15, row = (lane>>4)*4 + reg
  const int cc  = lane & 15;
  const int cr0 = (lane >> 4) * 4;
  const float b0 = bias ? bias[n0 + cc] : 0.f;
  const float b1 = bias ? bias[n0 + 16 + cc] : 0.f;
  #pragma unroll
  for (int r = 0; r < 4; ++r) {
    const int m = m0 + cr0 + r;
    float v0 = acc0[r] + b0;
    float v1 = acc1[r] + b1;
    if (GELU) {
      v0 = 0.5f * v0 * (1.f + erff(v0 * 0.70710678118f));
      v1 = 0.5f * v1 * (1.f + erff(v1 * 0.70710678118f));
    }
    if (OUT_BF16) {
      Cb[(size_t)m * N + n0 + cc]      = f2bf(v0);
      Cb[(size_t)m * N + n0 + 16 + cc] = f2bf(v1);
    } else {
      Cf[(size_t)m * N + n0 + cc]      = v0;
      Cf[(size_t)m * N + n0 + 16 + cc] = v1;
    }
  }
}

// ---------------------------------------------------------------- Attention (bf16 in/out)
__global__ __launch_bounds__(64) void attn_kernel(
    const unsigned short* __restrict__ qkv, const float* __restrict__ rpb_ld,
    unsigned short* __restrict__ out, int shift)
{
  const int head = blockIdx.x % NH;
  const int widx = blockIdx.x / NH;
  const int lane = threadIdx.x;
  __shared__ float ks[64][20];
  __shared__ float vs[64][20];
  __shared__ float bias_s[225];
  __shared__ int reg_s[64];
  const unsigned short* base = qkv + (size_t)(widx * 64 + lane) * 288 + head * 16;
  float q[16];
  {
    const short8 q0 = *(const short8*)(base);
    const short8 q1 = *(const short8*)(base + 8);
    const short8 k0 = *(const short8*)(base + 96);
    const short8 k1 = *(const short8*)(base + 104);
    const short8 v0 = *(const short8*)(base + 192);
    const short8 v1 = *(const short8*)(base + 200);
    #pragma unroll
    for (int i = 0; i < 8; ++i) {
      q[i]     = bf2f((unsigned short)q0[i]);
      q[8 + i] = bf2f((unsigned short)q1[i]);
      ks[lane][i]     = bf2f((unsigned short)k0[i]);
      ks[lane][8 + i] = bf2f((unsigned short)k1[i]);
      vs[lane][i]     = bf2f((unsigned short)v0[i]);
      vs[lane][8 + i] = bf2f((unsigned short)v1[i]);
    }
  }
  for (int i = lane; i < 225; i += 64) bias_s[i] = rpb_ld[i * NH + head];
  {
    const int wimg = widx & 15;
    const int h = (wimg >> 2) * 8 + (lane >> 3);
    const int w = (wimg & 3) * 8 + (lane & 7);
    reg_s[lane] = 3 * (h < 24 ? 0 : (h < 28 ? 1 : 2)) +
                      (w < 24 ? 0 : (w < 28 ? 1 : 2));
  }
  __syncthreads();
  const int ih = lane >> 3, iw = lane & 7;
  const int myreg = reg_s[lane];
  float s[64];
  #pragma unroll
  for (int j = 0; j < 64; ++j) {
    const float4 k0 = *(const float4*)&ks[j][0];
    const float4 k1 = *(const float4*)&ks[j][4];
    const float4 k2 = *(const float4*)&ks[j][8];
    const float4 k3 = *(const float4*)&ks[j][12];
    float acc = 0.f;
    acc = fmaf(q[0],  k0.x, acc); acc = fmaf(q[1],  k0.y, acc);
    acc = fmaf(q[2],  k0.z, acc); acc = fmaf(q[3],  k0.w, acc);
    acc = fmaf(q[4],  k1.x, acc); acc = fmaf(q[5],  k1.y, acc);
    acc = fmaf(q[6],  k1.z, acc); acc = fmaf(q[7],  k1.w, acc);
    acc = fmaf(q[8],  k2.x, acc); acc = fmaf(q[9],  k2.y, acc);
    acc = fmaf(q[10], k2.z, acc); acc = fmaf(q[11], k2.w, acc);
    acc = fmaf(q[12], k3.x, acc); acc = fmaf(q[13], k3.y, acc);
    acc = fmaf(q[14], k3.z, acc); acc = fmaf(q[15], k3.w, acc);
    const int idx = (ih - (j >> 3) + 7) * 15 + (iw - (j & 7) + 7);
    acc = acc * 0.25f + bias_s[idx];
    if (shift && reg_s[j] != myreg) acc -= 100.f;
    s[j] = acc;
  }
  float m = s[0];
  #pragma unroll
  for (int j = 1; j < 64; ++j) m = fmaxf(m, s[j]);
  float sum = 0.f;
  #pragma unroll
  for (int j = 0; j < 64; ++j) { const float p = __expf(s[j] - m); s[j] = p; sum += p; }
  const float inv = 1.f / sum;
  float o[16] = {};
  #pragma unroll
  for (int j = 0; j < 64; ++j) {
    const float p = s[j] * inv;
    const float4 v0 = *(const float4*)&vs[j][0];
    const float4 v1 = *(const float4*)&vs[j][4];
    const float4 v2 = *(const float4*)&vs[j][8];
    const float4 v3 = *(const float4*)&vs[j][12];
    o[0]  = fmaf(p, v0.x, o[0]);  o[1]  = fmaf(p, v0.y, o[1]);
    o[2]  = fmaf(p, v0.z, o[2]);  o[3]  = fmaf(p, v0.w, o[3]);
    o[4]  = fmaf(p, v1.x, o[4]);  o[5]  = fmaf(p, v1.y, o[5]);
    o[6]  = fmaf(p, v1.z, o[6]);  o[7]  = fmaf(p, v1.w, o[7]);
    o[8]  = fmaf(p, v2.x, o[8]);  o[9]  = fmaf(p, v2.y, o[9]);
    o[10] = fmaf(p, v2.z, o[10]); o[11] = fmaf(p, v2.w, o[11]);
    o[12] = fmaf(p, v3.x, o[12]); o[13] = fmaf(p, v3.y, o[13]);
    o[14] = fmaf(p, v3.z, o[14]); o[15] = fmaf(p, v3.w, o[15]);
  }
  unsigned short* op = out + (size_t)(widx * 64 + lane) * CC + head * 16;
  short8 o0, o1;
  #pragma unroll
  for (int i = 0; i < 8; ++i) {
    o0[i] = (short)f2bf(o[i]);
    o1[i] = (short)f2bf(o[8 + i]);
  }
  *(short8*)(op) = o0;
  *(short8*)(op + 8) = o1;
}

// ---------------------------------------------------------------- add-backs
__global__ __launch_bounds__(256) void addback_kernel(
    float* __restrict__ x, const float* __restrict__ pout, int shift)
{
  const int idx = blockIdx.x * 256 + threadIdx.x;
  const int c = idx % CC;
  const int t = idx / CC;
  const int q = t & 31, p = (t >> 5) & 31, b = t >> 10;
  const int r  = (p + 32 - shift) & 31;
  const int cc = (q + 32 - shift) & 31;
  const int widx = b * 16 + (r >> 3) * 4 + (cc >> 3);
  const int n = (r & 7) * 8 + (cc & 7);
  x[idx] += pout[(size_t)(widx * 64 + n) * CC + c];
}

__global__ __launch_bounds__(256) void add_kernel(
    float* __restrict__ x, const float* __restrict__ t)
{
  const int idx = blockIdx.x * 256 + threadIdx.x;
  x[idx] += t[idx];
}

__global__ __launch_bounds__(256) void copy_kernel(
    float* __restrict__ dst, const float* __restrict__ src)
{
  const int idx = blockIdx.x * 256 + threadIdx.x;
  dst[idx] = src[idx];
}

// ---------------------------------------------------------------- conv 3x3 96->96
// resid/out may alias (same-index read->write) — no __restrict__.
__global__ __launch_bounds__(384) void conv96_kernel(
    const float* __restrict__ x, const float* __restrict__ wgt,
    const float* __restrict__ bias, const float* resid, float* out)
{
  const int blk = blockIdx.x;
  const int b = blk >> 4, th = (blk >> 2) & 3, tw = blk & 3;
  const int h0 = th * 8, w0 = tw * 8;
  __shared__ float patch[100][96];
  for (int idx = threadIdx.x; idx < 9600; idx += 384) {
    const int ic = idx % 96, pp = idx / 96;
    const int ph = pp / 10, pw = pp % 10;
    const int hh = h0 + ph - 1, ww = w0 + pw - 1;
    float v = 0.f;
    if ((unsigned)hh < 32u && (unsigned)ww < 32u)
      v = x[(((size_t)b * 32 + hh) * 32 + ww) * 96 + ic];
    patch[pp][ic] = v;
  }
  __syncthreads();
  const int oc = threadIdx.x % 96;
  const int pg = threadIdx.x / 96;
  float acc[16];
  #pragma unroll
  for (int i = 0; i < 16; ++i) acc[i] = bias[oc];
  for (int kh = 0; kh < 3; ++kh)
    for (int kw = 0; kw < 3; ++kw) {
      const float* wcol = wgt + (size_t)((kh * 3 + kw) * 96) * 96 + oc;
      #pragma unroll 4
      for (int ic = 0; ic < 96; ++ic) {
        const float wv = wcol[(size_t)ic * 96];
        #pragma unroll
        for (int i = 0; i < 16; ++i) {
          const int pos = pg * 16 + i;
          const int h = pos >> 3, w = pos & 7;
          acc[i] = fmaf(patch[(h + kh) * 10 + (w + kw)][ic], wv, acc[i]);
        }
      }
    }
  #pragma unroll
  for (int i = 0; i < 16; ++i) {
    const int pos = pg * 16 + i;
    const int h = pos >> 3, w = pos & 7;
    const size_t t = (((size_t)b * 32 + h0 + h) * 32 + (w0 + w));
    const float rr = resid ? resid[t * 96 + oc] : 0.f;
    out[t * 96 + oc] = acc[i] + rr;
  }
}

// ---------------------------------------------------------------- conv stem 4->96
__global__ __launch_bounds__(256) void conv_first_kernel(
    const float* __restrict__ es, const float* __restrict__ jp,
    const float* __restrict__ wgt, const float* __restrict__ bias,
    float* __restrict__ xf)
{
  const int idx = blockIdx.x * 256 + threadIdx.x;
  const int oc = idx % 96;
  const int pos = idx / 96;
  const int w = pos % 32, hp = (pos / 32) % 32, b = pos / 1024;
  float acc = bias[oc];
  for (int kh = 0; kh < 3; ++kh) {
    const int hh = hp + kh - 1;
    if ((unsigned)hh >= 32u) continue;
    for (int kw = 0; kw < 3; ++kw) {
      const int ww = w + kw - 1;
      if ((unsigned)ww >= 32u) continue;
      const size_t sp = ((size_t)b * 2 * 32 + hh) * 32 + ww;
      const float i0 = es[sp];
      const float i1 = es[sp + 1024];
      const float i2 = jp[sp];
      const float i3 = jp[sp + 1024];
      const float* wr = wgt + (size_t)((kh * 3 + kw) * 4) * 96 + oc;
      acc = fmaf(i0, wr[0], acc);
      acc = fmaf(i1, wr[96], acc);
      acc = fmaf(i2, wr[192], acc);
      acc = fmaf(i3, wr[288], acc);
    }
  }
  xf[idx] = acc;
}

// ---------------------------------------------------------------- conv tail 96->2
__global__ __launch_bounds__(256) void conv_last_kernel(
    const float* __restrict__ res, const float* __restrict__ wgt,
    const float* __restrict__ bias, float* __restrict__ out)
{
  const int idx = blockIdx.x * 256 + threadIdx.x;
  const int oc = idx % 2;
  const int pos = idx / 2;
  const int w = pos % 32, hp = (pos / 32) % 32, b = pos / 1024;
  float acc = bias[oc];
  for (int kh = 0; kh < 3; ++kh) {
    const int hh = hp + kh - 1;
    if ((unsigned)hh >= 32u) continue;
    for (int kw = 0; kw < 3; ++kw) {
      const int ww = w + kw - 1;
      if ((unsigned)ww >= 32u) continue;
      const float* pr = res + (((size_t)b * 32 + hh) * 32 + ww) * 96;
      const float* wr = wgt + (size_t)((kh * 3 + kw) * 96) * 2 + oc;
      #pragma unroll 8
      for (int ic = 0; ic < 96; ++ic)
        acc = fmaf(pr[ic], wr[ic * 2], acc);
    }
  }
  out[(((size_t)b * 2 + oc) * 32 + hp) * 32 + w] = acc;
}

// ---------------------------------------------------------------- host
extern "C" void kernel_launch(void* const* d_in, const int* in_sizes, int n_in,
                              void* d_out, int out_size, void* d_ws, size_t ws_size,
                              hipStream_t stream)
{
  const int fill_grid = (out_size + 255) / 256;

  if (n_in != 27) {
    fill_kernel<<<fill_grid, 256, 0, stream>>>((float*)d_out, 200.0f + (float)n_in, out_size);
    return;
  }
  static const int expected_sizes[27] = {
    131072, 131072, 3456, 96, 96, 96, 2304, 2304, 663552, 6912,
    221184, 2304, 32400, 2304, 2304, 884736, 9216, 884736, 2304,
    331776, 384, 96, 96, 82944, 96, 1728, 2
  };
  for (int i = 0; i < 27; ++i) {
    if (in_sizes[i] != expected_sizes[i]) {
      fill_kernel<<<fill_grid, 256, 0, stream>>>((float*)d_out, 300.0f + (float)i, out_size);
      return;
    }
  }
  if (out_size != 131072) {
    fill_kernel<<<fill_grid, 256, 0, stream>>>((float*)d_out, 400.0f, out_size);
    return;
  }
  const uintptr_t raw = (uintptr_t)d_ws;
  const uintptr_t alignedp = (raw + 255) & ~(uintptr_t)255;
  const size_t ws_avail_bytes = (ws_size > (alignedp - raw)) ? ws_size - (alignedp - raw) : 0;
  const size_t avail = ws_avail_bytes / 4;   // floats
  const size_t WBUF_F = 1327104;             // all bf16 weights, in float units
  const size_t floor_need = 2 * TC + WBUF_F + (size_t)1024 * 336;
  if (avail < floor_need) {
    fill_kernel<<<fill_grid, 256, 0, stream>>>((float*)d_out,
        100.0f + (float)(ws_size >> 20), out_size);
    return;
  }

  const float* es      = (const float*)d_in[0];
  const float* jp      = (const float*)d_in[1];
  const float* cf_w    = (const float*)d_in[2];
  const float* cf_b    = (const float*)d_in[3];
  const float* pe_s    = (const float*)d_in[4];
  const float* pe_b    = (const float*)d_in[5];
  const float* n1_s    = (const float*)d_in[6];
  const float* n1_b    = (const float*)d_in[7];
  const float* qkv_w   = (const float*)d_in[8];
  const float* qkv_b   = (const float*)d_in[9];
  const float* proj_w  = (const float*)d_in[10];
  const float* proj_b  = (const float*)d_in[11];
  const float* rpb     = (const float*)d_in[12];
  const float* n2_s    = (const float*)d_in[13];
  const float* n2_b    = (const float*)d_in[14];
  const float* fc1_w   = (const float*)d_in[15];
  const float* fc1_b   = (const float*)d_in[16];
  const float* fc2_w   = (const float*)d_in[17];
  const float* fc2_b   = (const float*)d_in[18];
  const float* rstb_w  = (const float*)d_in[19];
  const float* rstb_b  = (const float*)d_in[20];
  const float* nf_s    = (const float*)d_in[21];
  const float* nf_b    = (const float*)d_in[22];
  const float* body_w  = (const float*)d_in[23];
  const float* body_b  = (const float*)d_in[24];
  const float* last_w  = (const float*)d_in[25];
  const float* last_b  = (const float*)d_in[26];

  float* x = (float*)alignedp;
  float* r = x + TC;
  unsigned short* wq = (unsigned short*)(r + TC);        // [24][288][96] bf16
  unsigned short* wp = wq + 663552;                      // [24][96][96]
  unsigned short* w1 = wp + 221184;                      // [24][384][96]
  unsigned short* w2 = w1 + 884736;                      // [24][96][384]
  float* chunk_base = (float*)(w2 + 884736);

  int Tc = T_TOK;
  while (Tc > 1024 && 2 * TC + WBUF_F + (size_t)Tc * 336 > avail) Tc >>= 1;
  const int cn = T_TOK / Tc;
  unsigned short* a_b = (unsigned short*)chunk_base;     // [Tc][96] bf16
  unsigned short* g_b = a_b + (size_t)Tc * 96;           // [Tc][384] bf16
  float* o_f = (float*)(g_b + (size_t)Tc * 384);         // [Tc][96] fp32

  const int grid_tc = (int)(TC / 256);
  const int grid_ch = (Tc * CC) / 256;
  const int grid_lf = T_TOK / 4;
  const int grid_lc = Tc / 4;

  // weight convert+transpose (runs every launch; deterministic, tiny)
  wconv_kernel<<<dim3((96 * 288 + 255) / 256, 24), 256, 0, stream>>>(qkv_w, wq, 96, 288);
  wconv_kernel<<<dim3((96 * 96 + 255) / 256, 24), 256, 0, stream>>>(proj_w, wp, 96, 96);
  wconv_kernel<<<dim3((96 * 384 + 255) / 256, 24), 256, 0, stream>>>(fc1_w, w1, 96, 384);
  wconv_kernel<<<dim3((384 * 96 + 255) / 256, 24), 256, 0, stream>>>(fc2_w, w2, 384, 96);

  // stem
  conv_first_kernel<<<grid_tc, 256, 0, stream>>>(es, jp, cf_w, cf_b, x);
  // LN_pe: write bf16 into a_b chunk? pe-LN output must persist in fp32 x.
  // Do it in fp32 via: LN to r (reuse ln via bf16 not possible) -> use a small trick:
  // run ln into a_b (bf16) then expand? Cheaper: keep a dedicated fp32 LN pass via
  // copy: LN_pe(x) -> bf16 a_b, then expand a_b -> x. Precision: x is immediately
  // LN-normalized input to block 0; reference keeps fp32. Expanding bf16 loses
  // ~0.4% here; instead compute LN_pe in fp32 using conv96-free path:
  //   reuse ln_kernel to write bf16, then promote. Promote kernel below.
  ln_kernel<<<grid_lf, 256, 0, stream>>>(x, pe_s, pe_b, a_b, -1, 0);
  // promote bf16 -> fp32 x (block 0's LN1 re-reads x; drift negligible but keep
  // the residual stream itself faithful: x := bf16(LN_pe) promoted)
  {
    // inline promote via add_kernel-style kernel
    struct Local {};
  }
  // promote kernel launch (defined below via lambda-impossible; use copy trick)
  extern __global__ void promote_kernel(const unsigned short*, float*);
  promote_kernel<<<grid_tc, 256, 0, stream>>>(a_b, x);

  float* xb = x;
  float* rb = r;
  for (int l = 0; l < NL; ++l) {
    copy_kernel<<<grid_tc, 256, 0, stream>>>(rb, xb);
    for (int d = 0; d < ND; ++d) {
      const int ld = l * ND + d;
      const int shift = (d & 1) ? 4 : 0;
      for (int c = 0; c < cn; ++c) {
        const size_t off = (size_t)c * Tc * CC;
        const int t0 = c * Tc;
        ln_kernel<<<grid_lc, 256, 0, stream>>>(xb, n1_s + ld * CC, n1_b + ld * CC,
                                               a_b, shift, t0);
        { dim3 g(Tc / 64, 288 / 32);
          mgemm<1, 0><<<g, 256, 0, stream>>>(a_b, wq + (size_t)ld * 288 * 96,
              qkv_b + (size_t)ld * 288, nullptr, g_b, 288, 96); }
        attn_kernel<<<(Tc / 64) * NH, 64, 0, stream>>>(
            g_b, rpb + (size_t)ld * 225 * NH, a_b, shift);
        { dim3 g(Tc / 64, 96 / 32);
          mgemm<0, 0><<<g, 256, 0, stream>>>(a_b, wp + (size_t)ld * 96 * 96,
              proj_b + (size_t)ld * 96, o_f, nullptr, 96, 96); }
        addback_kernel<<<grid_ch, 256, 0, stream>>>(xb + off, o_f, shift);
        ln_kernel<<<grid_lc, 256, 0, stream>>>(xb, n2_s + ld * CC, n2_b + ld * CC,
                                               a_b, -1, t0);
        { dim3 g(Tc / 64, 384 / 32);
          mgemm<1, 1><<<g, 256, 0, stream>>>(a_b, w1 + (size_t)ld * 384 * 96,
              fc1_b + (size_t)ld * 384, nullptr, g_b, 384, 96); }
        { dim3 g(Tc / 64, 96 / 32);
          mgemm<0, 0><<<g, 256, 0, stream>>>(g_b, w2 + (size_t)ld * 96 * 384,
              fc2_b + (size_t)ld * 96, o_f, nullptr, 96, 384); }
        add_kernel<<<grid_ch, 256, 0, stream>>>(xb + off, o_f);
      }
    }
    conv96_kernel<<<1024, 384, 0, stream>>>(xb, rstb_w + (size_t)l * 9 * CC * CC,
                                            rstb_b + (size_t)l * CC, rb, rb);
    float* sw = xb; xb = rb; rb = sw;
  }
  // tail: rb = LN_f(xb) in fp32 via bf16+promote; then convs
  ln_kernel<<<grid_lf, 256, 0, stream>>>(xb, nf_s, nf_b, a_b, -1, 0);
  promote_kernel<<<grid_tc, 256, 0, stream>>>(a_b, rb);
  conv_first_kernel<<<grid_tc, 256, 0, stream>>>(es, jp, cf_w, cf_b, xb);
  conv96_kernel<<<1024, 384, 0, stream>>>(rb, body_w, body_b, xb, xb);
  conv_last_kernel<<<(BB * 32 * 32 * 2) / 256, 256, 0, stream>>>(xb, last_w, last_b, (float*)d_out);
}

// promote bf16 -> fp32
__global__ __launch_bounds__(256) void promote_kernel(
    const unsigned short* __restrict__ src, float* __restrict__ dst)
{
  const int idx = blockIdx.x * 256 + threadIdx.x;
  dst[idx] = bf2f(src[idx]);
}

// Round 11
// 6631.461 us; speedup vs baseline: 1.5430x; 1.0532x over previous
//
#include <hip/hip_runtime.h>
#include <hip/hip_bf16.h>
#include <cstddef>
#include <cstdint>

#define BB 64
#define HH 32
#define WW_ 32
#define CC 96
#define WS 8
#define NH 6
#define NL 4
#define ND 6
#define T_TOK (BB*HH*WW_)      // 65536 tokens
#define TC ((size_t)T_TOK*CC)  // 6291456 floats

typedef long long ll;
typedef __attribute__((ext_vector_type(8))) short short8;
typedef __attribute__((ext_vector_type(4))) float f32x4;
typedef __attribute__((ext_vector_type(4))) unsigned short ushort4v;

// Harness-named kernel symbol.
__global__ void JNetSwinIR_41034117546277_kernel() {}

__device__ __forceinline__ unsigned short f2bf(float f) {
  unsigned u = __float_as_uint(f);
  unsigned r = (u + 0x7FFF + ((u >> 16) & 1)) >> 16;
  return (unsigned short)r;
}
__device__ __forceinline__ float bf2f(unsigned short h) {
  return __uint_as_float(((unsigned)h) << 16);
}

// ---------------------------------------------------------------- diagnostic fill
__global__ __launch_bounds__(256) void fill_kernel(float* p, float v, int n)
{
  const int idx = blockIdx.x * 256 + threadIdx.x;
  if (idx < n) p[idx] = v;
}

// ---------------------------------------------------------------- weight fp32->bf16 transpose
// W [24][K][N] fp32 -> Wt [24][N][K] bf16
__global__ __launch_bounds__(256) void wconv_kernel(
    const float* __restrict__ W, unsigned short* __restrict__ Wt, int K, int N)
{
  const int ld = blockIdx.y;
  const int idx = blockIdx.x * 256 + threadIdx.x;
  if (idx >= K * N) return;
  const int k = idx / N, n = idx % N;
  Wt[(size_t)ld * K * N + (size_t)n * K + k] = f2bf(W[(size_t)ld * K * N + idx]);
}

// ---------------------------------------------------------------- LayerNorm
// BF16OUT=1: write bf16 to outb; BF16OUT=0: write fp32 to outf (in-place-safe).
template<int BF16OUT>
__global__ __launch_bounds__(256) void ln_kernel(
    const float* __restrict__ x, const float* __restrict__ gamma,
    const float* __restrict__ beta, unsigned short* __restrict__ outb,
    float* __restrict__ outf, int shift, int t0)
{
  const int wave = threadIdx.x >> 6;
  const int lane = threadIdx.x & 63;
  const int lt = blockIdx.x * 4 + wave;
  const int ot = t0 + lt;
  int st;
  if (shift < 0) {
    st = ot;
  } else {
    const int widx = ot >> 6, n = ot & 63;
    const int b = widx >> 4, wimg = widx & 15;
    const int wh = wimg >> 2, ww = wimg & 3;
    const int r = wh * 8 + (n >> 3), c = ww * 8 + (n & 7);
    const int p = (r + shift) & 31, q = (c + shift) & 31;
    st = (b << 10) + (p << 5) + q;
  }
  const float* xp = x + (size_t)st * CC;
  const float v0 = xp[lane];
  const float v1 = (lane < 32) ? xp[64 + lane] : 0.f;
  float s = v0 + v1, s2 = v0 * v0 + v1 * v1;
  #pragma unroll
  for (int off = 32; off; off >>= 1) {
    s  += __shfl_xor(s,  off);
    s2 += __shfl_xor(s2, off);
  }
  const float mean = s * (1.f / 96.f);
  const float var  = s2 * (1.f / 96.f) - mean * mean;
  const float inv  = rsqrtf(var + 1e-5f);
  const float r0 = (v0 - mean) * inv * gamma[lane] + beta[lane];
  if (BF16OUT) {
    unsigned short* op = outb + (size_t)lt * CC;
    op[lane] = f2bf(r0);
    if (lane < 32)
      op[64 + lane] = f2bf((v1 - mean) * inv * gamma[64 + lane] + beta[64 + lane]);
  } else {
    float* op = outf + (size_t)lt * CC;
    const float r1 = (v1 - mean) * inv * gamma[64 + lane] + beta[64 + lane];
    op[lane] = r0;
    if (lane < 32) op[64 + lane] = r1;
  }
}

// ---------------------------------------------------------------- MFMA GEMM
// C[M,N] = A[M,K](bf16) @ Wt[N,K]^T (+bias).
// MODE 0: Cf=  ; 1: Cb= (bf16); 2: Cf+= (identity rows); 3: Cf+= scatter
// (window-token row m -> image token t via roll-back, for proj residual add).
template<int MODE, int GELU>
__global__ __launch_bounds__(256) void mgemm(
    const unsigned short* __restrict__ A, const unsigned short* __restrict__ Bt,
    const float* __restrict__ bias, float* __restrict__ Cf,
    unsigned short* __restrict__ Cb, int N, int K, int shift)
{
  const int wv   = threadIdx.x >> 6;
  const int lane = threadIdx.x & 63;
  const int m0 = blockIdx.x * 64 + wv * 16;
  const int n0 = blockIdx.y * 32;
  const int row = lane & 15;
  const int ko  = (lane >> 4) * 8;
  f32x4 acc0 = {0.f, 0.f, 0.f, 0.f};
  f32x4 acc1 = {0.f, 0.f, 0.f, 0.f};
  const unsigned short* ap  = A  + (size_t)(m0 + row) * K + ko;
  const unsigned short* bp0 = Bt + (size_t)(n0 + row) * K + ko;
  const unsigned short* bp1 = Bt + (size_t)(n0 + 16 + row) * K + ko;
  for (int k0 = 0; k0 < K; k0 += 32) {
    const short8 af  = *(const short8*)(ap + k0);
    const short8 bf0 = *(const short8*)(bp0 + k0);
    const short8 bf1 = *(const short8*)(bp1 + k0);
    acc0 = __builtin_amdgcn_mfma_f32_16x16x32_bf16(af, bf0, acc0, 0, 0, 0);
    acc1 = __builtin_amdgcn_mfma_f32_16x16x32_bf16(af, bf1, acc1, 0, 0, 0);
  }
  const int cc  = lane & 15;
  const int cr0 = (lane >> 4) * 4;
  const float b0 = bias ? bias[n0 + cc] : 0.f;
  const float b1 = bias ? bias[n0 + 16 + cc] : 0.f;
  #pragma unroll
  for (int r = 0; r < 4; ++r) {
    const int m = m0 + cr0 + r;
    float v0 = acc0[r] + b0;
    float v1 = acc1[r] + b1;
    if (GELU) {
      v0 = 0.5f * v0 * (1.f + erff(v0 * 0.70710678118f));
      v1 = 0.5f * v1 * (1.f + erff(v1 * 0.70710678118f));
    }
    if (MODE == 0) {
      Cf[(size_t)m * N + n0 + cc]      = v0;
      Cf[(size_t)m * N + n0 + 16 + cc] = v1;
    } else if (MODE == 1) {
      Cb[(size_t)m * N + n0 + cc]      = f2bf(v0);
      Cb[(size_t)m * N + n0 + 16 + cc] = f2bf(v1);
    } else if (MODE == 2) {
      Cf[(size_t)m * N + n0 + cc]      += v0;
      Cf[(size_t)m * N + n0 + 16 + cc] += v1;
    } else {
      // window token m -> image token t (undo window partition + roll)
      const int widx = m >> 6, n = m & 63;
      const int b = widx >> 4, wimg = widx & 15;
      const int rr2 = (wimg >> 2) * 8 + (n >> 3);
      const int cc2 = (wimg & 3) * 8 + (n & 7);
      const int p = (rr2 + shift) & 31, q = (cc2 + shift) & 31;
      const int t = (b << 10) + (p << 5) + q;
      Cf[(size_t)t * 96 + n0 + cc]      += v0;
      Cf[(size_t)t * 96 + n0 + 16 + cc] += v1;
    }
  }
}

// ---------------------------------------------------------------- Attention
// one block per window: 384 threads = 6 waves, wave = head.
// QKV staged coalesced into LDS; K/V fp32 (aligned float4 broadcast), Q bf16.
__global__ __launch_bounds__(384) void attn_kernel(
    const unsigned short* __restrict__ qkv, const float* __restrict__ rpb_ld,
    unsigned short* __restrict__ out, int shift)
{
  const int widx = blockIdx.x;
  const int tid  = threadIdx.x;
  const int head = tid >> 6;
  const int lane = tid & 63;
  __shared__ float kv[64][200];            // [tok][0..95 K | 96..191 V] pad->200
  __shared__ unsigned short qsh[64][104];  // [tok][96] bf16, pad->104
  __shared__ float bias_s[NH * 225];
  __shared__ int reg_s[64];
  // stage K,V (fp32) — coalesced ushort4 global reads
  const size_t gbase = (size_t)widx * 64 * 288;
  for (int i4 = tid; i4 < 64 * 48; i4 += 384) {      // 64*192/4
    const int row = i4 / 48, c4 = (i4 % 48) * 4;
    const ushort4v v = *(const ushort4v*)(qkv + gbase + (size_t)row * 288 + 96 + c4);
    kv[row][c4]     = bf2f(v.x);
    kv[row][c4 + 1] = bf2f(v.y);
    kv[row][c4 + 2] = bf2f(v.z);
    kv[row][c4 + 3] = bf2f(v.w);
  }
  // stage Q (bf16 raw)
  for (int i4 = tid; i4 < 64 * 24; i4 += 384) {      // 64*96/4
    const int row = i4 / 24, c4 = (i4 % 24) * 4;
    *(ushort4v*)&qsh[row][c4] =
        *(const ushort4v*)(qkv + gbase + (size_t)row * 288 + c4);
  }
  for (int i = tid; i < NH * 225; i += 384) {
    const int h = i / 225, ii = i % 225;
    bias_s[i] = rpb_ld[ii * NH + h];
  }
  if (tid < 64) {
    const int wimg = widx & 15;
    const int h = (wimg >> 2) * 8 + (tid >> 3);
    const int w = (wimg & 3) * 8 + (tid & 7);
    reg_s[tid] = 3 * (h < 24 ? 0 : (h < 28 ? 1 : 2)) +
                     (w < 24 ? 0 : (w < 28 ? 1 : 2));
  }
  __syncthreads();

  const float* bias_h = bias_s + head * 225;
  float q[16];
  #pragma unroll
  for (int c = 0; c < 16; ++c) q[c] = bf2f(qsh[lane][head * 16 + c]);
  const int ih = lane >> 3, iw = lane & 7;
  const int myreg = reg_s[lane];
  float s[64];
  #pragma unroll
  for (int j = 0; j < 64; ++j) {
    const float4 k0 = *(const float4*)&kv[j][head * 16];
    const float4 k1 = *(const float4*)&kv[j][head * 16 + 4];
    const float4 k2 = *(const float4*)&kv[j][head * 16 + 8];
    const float4 k3 = *(const float4*)&kv[j][head * 16 + 12];
    float acc = 0.f;
    acc = fmaf(q[0],  k0.x, acc); acc = fmaf(q[1],  k0.y, acc);
    acc = fmaf(q[2],  k0.z, acc); acc = fmaf(q[3],  k0.w, acc);
    acc = fmaf(q[4],  k1.x, acc); acc = fmaf(q[5],  k1.y, acc);
    acc = fmaf(q[6],  k1.z, acc); acc = fmaf(q[7],  k1.w, acc);
    acc = fmaf(q[8],  k2.x, acc); acc = fmaf(q[9],  k2.y, acc);
    acc = fmaf(q[10], k2.z, acc); acc = fmaf(q[11], k2.w, acc);
    acc = fmaf(q[12], k3.x, acc); acc = fmaf(q[13], k3.y, acc);
    acc = fmaf(q[14], k3.z, acc); acc = fmaf(q[15], k3.w, acc);
    const int idx = (ih - (j >> 3) + 7) * 15 + (iw - (j & 7) + 7);
    acc = acc * 0.25f + bias_h[idx];
    if (shift && reg_s[j] != myreg) acc -= 100.f;
    s[j] = acc;
  }
  float m = s[0];
  #pragma unroll
  for (int j = 1; j < 64; ++j) m = fmaxf(m, s[j]);
  float sum = 0.f;
  #pragma unroll
  for (int j = 0; j < 64; ++j) { const float p = __expf(s[j] - m); s[j] = p; sum += p; }
  const float inv = 1.f / sum;
  float o[16] = {};
  #pragma unroll
  for (int j = 0; j < 64; ++j) {
    const float p = s[j] * inv;
    const float4 v0 = *(const float4*)&kv[j][96 + head * 16];
    const float4 v1 = *(const float4*)&kv[j][96 + head * 16 + 4];
    const float4 v2 = *(const float4*)&kv[j][96 + head * 16 + 8];
    const float4 v3 = *(const float4*)&kv[j][96 + head * 16 + 12];
    o[0]  = fmaf(p, v0.x, o[0]);  o[1]  = fmaf(p, v0.y, o[1]);
    o[2]  = fmaf(p, v0.z, o[2]);  o[3]  = fmaf(p, v0.w, o[3]);
    o[4]  = fmaf(p, v1.x, o[4]);  o[5]  = fmaf(p, v1.y, o[5]);
    o[6]  = fmaf(p, v1.z, o[6]);  o[7]  = fmaf(p, v1.w, o[7]);
    o[8]  = fmaf(p, v2.x, o[8]);  o[9]  = fmaf(p, v2.y, o[9]);
    o[10] = fmaf(p, v2.z, o[10]); o[11] = fmaf(p, v2.w, o[11]);
    o[12] = fmaf(p, v3.x, o[12]); o[13] = fmaf(p, v3.y, o[13]);
    o[14] = fmaf(p, v3.z, o[14]); o[15] = fmaf(p, v3.w, o[15]);
  }
  unsigned short* op = out + ((size_t)widx * 64 + lane) * CC + head * 16;
  short8 o0, o1;
  #pragma unroll
  for (int i = 0; i < 8; ++i) {
    o0[i] = (short)f2bf(o[i]);
    o1[i] = (short)f2bf(o[8 + i]);
  }
  *(short8*)(op) = o0;
  *(short8*)(op + 8) = o1;
}

// ---------------------------------------------------------------- copy
__global__ __launch_bounds__(256) void copy_kernel(
    float* __restrict__ dst, const float* __restrict__ src)
{
  const int idx = blockIdx.x * 256 + threadIdx.x;
  dst[idx] = src[idx];
}

// ---------------------------------------------------------------- conv 3x3 96->96
__global__ __launch_bounds__(384) void conv96_kernel(
    const float* __restrict__ x, const float* __restrict__ wgt,
    const float* __restrict__ bias, const float* resid, float* out)
{
  const int blk = blockIdx.x;
  const int b = blk >> 4, th = (blk >> 2) & 3, tw = blk & 3;
  const int h0 = th * 8, w0 = tw * 8;
  __shared__ float patch[100][96];
  for (int idx = threadIdx.x; idx < 9600; idx += 384) {
    const int ic = idx % 96, pp = idx / 96;
    const int ph = pp / 10, pw = pp % 10;
    const int hh = h0 + ph - 1, ww = w0 + pw - 1;
    float v = 0.f;
    if ((unsigned)hh < 32u && (unsigned)ww < 32u)
      v = x[(((size_t)b * 32 + hh) * 32 + ww) * 96 + ic];
    patch[pp][ic] = v;
  }
  __syncthreads();
  const int oc = threadIdx.x % 96;
  const int pg = threadIdx.x / 96;
  float acc[16];
  #pragma unroll
  for (int i = 0; i < 16; ++i) acc[i] = bias[oc];
  for (int kh = 0; kh < 3; ++kh)
    for (int kw = 0; kw < 3; ++kw) {
      const float* wcol = wgt + (size_t)((kh * 3 + kw) * 96) * 96 + oc;
      #pragma unroll 4
      for (int ic = 0; ic < 96; ++ic) {
        const float wv = wcol[(size_t)ic * 96];
        #pragma unroll
        for (int i = 0; i < 16; ++i) {
          const int pos = pg * 16 + i;
          const int h = pos >> 3, w = pos & 7;
          acc[i] = fmaf(patch[(h + kh) * 10 + (w + kw)][ic], wv, acc[i]);
        }
      }
    }
  #pragma unroll
  for (int i = 0; i < 16; ++i) {
    const int pos = pg * 16 + i;
    const int h = pos >> 3, w = pos & 7;
    const size_t t = (((size_t)b * 32 + h0 + h) * 32 + (w0 + w));
    const float rr = resid ? resid[t * 96 + oc] : 0.f;
    out[t * 96 + oc] = acc[i] + rr;
  }
}

// ---------------------------------------------------------------- conv stem 4->96
__global__ __launch_bounds__(256) void conv_first_kernel(
    const float* __restrict__ es, const float* __restrict__ jp,
    const float* __restrict__ wgt, const float* __restrict__ bias,
    float* __restrict__ xf)
{
  const int idx = blockIdx.x * 256 + threadIdx.x;
  const int oc = idx % 96;
  const int pos = idx / 96;
  const int w = pos % 32, hp = (pos / 32) % 32, b = pos / 1024;
  float acc = bias[oc];
  for (int kh = 0; kh < 3; ++kh) {
    const int hh = hp + kh - 1;
    if ((unsigned)hh >= 32u) continue;
    for (int kw = 0; kw < 3; ++kw) {
      const int ww = w + kw - 1;
      if ((unsigned)ww >= 32u) continue;
      const size_t sp = ((size_t)b * 2 * 32 + hh) * 32 + ww;
      const float i0 = es[sp];
      const float i1 = es[sp + 1024];
      const float i2 = jp[sp];
      const float i3 = jp[sp + 1024];
      const float* wr = wgt + (size_t)((kh * 3 + kw) * 4) * 96 + oc;
      acc = fmaf(i0, wr[0], acc);
      acc = fmaf(i1, wr[96], acc);
      acc = fmaf(i2, wr[192], acc);
      acc = fmaf(i3, wr[288], acc);
    }
  }
  xf[idx] = acc;
}

// ---------------------------------------------------------------- conv tail 96->2
__global__ __launch_bounds__(256) void conv_last_kernel(
    const float* __restrict__ res, const float* __restrict__ wgt,
    const float* __restrict__ bias, float* __restrict__ out)
{
  const int idx = blockIdx.x * 256 + threadIdx.x;
  const int oc = idx % 2;
  const int pos = idx / 2;
  const int w = pos % 32, hp = (pos / 32) % 32, b = pos / 1024;
  float acc = bias[oc];
  for (int kh = 0; kh < 3; ++kh) {
    const int hh = hp + kh - 1;
    if ((unsigned)hh >= 32u) continue;
    for (int kw = 0; kw < 3; ++kw) {
      const int ww = w + kw - 1;
      if ((unsigned)ww >= 32u) continue;
      const float* pr = res + (((size_t)b * 32 + hh) * 32 + ww) * 96;
      const float* wr = wgt + (size_t)((kh * 3 + kw) * 96) * 2 + oc;
      #pragma unroll 8
      for (int ic = 0; ic < 96; ++ic)
        acc = fmaf(pr[ic], wr[ic * 2], acc);
    }
  }
  out[(((size_t)b * 2 + oc) * 32 + hp) * 32 + w] = acc;
}

// ---------------------------------------------------------------- host
extern "C" void kernel_launch(void* const* d_in, const int* in_sizes, int n_in,
                              void* d_out, int out_size, void* d_ws, size_t ws_size,
                              hipStream_t stream)
{
  const int fill_grid = (out_size + 255) / 256;

  if (n_in != 27) {
    fill_kernel<<<fill_grid, 256, 0, stream>>>((float*)d_out, 200.0f + (float)n_in, out_size);
    return;
  }
  static const int expected_sizes[27] = {
    131072, 131072, 3456, 96, 96, 96, 2304, 2304, 663552, 6912,
    221184, 2304, 32400, 2304, 2304, 884736, 9216, 884736, 2304,
    331776, 384, 96, 96, 82944, 96, 1728, 2
  };
  for (int i = 0; i < 27; ++i) {
    if (in_sizes[i] != expected_sizes[i]) {
      fill_kernel<<<fill_grid, 256, 0, stream>>>((float*)d_out, 300.0f + (float)i, out_size);
      return;
    }
  }
  if (out_size != 131072) {
    fill_kernel<<<fill_grid, 256, 0, stream>>>((float*)d_out, 400.0f, out_size);
    return;
  }
  const uintptr_t raw = (uintptr_t)d_ws;
  const uintptr_t alignedp = (raw + 255) & ~(uintptr_t)255;
  const size_t ws_avail_bytes = (ws_size > (alignedp - raw)) ? ws_size - (alignedp - raw) : 0;
  const size_t avail = ws_avail_bytes / 4;   // floats
  const size_t WBUF_F = 1327104;             // bf16 weights, float units
  const size_t floor_need = 2 * TC + WBUF_F + (size_t)1024 * 240;
  if (avail < floor_need) {
    fill_kernel<<<fill_grid, 256, 0, stream>>>((float*)d_out,
        100.0f + (float)(ws_size >> 20), out_size);
    return;
  }

  const float* es      = (const float*)d_in[0];
  const float* jp      = (const float*)d_in[1];
  const float* cf_w    = (const float*)d_in[2];
  const float* cf_b    = (const float*)d_in[3];
  const float* pe_s    = (const float*)d_in[4];
  const float* pe_b    = (const float*)d_in[5];
  const float* n1_s    = (const float*)d_in[6];
  const float* n1_b    = (const float*)d_in[7];
  const float* qkv_w   = (const float*)d_in[8];
  const float* qkv_b   = (const float*)d_in[9];
  const float* proj_w  = (const float*)d_in[10];
  const float* proj_b  = (const float*)d_in[11];
  const float* rpb     = (const float*)d_in[12];
  const float* n2_s    = (const float*)d_in[13];
  const float* n2_b    = (const float*)d_in[14];
  const float* fc1_w   = (const float*)d_in[15];
  const float* fc1_b   = (const float*)d_in[16];
  const float* fc2_w   = (const float*)d_in[17];
  const float* fc2_b   = (const float*)d_in[18];
  const float* rstb_w  = (const float*)d_in[19];
  const float* rstb_b  = (const float*)d_in[20];
  const float* nf_s    = (const float*)d_in[21];
  const float* nf_b    = (const float*)d_in[22];
  const float* body_w  = (const float*)d_in[23];
  const float* body_b  = (const float*)d_in[24];
  const float* last_w  = (const float*)d_in[25];
  const float* last_b  = (const float*)d_in[26];

  float* x = (float*)alignedp;
  float* r = x + TC;
  unsigned short* wq = (unsigned short*)(r + TC);        // [24][288][96] bf16
  unsigned short* wp = wq + 663552;                      // [24][96][96]
  unsigned short* w1 = wp + 221184;                      // [24][384][96]
  unsigned short* w2 = w1 + 884736;                      // [24][96][384]
  float* chunk_base = (float*)(w2 + 884736);

  int Tc = T_TOK;
  while (Tc > 1024 && 2 * TC + WBUF_F + (size_t)Tc * 240 > avail) Tc >>= 1;
  const int cn = T_TOK / Tc;
  unsigned short* a_b = (unsigned short*)chunk_base;     // [Tc][96] bf16
  unsigned short* g_b = a_b + (size_t)Tc * 96;           // [Tc][384] bf16

  const int grid_tc = (int)(TC / 256);
  const int grid_lf = T_TOK / 4;
  const int grid_lc = Tc / 4;

  // weight convert+transpose
  wconv_kernel<<<dim3((96 * 288 + 255) / 256, 24), 256, 0, stream>>>(qkv_w, wq, 96, 288);
  wconv_kernel<<<dim3((96 * 96 + 255) / 256, 24), 256, 0, stream>>>(proj_w, wp, 96, 96);
  wconv_kernel<<<dim3((96 * 384 + 255) / 256, 24), 256, 0, stream>>>(fc1_w, w1, 96, 384);
  wconv_kernel<<<dim3((384 * 96 + 255) / 256, 24), 256, 0, stream>>>(fc2_w, w2, 384, 96);

  // stem: x = LN_pe(conv_first(inputs)), LN in place
  conv_first_kernel<<<grid_tc, 256, 0, stream>>>(es, jp, cf_w, cf_b, x);
  ln_kernel<0><<<grid_lf, 256, 0, stream>>>(x, pe_s, pe_b, nullptr, x, -1, 0);

  float* xb = x;
  float* rb = r;
  for (int l = 0; l < NL; ++l) {
    copy_kernel<<<grid_tc, 256, 0, stream>>>(rb, xb);
    for (int d = 0; d < ND; ++d) {
      const int ld = l * ND + d;
      const int shift = (d & 1) ? 4 : 0;
      for (int c = 0; c < cn; ++c) {
        const size_t off = (size_t)c * Tc * CC;
        const int t0 = c * Tc;
        // LN1 (+roll+window) -> a_b bf16
        ln_kernel<1><<<grid_lc, 256, 0, stream>>>(xb, n1_s + ld * CC, n1_b + ld * CC,
                                                  a_b, nullptr, shift, t0);
        // QKV -> g_b bf16
        { dim3 g(Tc / 64, 288 / 32);
          mgemm<1, 0><<<g, 256, 0, stream>>>(a_b, wq + (size_t)ld * 288 * 96,
              qkv_b + (size_t)ld * 288, nullptr, g_b, 288, 96, 0); }
        // attention -> a_b bf16 (window order), 1 block/window
        attn_kernel<<<Tc / 64, 384, 0, stream>>>(
            g_b, rpb + (size_t)ld * 225 * NH, a_b, shift);
        // proj + window-reverse + residual-add, fused scatter into xb chunk
        { dim3 g(Tc / 64, 96 / 32);
          mgemm<3, 0><<<g, 256, 0, stream>>>(a_b, wp + (size_t)ld * 96 * 96,
              proj_b + (size_t)ld * 96, xb + off, nullptr, 96, 96, shift); }
        // LN2 -> a_b bf16
        ln_kernel<1><<<grid_lc, 256, 0, stream>>>(xb, n2_s + ld * CC, n2_b + ld * CC,
                                                  a_b, nullptr, -1, t0);
        // fc1 + gelu -> g_b bf16
        { dim3 g(Tc / 64, 384 / 32);
          mgemm<1, 1><<<g, 256, 0, stream>>>(a_b, w1 + (size_t)ld * 384 * 96,
              fc1_b + (size_t)ld * 384, nullptr, g_b, 384, 96, 0); }
        // fc2 + residual-add, fused accumulate into xb chunk
        { dim3 g(Tc / 64, 96 / 32);
          mgemm<2, 0><<<g, 256, 0, stream>>>(g_b, w2 + (size_t)ld * 96 * 384,
              fc2_b + (size_t)ld * 96, xb + off, nullptr, 96, 384, 0); }
      }
    }
    conv96_kernel<<<1024, 384, 0, stream>>>(xb, rstb_w + (size_t)l * 9 * CC * CC,
                                            rstb_b + (size_t)l * CC, rb, rb);
    float* sw = xb; xb = rb; rb = sw;
  }
  // tail
  ln_kernel<0><<<grid_lf, 256, 0, stream>>>(xb, nf_s, nf_b, nullptr, rb, -1, 0);
  conv_first_kernel<<<grid_tc, 256, 0, stream>>>(es, jp, cf_w, cf_b, xb);
  conv96_kernel<<<1024, 384, 0, stream>>>(rb, body_w, body_b, xb, xb);
  conv_last_kernel<<<(BB * 32 * 32 * 2) / 256, 256, 0, stream>>>(xb, last_w, last_b, (float*)d_out);
}

// Round 12
// 5503.637 us; speedup vs baseline: 1.8592x; 1.2049x over previous
//
#include <hip/hip_runtime.h>
#include <hip/hip_bf16.h>
#include <cstddef>
#include <cstdint>

#define BB 64
#define HH 32
#define WW_ 32
#define CC 96
#define WS 8
#define NH 6
#define NL 4
#define ND 6
#define T_TOK (BB*HH*WW_)      // 65536 tokens
#define TC ((size_t)T_TOK*CC)  // 6291456 floats

typedef long long ll;
typedef __attribute__((ext_vector_type(8))) short short8;
typedef __attribute__((ext_vector_type(4))) float f32x4;
typedef __attribute__((ext_vector_type(4))) unsigned short ushort4v;

// Harness-named kernel symbol.
__global__ void JNetSwinIR_41034117546277_kernel() {}

__device__ __forceinline__ unsigned short f2bf(float f) {
  unsigned u = __float_as_uint(f);
  unsigned r = (u + 0x7FFF + ((u >> 16) & 1)) >> 16;
  return (unsigned short)r;
}
__device__ __forceinline__ float bf2f(unsigned short h) {
  return __uint_as_float(((unsigned)h) << 16);
}

// ---------------------------------------------------------------- diagnostic fill
__global__ __launch_bounds__(256) void fill_kernel(float* p, float v, int n)
{
  const int idx = blockIdx.x * 256 + threadIdx.x;
  if (idx < n) p[idx] = v;
}

// ---------------------------------------------------------------- weight fp32->bf16 transpose
// W [24][K][N] fp32 -> Wt [24][N][K] bf16
__global__ __launch_bounds__(256) void wconv_kernel(
    const float* __restrict__ W, unsigned short* __restrict__ Wt, int K, int N)
{
  const int ld = blockIdx.y;
  const int idx = blockIdx.x * 256 + threadIdx.x;
  if (idx >= K * N) return;
  const int k = idx / N, n = idx % N;
  Wt[(size_t)ld * K * N + (size_t)n * K + k] = f2bf(W[(size_t)ld * K * N + idx]);
}

// conv weights [L][3][3][ic=96][oc=96] fp32 -> [L][9][oc][ic] bf16
__global__ __launch_bounds__(256) void wconv_conv_kernel(
    const float* __restrict__ W, unsigned short* __restrict__ Wt, int total)
{
  const int idx = blockIdx.x * 256 + threadIdx.x;
  if (idx >= total) return;
  const int l9 = idx / 9216;
  const int rest = idx % 9216;
  const int oc = rest / 96, ic = rest % 96;
  Wt[idx] = f2bf(W[(size_t)(l9 * 96 + ic) * 96 + oc]);
}

// ---------------------------------------------------------------- LayerNorm
template<int BF16OUT>
__global__ __launch_bounds__(256) void ln_kernel(
    const float* __restrict__ x, const float* __restrict__ gamma,
    const float* __restrict__ beta, unsigned short* __restrict__ outb,
    float* __restrict__ outf, int shift, int t0)
{
  const int wave = threadIdx.x >> 6;
  const int lane = threadIdx.x & 63;
  const int lt = blockIdx.x * 4 + wave;
  const int ot = t0 + lt;
  int st;
  if (shift < 0) {
    st = ot;
  } else {
    const int widx = ot >> 6, n = ot & 63;
    const int b = widx >> 4, wimg = widx & 15;
    const int wh = wimg >> 2, ww = wimg & 3;
    const int r = wh * 8 + (n >> 3), c = ww * 8 + (n & 7);
    const int p = (r + shift) & 31, q = (c + shift) & 31;
    st = (b << 10) + (p << 5) + q;
  }
  const float* xp = x + (size_t)st * CC;
  const float v0 = xp[lane];
  const float v1 = (lane < 32) ? xp[64 + lane] : 0.f;
  float s = v0 + v1, s2 = v0 * v0 + v1 * v1;
  #pragma unroll
  for (int off = 32; off; off >>= 1) {
    s  += __shfl_xor(s,  off);
    s2 += __shfl_xor(s2, off);
  }
  const float mean = s * (1.f / 96.f);
  const float var  = s2 * (1.f / 96.f) - mean * mean;
  const float inv  = rsqrtf(var + 1e-5f);
  const float r0 = (v0 - mean) * inv * gamma[lane] + beta[lane];
  if (BF16OUT) {
    unsigned short* op = outb + (size_t)lt * CC;
    op[lane] = f2bf(r0);
    if (lane < 32)
      op[64 + lane] = f2bf((v1 - mean) * inv * gamma[64 + lane] + beta[64 + lane]);
  } else {
    float* op = outf + (size_t)lt * CC;
    const float r1 = (v1 - mean) * inv * gamma[64 + lane] + beta[64 + lane];
    op[lane] = r0;
    if (lane < 32) op[64 + lane] = r1;
  }
}

// ---------------------------------------------------------------- MFMA GEMM
// MODE 0: Cf= ; 1: Cb= bf16; 2: Cf+= ; 3: Cf+= scattered (window->image roll-back)
template<int MODE, int GELU>
__global__ __launch_bounds__(256) void mgemm(
    const unsigned short* __restrict__ A, const unsigned short* __restrict__ Bt,
    const float* __restrict__ bias, float* __restrict__ Cf,
    unsigned short* __restrict__ Cb, int N, int K, int shift)
{
  const int wv   = threadIdx.x >> 6;
  const int lane = threadIdx.x & 63;
  const int m0 = blockIdx.x * 64 + wv * 16;
  const int n0 = blockIdx.y * 32;
  const int row = lane & 15;
  const int ko  = (lane >> 4) * 8;
  f32x4 acc0 = {0.f, 0.f, 0.f, 0.f};
  f32x4 acc1 = {0.f, 0.f, 0.f, 0.f};
  const unsigned short* ap  = A  + (size_t)(m0 + row) * K + ko;
  const unsigned short* bp0 = Bt + (size_t)(n0 + row) * K + ko;
  const unsigned short* bp1 = Bt + (size_t)(n0 + 16 + row) * K + ko;
  for (int k0 = 0; k0 < K; k0 += 32) {
    const short8 af  = *(const short8*)(ap + k0);
    const short8 bf0 = *(const short8*)(bp0 + k0);
    const short8 bf1 = *(const short8*)(bp1 + k0);
    acc0 = __builtin_amdgcn_mfma_f32_16x16x32_bf16(af, bf0, acc0, 0, 0, 0);
    acc1 = __builtin_amdgcn_mfma_f32_16x16x32_bf16(af, bf1, acc1, 0, 0, 0);
  }
  const int cc  = lane & 15;
  const int cr0 = (lane >> 4) * 4;
  const float b0 = bias ? bias[n0 + cc] : 0.f;
  const float b1 = bias ? bias[n0 + 16 + cc] : 0.f;
  #pragma unroll
  for (int r = 0; r < 4; ++r) {
    const int m = m0 + cr0 + r;
    float v0 = acc0[r] + b0;
    float v1 = acc1[r] + b1;
    if (GELU) {
      v0 = 0.5f * v0 * (1.f + erff(v0 * 0.70710678118f));
      v1 = 0.5f * v1 * (1.f + erff(v1 * 0.70710678118f));
    }
    if (MODE == 0) {
      Cf[(size_t)m * N + n0 + cc]      = v0;
      Cf[(size_t)m * N + n0 + 16 + cc] = v1;
    } else if (MODE == 1) {
      Cb[(size_t)m * N + n0 + cc]      = f2bf(v0);
      Cb[(size_t)m * N + n0 + 16 + cc] = f2bf(v1);
    } else if (MODE == 2) {
      Cf[(size_t)m * N + n0 + cc]      += v0;
      Cf[(size_t)m * N + n0 + 16 + cc] += v1;
    } else {
      const int widx = m >> 6, n = m & 63;
      const int b = widx >> 4, wimg = widx & 15;
      const int rr2 = (wimg >> 2) * 8 + (n >> 3);
      const int cc2 = (wimg & 3) * 8 + (n & 7);
      const int p = (rr2 + shift) & 31, q = (cc2 + shift) & 31;
      const int t = (b << 10) + (p << 5) + q;
      Cf[(size_t)t * 96 + n0 + cc]      += v0;
      Cf[(size_t)t * 96 + n0 + 16 + cc] += v1;
    }
  }
}

// ---------------------------------------------------------------- Attention
// one block per window: 384 threads = 6 waves, wave = head.
__global__ __launch_bounds__(384) void attn_kernel(
    const unsigned short* __restrict__ qkv, const float* __restrict__ rpb_ld,
    unsigned short* __restrict__ out, int shift)
{
  const int widx = blockIdx.x;
  const int tid  = threadIdx.x;
  const int head = tid >> 6;
  const int lane = tid & 63;
  __shared__ float kv[64][200];
  __shared__ unsigned short qsh[64][104];
  __shared__ float bias_s[NH * 225];
  __shared__ int reg_s[64];
  const size_t gbase = (size_t)widx * 64 * 288;
  for (int i4 = tid; i4 < 64 * 48; i4 += 384) {
    const int row = i4 / 48, c4 = (i4 % 48) * 4;
    const ushort4v v = *(const ushort4v*)(qkv + gbase + (size_t)row * 288 + 96 + c4);
    kv[row][c4]     = bf2f(v.x);
    kv[row][c4 + 1] = bf2f(v.y);
    kv[row][c4 + 2] = bf2f(v.z);
    kv[row][c4 + 3] = bf2f(v.w);
  }
  for (int i4 = tid; i4 < 64 * 24; i4 += 384) {
    const int row = i4 / 24, c4 = (i4 % 24) * 4;
    *(ushort4v*)&qsh[row][c4] =
        *(const ushort4v*)(qkv + gbase + (size_t)row * 288 + c4);
  }
  for (int i = tid; i < NH * 225; i += 384) {
    const int h = i / 225, ii = i % 225;
    bias_s[i] = rpb_ld[ii * NH + h];
  }
  if (tid < 64) {
    const int wimg = widx & 15;
    const int h = (wimg >> 2) * 8 + (tid >> 3);
    const int w = (wimg & 3) * 8 + (tid & 7);
    reg_s[tid] = 3 * (h < 24 ? 0 : (h < 28 ? 1 : 2)) +
                     (w < 24 ? 0 : (w < 28 ? 1 : 2));
  }
  __syncthreads();

  const float* bias_h = bias_s + head * 225;
  float q[16];
  #pragma unroll
  for (int c = 0; c < 16; ++c) q[c] = bf2f(qsh[lane][head * 16 + c]);
  const int ih = lane >> 3, iw = lane & 7;
  const int myreg = reg_s[lane];
  float s[64];
  #pragma unroll
  for (int j = 0; j < 64; ++j) {
    const float4 k0 = *(const float4*)&kv[j][head * 16];
    const float4 k1 = *(const float4*)&kv[j][head * 16 + 4];
    const float4 k2 = *(const float4*)&kv[j][head * 16 + 8];
    const float4 k3 = *(const float4*)&kv[j][head * 16 + 12];
    float acc = 0.f;
    acc = fmaf(q[0],  k0.x, acc); acc = fmaf(q[1],  k0.y, acc);
    acc = fmaf(q[2],  k0.z, acc); acc = fmaf(q[3],  k0.w, acc);
    acc = fmaf(q[4],  k1.x, acc); acc = fmaf(q[5],  k1.y, acc);
    acc = fmaf(q[6],  k1.z, acc); acc = fmaf(q[7],  k1.w, acc);
    acc = fmaf(q[8],  k2.x, acc); acc = fmaf(q[9],  k2.y, acc);
    acc = fmaf(q[10], k2.z, acc); acc = fmaf(q[11], k2.w, acc);
    acc = fmaf(q[12], k3.x, acc); acc = fmaf(q[13], k3.y, acc);
    acc = fmaf(q[14], k3.z, acc); acc = fmaf(q[15], k3.w, acc);
    const int idx = (ih - (j >> 3) + 7) * 15 + (iw - (j & 7) + 7);
    acc = acc * 0.25f + bias_h[idx];
    if (shift && reg_s[j] != myreg) acc -= 100.f;
    s[j] = acc;
  }
  float m = s[0];
  #pragma unroll
  for (int j = 1; j < 64; ++j) m = fmaxf(m, s[j]);
  float sum = 0.f;
  #pragma unroll
  for (int j = 0; j < 64; ++j) { const float p = __expf(s[j] - m); s[j] = p; sum += p; }
  const float inv = 1.f / sum;
  float o[16] = {};
  #pragma unroll
  for (int j = 0; j < 64; ++j) {
    const float p = s[j] * inv;
    const float4 v0 = *(const float4*)&kv[j][96 + head * 16];
    const float4 v1 = *(const float4*)&kv[j][96 + head * 16 + 4];
    const float4 v2 = *(const float4*)&kv[j][96 + head * 16 + 8];
    const float4 v3 = *(const float4*)&kv[j][96 + head * 16 + 12];
    o[0]  = fmaf(p, v0.x, o[0]);  o[1]  = fmaf(p, v0.y, o[1]);
    o[2]  = fmaf(p, v0.z, o[2]);  o[3]  = fmaf(p, v0.w, o[3]);
    o[4]  = fmaf(p, v1.x, o[4]);  o[5]  = fmaf(p, v1.y, o[5]);
    o[6]  = fmaf(p, v1.z, o[6]);  o[7]  = fmaf(p, v1.w, o[7]);
    o[8]  = fmaf(p, v2.x, o[8]);  o[9]  = fmaf(p, v2.y, o[9]);
    o[10] = fmaf(p, v2.z, o[10]); o[11] = fmaf(p, v2.w, o[11]);
    o[12] = fmaf(p, v3.x, o[12]); o[13] = fmaf(p, v3.y, o[13]);
    o[14] = fmaf(p, v3.z, o[14]); o[15] = fmaf(p, v3.w, o[15]);
  }
  unsigned short* op = out + ((size_t)widx * 64 + lane) * CC + head * 16;
  short8 o0, o1;
  #pragma unroll
  for (int i = 0; i < 8; ++i) {
    o0[i] = (short)f2bf(o[i]);
    o1[i] = (short)f2bf(o[8 + i]);
  }
  *(short8*)(op) = o0;
  *(short8*)(op + 8) = o1;
}

// ---------------------------------------------------------------- copy
__global__ __launch_bounds__(256) void copy_kernel(
    float* __restrict__ dst, const float* __restrict__ src)
{
  const int idx = blockIdx.x * 256 + threadIdx.x;
  dst[idx] = src[idx];
}

// ---------------------------------------------------------------- conv 3x3 96->96, MFMA implicit GEMM
// wt: [9][oc=96][ic=96] bf16. resid/out may alias (same-index) — no __restrict__.
__global__ __launch_bounds__(256) void conv96m_kernel(
    const float* __restrict__ x, const unsigned short* __restrict__ wt,
    const float* __restrict__ bias, const float* resid, float* out)
{
  const int blk = blockIdx.x;
  const int b = blk >> 4, th = (blk >> 2) & 3, tw = blk & 3;
  const int h0 = th * 8, w0 = tw * 8;
  __shared__ unsigned short patch[100][104];   // 10x10 pixels x 96 ic (bf16)
  for (int idx = threadIdx.x; idx < 100 * 24; idx += 256) {
    const int pp = idx / 24, c4 = (idx % 24) * 4;
    const int ph = pp / 10, pw = pp % 10;
    const int hh = h0 + ph - 1, ww = w0 + pw - 1;
    float4 v = {0.f, 0.f, 0.f, 0.f};
    if ((unsigned)hh < 32u && (unsigned)ww < 32u)
      v = *(const float4*)&x[(((size_t)b * 32 + hh) * 32 + ww) * 96 + c4];
    ushort4v o;
    o.x = f2bf(v.x); o.y = f2bf(v.y); o.z = f2bf(v.z); o.w = f2bf(v.w);
    *(ushort4v*)&patch[pp][c4] = o;
  }
  __syncthreads();
  const int wv = threadIdx.x >> 6, lane = threadIdx.x & 63;
  const int m0 = wv * 16;
  const int arow = lane & 15;
  const int ko  = (lane >> 4) * 8;
  const int px = m0 + arow;
  const int ph_ = px >> 3, pw_ = px & 7;
  f32x4 acc[6];
  #pragma unroll
  for (int i = 0; i < 6; ++i) acc[i] = (f32x4){0.f, 0.f, 0.f, 0.f};
  #pragma unroll
  for (int kh = 0; kh < 3; ++kh)
    #pragma unroll
    for (int kw = 0; kw < 3; ++kw) {
      const unsigned short* wbase = wt + (size_t)(kh * 3 + kw) * 9216;
      const unsigned short* prow = &patch[(ph_ + kh) * 10 + (pw_ + kw)][ko];
      #pragma unroll
      for (int k0 = 0; k0 < 96; k0 += 32) {
        const short8 af = *(const short8*)(prow + k0);
        #pragma unroll
        for (int nt = 0; nt < 6; ++nt) {
          const short8 bf = *(const short8*)(wbase + (size_t)(nt * 16 + arow) * 96 + ko + k0);
          acc[nt] = __builtin_amdgcn_mfma_f32_16x16x32_bf16(af, bf, acc[nt], 0, 0, 0);
        }
      }
    }
  const int cc = lane & 15;
  const int cr0 = (lane >> 4) * 4;
  #pragma unroll
  for (int nt = 0; nt < 6; ++nt) {
    const int oc = nt * 16 + cc;
    const float bz = bias[oc];
    #pragma unroll
    for (int r = 0; r < 4; ++r) {
      const int p = m0 + cr0 + r;
      const int h = p >> 3, w = p & 7;
      const size_t t = (((size_t)b * 32 + h0 + h) * 32 + (w0 + w));
      float v = acc[nt][r] + bz;
      if (resid) v += resid[t * 96 + oc];
      out[t * 96 + oc] = v;
    }
  }
}

// ---------------------------------------------------------------- conv stem 4->96
__global__ __launch_bounds__(256) void conv_first_kernel(
    const float* __restrict__ es, const float* __restrict__ jp,
    const float* __restrict__ wgt, const float* __restrict__ bias,
    float* __restrict__ xf)
{
  const int idx = blockIdx.x * 256 + threadIdx.x;
  const int oc = idx % 96;
  const int pos = idx / 96;
  const int w = pos % 32, hp = (pos / 32) % 32, b = pos / 1024;
  float acc = bias[oc];
  for (int kh = 0; kh < 3; ++kh) {
    const int hh = hp + kh - 1;
    if ((unsigned)hh >= 32u) continue;
    for (int kw = 0; kw < 3; ++kw) {
      const int ww = w + kw - 1;
      if ((unsigned)ww >= 32u) continue;
      const size_t sp = ((size_t)b * 2 * 32 + hh) * 32 + ww;
      const float i0 = es[sp];
      const float i1 = es[sp + 1024];
      const float i2 = jp[sp];
      const float i3 = jp[sp + 1024];
      const float* wr = wgt + (size_t)((kh * 3 + kw) * 4) * 96 + oc;
      acc = fmaf(i0, wr[0], acc);
      acc = fmaf(i1, wr[96], acc);
      acc = fmaf(i2, wr[192], acc);
      acc = fmaf(i3, wr[288], acc);
    }
  }
  xf[idx] = acc;
}

// ---------------------------------------------------------------- conv tail 96->2
__global__ __launch_bounds__(256) void conv_last_kernel(
    const float* __restrict__ res, const float* __restrict__ wgt,
    const float* __restrict__ bias, float* __restrict__ out)
{
  const int idx = blockIdx.x * 256 + threadIdx.x;
  const int oc = idx % 2;
  const int pos = idx / 2;
  const int w = pos % 32, hp = (pos / 32) % 32, b = pos / 1024;
  float acc = bias[oc];
  for (int kh = 0; kh < 3; ++kh) {
    const int hh = hp + kh - 1;
    if ((unsigned)hh >= 32u) continue;
    for (int kw = 0; kw < 3; ++kw) {
      const int ww = w + kw - 1;
      if ((unsigned)ww >= 32u) continue;
      const float* pr = res + (((size_t)b * 32 + hh) * 32 + ww) * 96;
      const float* wr = wgt + (size_t)((kh * 3 + kw) * 96) * 2 + oc;
      #pragma unroll 8
      for (int ic = 0; ic < 96; ++ic)
        acc = fmaf(pr[ic], wr[ic * 2], acc);
    }
  }
  out[(((size_t)b * 2 + oc) * 32 + hp) * 32 + w] = acc;
}

// ---------------------------------------------------------------- host
extern "C" void kernel_launch(void* const* d_in, const int* in_sizes, int n_in,
                              void* d_out, int out_size, void* d_ws, size_t ws_size,
                              hipStream_t stream)
{
  const int fill_grid = (out_size + 255) / 256;

  if (n_in != 27) {
    fill_kernel<<<fill_grid, 256, 0, stream>>>((float*)d_out, 200.0f + (float)n_in, out_size);
    return;
  }
  static const int expected_sizes[27] = {
    131072, 131072, 3456, 96, 96, 96, 2304, 2304, 663552, 6912,
    221184, 2304, 32400, 2304, 2304, 884736, 9216, 884736, 2304,
    331776, 384, 96, 96, 82944, 96, 1728, 2
  };
  for (int i = 0; i < 27; ++i) {
    if (in_sizes[i] != expected_sizes[i]) {
      fill_kernel<<<fill_grid, 256, 0, stream>>>((float*)d_out, 300.0f + (float)i, out_size);
      return;
    }
  }
  if (out_size != 131072) {
    fill_kernel<<<fill_grid, 256, 0, stream>>>((float*)d_out, 400.0f, out_size);
    return;
  }
  const uintptr_t raw = (uintptr_t)d_ws;
  const uintptr_t alignedp = (raw + 255) & ~(uintptr_t)255;
  const size_t ws_avail_bytes = (ws_size > (alignedp - raw)) ? ws_size - (alignedp - raw) : 0;
  const size_t avail = ws_avail_bytes / 4;   // floats
  const size_t WBUF_F = 1534464;             // all bf16 weights (gemm + conv), float units
  const size_t floor_need = 2 * TC + WBUF_F + (size_t)1024 * 240;
  if (avail < floor_need) {
    fill_kernel<<<fill_grid, 256, 0, stream>>>((float*)d_out,
        100.0f + (float)(ws_size >> 20), out_size);
    return;
  }

  const float* es      = (const float*)d_in[0];
  const float* jp      = (const float*)d_in[1];
  const float* cf_w    = (const float*)d_in[2];
  const float* cf_b    = (const float*)d_in[3];
  const float* pe_s    = (const float*)d_in[4];
  const float* pe_b    = (const float*)d_in[5];
  const float* n1_s    = (const float*)d_in[6];
  const float* n1_b    = (const float*)d_in[7];
  const float* qkv_w   = (const float*)d_in[8];
  const float* qkv_b   = (const float*)d_in[9];
  const float* proj_w  = (const float*)d_in[10];
  const float* proj_b  = (const float*)d_in[11];
  const float* rpb     = (const float*)d_in[12];
  const float* n2_s    = (const float*)d_in[13];
  const float* n2_b    = (const float*)d_in[14];
  const float* fc1_w   = (const float*)d_in[15];
  const float* fc1_b   = (const float*)d_in[16];
  const float* fc2_w   = (const float*)d_in[17];
  const float* fc2_b   = (const float*)d_in[18];
  const float* rstb_w  = (const float*)d_in[19];
  const float* rstb_b  = (const float*)d_in[20];
  const float* nf_s    = (const float*)d_in[21];
  const float* nf_b    = (const float*)d_in[22];
  const float* body_w  = (const float*)d_in[23];
  const float* body_b  = (const float*)d_in[24];
  const float* last_w  = (const float*)d_in[25];
  const float* last_b  = (const float*)d_in[26];

  float* x = (float*)alignedp;
  float* r = x + TC;
  unsigned short* wq  = (unsigned short*)(r + TC);   // [24][288][96] bf16
  unsigned short* wp  = wq + 663552;                 // [24][96][96]
  unsigned short* w1  = wp + 221184;                 // [24][384][96]
  unsigned short* w2  = w1 + 884736;                 // [24][96][384]
  unsigned short* wcr = w2 + 884736;                 // [4][9][96][96] conv rstb
  unsigned short* wcb = wcr + 331776;                // [9][96][96] conv body
  float* chunk_base = (float*)(wcb + 82944);

  int Tc = T_TOK;
  while (Tc > 1024 && 2 * TC + WBUF_F + (size_t)Tc * 240 > avail) Tc >>= 1;
  const int cn = T_TOK / Tc;
  unsigned short* a_b = (unsigned short*)chunk_base; // [Tc][96] bf16
  unsigned short* g_b = a_b + (size_t)Tc * 96;       // [Tc][384] bf16

  const int grid_tc = (int)(TC / 256);
  const int grid_lf = T_TOK / 4;
  const int grid_lc = Tc / 4;

  // weight convert+transpose
  wconv_kernel<<<dim3((96 * 288 + 255) / 256, 24), 256, 0, stream>>>(qkv_w, wq, 96, 288);
  wconv_kernel<<<dim3((96 * 96 + 255) / 256, 24), 256, 0, stream>>>(proj_w, wp, 96, 96);
  wconv_kernel<<<dim3((96 * 384 + 255) / 256, 24), 256, 0, stream>>>(fc1_w, w1, 96, 384);
  wconv_kernel<<<dim3((384 * 96 + 255) / 256, 24), 256, 0, stream>>>(fc2_w, w2, 384, 96);
  wconv_conv_kernel<<<(331776 + 255) / 256, 256, 0, stream>>>(rstb_w, wcr, 331776);
  wconv_conv_kernel<<<(82944 + 255) / 256, 256, 0, stream>>>(body_w, wcb, 82944);

  // stem: x = LN_pe(conv_first(inputs)), LN in place
  conv_first_kernel<<<grid_tc, 256, 0, stream>>>(es, jp, cf_w, cf_b, x);
  ln_kernel<0><<<grid_lf, 256, 0, stream>>>(x, pe_s, pe_b, nullptr, x, -1, 0);

  float* xb = x;
  float* rb = r;
  for (int l = 0; l < NL; ++l) {
    copy_kernel<<<grid_tc, 256, 0, stream>>>(rb, xb);
    for (int d = 0; d < ND; ++d) {
      const int ld = l * ND + d;
      const int shift = (d & 1) ? 4 : 0;
      for (int c = 0; c < cn; ++c) {
        const size_t off = (size_t)c * Tc * CC;
        const int t0 = c * Tc;
        ln_kernel<1><<<grid_lc, 256, 0, stream>>>(xb, n1_s + ld * CC, n1_b + ld * CC,
                                                  a_b, nullptr, shift, t0);
        { dim3 g(Tc / 64, 288 / 32);
          mgemm<1, 0><<<g, 256, 0, stream>>>(a_b, wq + (size_t)ld * 288 * 96,
              qkv_b + (size_t)ld * 288, nullptr, g_b, 288, 96, 0); }
        attn_kernel<<<Tc / 64, 384, 0, stream>>>(
            g_b, rpb + (size_t)ld * 225 * NH, a_b, shift);
        { dim3 g(Tc / 64, 96 / 32);
          mgemm<3, 0><<<g, 256, 0, stream>>>(a_b, wp + (size_t)ld * 96 * 96,
              proj_b + (size_t)ld * 96, xb + off, nullptr, 96, 96, shift); }
        ln_kernel<1><<<grid_lc, 256, 0, stream>>>(xb, n2_s + ld * CC, n2_b + ld * CC,
                                                  a_b, nullptr, -1, t0);
        { dim3 g(Tc / 64, 384 / 32);
          mgemm<1, 1><<<g, 256, 0, stream>>>(a_b, w1 + (size_t)ld * 384 * 96,
              fc1_b + (size_t)ld * 384, nullptr, g_b, 384, 96, 0); }
        { dim3 g(Tc / 64, 96 / 32);
          mgemm<2, 0><<<g, 256, 0, stream>>>(g_b, w2 + (size_t)ld * 96 * 384,
              fc2_b + (size_t)ld * 96, xb + off, nullptr, 96, 384, 0); }
      }
    }
    // rb = conv(xb) + rb (MFMA implicit GEMM), then rb becomes x
    conv96m_kernel<<<1024, 256, 0, stream>>>(xb, wcr + (size_t)l * 9 * 9216,
                                             rstb_b + (size_t)l * CC, rb, rb);
    float* sw = xb; xb = rb; rb = sw;
  }
  // tail
  ln_kernel<0><<<grid_lf, 256, 0, stream>>>(xb, nf_s, nf_b, nullptr, rb, -1, 0);
  conv_first_kernel<<<grid_tc, 256, 0, stream>>>(es, jp, cf_w, cf_b, xb);
  conv96m_kernel<<<1024, 256, 0, stream>>>(rb, wcb, body_b, xb, xb);
  conv_last_kernel<<<(BB * 32 * 32 * 2) / 256, 256, 0, stream>>>(xb, last_w, last_b, (float*)d_out);
}

// Round 13
// 4815.050 us; speedup vs baseline: 2.1251x; 1.1430x over previous
//
#include <hip/hip_runtime.h>
#include <hip/hip_bf16.h>
#include <cstddef>
#include <cstdint>

#define BB 64
#define HH 32
#define WW_ 32
#define CC 96
#define WS 8
#define NH 6
#define NL 4
#define ND 6
#define T_TOK (BB*HH*WW_)      // 65536 tokens
#define TC ((size_t)T_TOK*CC)  // 6291456 floats

typedef long long ll;
typedef __attribute__((ext_vector_type(8))) short short8;
typedef __attribute__((ext_vector_type(4))) float f32x4;
typedef __attribute__((ext_vector_type(4))) unsigned short ushort4v;

// Harness-named kernel symbol.
__global__ void JNetSwinIR_41034117546277_kernel() {}

__device__ __forceinline__ unsigned short f2bf(float f) {
  unsigned u = __float_as_uint(f);
  unsigned r = (u + 0x7FFF + ((u >> 16) & 1)) >> 16;
  return (unsigned short)r;
}
__device__ __forceinline__ float bf2f(unsigned short h) {
  return __uint_as_float(((unsigned)h) << 16);
}

// ---------------------------------------------------------------- diagnostic fill
__global__ __launch_bounds__(256) void fill_kernel(float* p, float v, int n)
{
  const int idx = blockIdx.x * 256 + threadIdx.x;
  if (idx < n) p[idx] = v;
}

// ---------------------------------------------------------------- weight fp32->bf16 transpose
// W [24][K][N] fp32 -> Wt [24][N][K] bf16
__global__ __launch_bounds__(256) void wconv_kernel(
    const float* __restrict__ W, unsigned short* __restrict__ Wt, int K, int N)
{
  const int ld = blockIdx.y;
  const int idx = blockIdx.x * 256 + threadIdx.x;
  if (idx >= K * N) return;
  const int k = idx / N, n = idx % N;
  Wt[(size_t)ld * K * N + (size_t)n * K + k] = f2bf(W[(size_t)ld * K * N + idx]);
}

// conv weights [L][3][3][ic=96][oc=96] fp32 -> [L][9][oc][ic] bf16
__global__ __launch_bounds__(256) void wconv_conv_kernel(
    const float* __restrict__ W, unsigned short* __restrict__ Wt, int total)
{
  const int idx = blockIdx.x * 256 + threadIdx.x;
  if (idx >= total) return;
  const int l9 = idx / 9216;
  const int rest = idx % 9216;
  const int oc = rest / 96, ic = rest % 96;
  Wt[idx] = f2bf(W[(size_t)(l9 * 96 + ic) * 96 + oc]);
}

// ---------------------------------------------------------------- LayerNorm fp32 (stem/tail)
__global__ __launch_bounds__(256) void ln_fp32_kernel(
    const float* __restrict__ x, const float* __restrict__ gamma,
    const float* __restrict__ beta, float* __restrict__ out)
{
  const int wave = threadIdx.x >> 6;
  const int lane = threadIdx.x & 63;
  const int t = blockIdx.x * 4 + wave;
  const float* xp = x + (size_t)t * CC;
  const float v0 = xp[lane];
  const float v1 = (lane < 32) ? xp[64 + lane] : 0.f;
  float s = v0 + v1, s2 = v0 * v0 + v1 * v1;
  #pragma unroll
  for (int off = 32; off; off >>= 1) {
    s  += __shfl_xor(s,  off);
    s2 += __shfl_xor(s2, off);
  }
  const float mean = s * (1.f / 96.f);
  const float var  = s2 * (1.f / 96.f) - mean * mean;
  const float inv  = rsqrtf(var + 1e-5f);
  float* op = out + (size_t)t * CC;
  const float r0 = (v0 - mean) * inv * gamma[lane] + beta[lane];
  const float r1 = (v1 - mean) * inv * gamma[64 + lane] + beta[64 + lane];
  op[lane] = r0;
  if (lane < 32) op[64 + lane] = r1;
}

// ---------------------------------------------------------------- fused swin attention half
// one block per window. 384 thr = 6 waves (wave = head).
// LN1(rolled x) -> qkv MFMA -> attention -> proj MFMA -> x += (scatter, bijective)
__global__ __launch_bounds__(384) void swin_attn_fused(
    float* x, const float* __restrict__ n1s, const float* __restrict__ n1b,
    const unsigned short* __restrict__ wq_ld, const float* __restrict__ qkvb,
    const float* __restrict__ rpb_ld,
    const unsigned short* __restrict__ wp_ld, const float* __restrict__ projb,
    int shift)
{
  const int widx = blockIdx.x;
  const int tid  = threadIdx.x;
  const int wv   = tid >> 6;      // 0..5
  const int lane = tid & 63;

  __shared__ unsigned short a[64][104];    // LN1 out / attn out (bf16)
  __shared__ float          kk[64][100];   // K fp32
  __shared__ unsigned short vv[64][104];   // V bf16
  __shared__ unsigned short qt[64][112];   // Q bf16 token-major
  __shared__ float bias_s[NH * 225];
  __shared__ int   reg_s[64];
  __shared__ int   st_s[64];               // window token -> image token

  if (tid < 64) {
    const int wimg = widx & 15;
    const int h = (wimg >> 2) * 8 + (tid >> 3);
    const int w = (wimg & 3) * 8 + (tid & 7);
    reg_s[tid] = 3 * (h < 24 ? 0 : (h < 28 ? 1 : 2)) +
                     (w < 24 ? 0 : (w < 28 ? 1 : 2));
    const int b = widx >> 4;
    const int p = (h + shift) & 31, q = (w + shift) & 31;
    st_s[tid] = (b << 10) + (p << 5) + q;
  }
  for (int i = tid; i < NH * 225; i += 384) {
    const int hh = i / 225, ii = i % 225;
    bias_s[i] = rpb_ld[ii * NH + hh];
  }
  __syncthreads();

  // phase 1: LN1 (each wave handles tokens wv, wv+6, ...)
  for (int t = wv; t < 64; t += 6) {
    const float* xp = x + (size_t)st_s[t] * CC;
    const float v0 = xp[lane];
    const float v1 = (lane < 32) ? xp[64 + lane] : 0.f;
    float s = v0 + v1, s2 = v0 * v0 + v1 * v1;
    #pragma unroll
    for (int off = 32; off; off >>= 1) {
      s  += __shfl_xor(s,  off);
      s2 += __shfl_xor(s2, off);
    }
    const float mean = s * (1.f / 96.f);
    const float var  = s2 * (1.f / 96.f) - mean * mean;
    const float inv  = rsqrtf(var + 1e-5f);
    a[t][lane] = f2bf((v0 - mean) * inv * n1s[lane] + n1b[lane]);
    if (lane < 32)
      a[t][64 + lane] = f2bf((v1 - mean) * inv * n1s[64 + lane] + n1b[64 + lane]);
  }
  __syncthreads();

  // phase 2: qkv MFMA — wave h computes its head's q,k,v (3 col-tiles x 4 row-tiles)
  {
    const int row = lane & 15;
    const int ko  = (lane >> 4) * 8;
    const int cc  = lane & 15;
    const int cr0 = (lane >> 4) * 4;
    #pragma unroll
    for (int out3 = 0; out3 < 3; ++out3) {
      const int n0 = out3 * 96 + wv * 16;
      const unsigned short* bp = wq_ld + (size_t)(n0 + row) * 96 + ko;
      const float bz = qkvb[n0 + cc];
      #pragma unroll
      for (int rt = 0; rt < 4; ++rt) {
        f32x4 acc = {0.f, 0.f, 0.f, 0.f};
        const unsigned short* ap = &a[rt * 16 + row][ko];
        #pragma unroll
        for (int k0 = 0; k0 < 96; k0 += 32) {
          const short8 af = *(const short8*)(ap + k0);
          const short8 bf = *(const short8*)(bp + k0);
          acc = __builtin_amdgcn_mfma_f32_16x16x32_bf16(af, bf, acc, 0, 0, 0);
        }
        #pragma unroll
        for (int r = 0; r < 4; ++r) {
          const int tok = rt * 16 + cr0 + r;
          const float v = acc[r] + bz;
          if (out3 == 0)      qt[tok][wv * 16 + cc] = f2bf(v);
          else if (out3 == 1) kk[tok][wv * 16 + cc] = v;
          else                vv[tok][wv * 16 + cc] = f2bf(v);
        }
      }
    }
  }
  __syncthreads();

  // phase 3: attention — wave = head, lane = query token
  const int head = wv;
  float q[16];
  {
    const short8 q0 = *(const short8*)&qt[lane][head * 16];
    const short8 q1 = *(const short8*)&qt[lane][head * 16 + 8];
    #pragma unroll
    for (int i = 0; i < 8; ++i) {
      q[i]     = bf2f((unsigned short)q0[i]);
      q[8 + i] = bf2f((unsigned short)q1[i]);
    }
  }
  const float* bias_h = bias_s + head * 225;
  const int ih = lane >> 3, iw = lane & 7;
  const int myreg = reg_s[lane];
  float s[64];
  #pragma unroll
  for (int j = 0; j < 64; ++j) {
    const float4 k0 = *(const float4*)&kk[j][head * 16];
    const float4 k1 = *(const float4*)&kk[j][head * 16 + 4];
    const float4 k2 = *(const float4*)&kk[j][head * 16 + 8];
    const float4 k3 = *(const float4*)&kk[j][head * 16 + 12];
    float acc = 0.f;
    acc = fmaf(q[0],  k0.x, acc); acc = fmaf(q[1],  k0.y, acc);
    acc = fmaf(q[2],  k0.z, acc); acc = fmaf(q[3],  k0.w, acc);
    acc = fmaf(q[4],  k1.x, acc); acc = fmaf(q[5],  k1.y, acc);
    acc = fmaf(q[6],  k1.z, acc); acc = fmaf(q[7],  k1.w, acc);
    acc = fmaf(q[8],  k2.x, acc); acc = fmaf(q[9],  k2.y, acc);
    acc = fmaf(q[10], k2.z, acc); acc = fmaf(q[11], k2.w, acc);
    acc = fmaf(q[12], k3.x, acc); acc = fmaf(q[13], k3.y, acc);
    acc = fmaf(q[14], k3.z, acc); acc = fmaf(q[15], k3.w, acc);
    const int idx = (ih - (j >> 3) + 7) * 15 + (iw - (j & 7) + 7);
    acc = acc * 0.25f + bias_h[idx];
    if (shift && reg_s[j] != myreg) acc -= 100.f;
    s[j] = acc;
  }
  float m = s[0];
  #pragma unroll
  for (int j = 1; j < 64; ++j) m = fmaxf(m, s[j]);
  float sum = 0.f;
  #pragma unroll
  for (int j = 0; j < 64; ++j) { const float p = __expf(s[j] - m); s[j] = p; sum += p; }
  const float inv = 1.f / sum;
  float o[16] = {};
  #pragma unroll
  for (int j = 0; j < 64; ++j) {
    const float p = s[j] * inv;
    const short8 v0 = *(const short8*)&vv[j][head * 16];
    const short8 v1 = *(const short8*)&vv[j][head * 16 + 8];
    #pragma unroll
    for (int i = 0; i < 8; ++i) {
      o[i]     = fmaf(p, bf2f((unsigned short)v0[i]), o[i]);
      o[8 + i] = fmaf(p, bf2f((unsigned short)v1[i]), o[8 + i]);
    }
  }
  // phase 4: write attn output into a (disjoint from kk/vv/qt; a-reads done at phase-2 barrier)
  {
    short8 o0, o1;
    #pragma unroll
    for (int i = 0; i < 8; ++i) {
      o0[i] = (short)f2bf(o[i]);
      o1[i] = (short)f2bf(o[8 + i]);
    }
    *(short8*)&a[lane][head * 16]     = o0;
    *(short8*)&a[lane][head * 16 + 8] = o1;
  }
  __syncthreads();

  // phase 5: proj MFMA + scatter residual-add (wave wv -> cols [wv*16, wv*16+16))
  {
    const int row = lane & 15;
    const int ko  = (lane >> 4) * 8;
    const int cc  = lane & 15;
    const int cr0 = (lane >> 4) * 4;
    const int n0 = wv * 16;
    const unsigned short* bp = wp_ld + (size_t)(n0 + row) * 96 + ko;
    const float bz = projb[n0 + cc];
    #pragma unroll
    for (int rt = 0; rt < 4; ++rt) {
      f32x4 acc = {0.f, 0.f, 0.f, 0.f};
      const unsigned short* ap = &a[rt * 16 + row][ko];
      #pragma unroll
      for (int k0 = 0; k0 < 96; k0 += 32) {
        const short8 af = *(const short8*)(ap + k0);
        const short8 bf = *(const short8*)(bp + k0);
        acc = __builtin_amdgcn_mfma_f32_16x16x32_bf16(af, bf, acc, 0, 0, 0);
      }
      #pragma unroll
      for (int r = 0; r < 4; ++r) {
        const int tok = rt * 16 + cr0 + r;
        x[(size_t)st_s[tok] * CC + n0 + cc] += acc[r] + bz;
      }
    }
  }
}

// ---------------------------------------------------------------- fused swin MLP half
// one block per 64 tokens. 256 thr = 4 waves.
// LN2 -> fc1+GELU (hidden in LDS) -> fc2 -> x +=
__global__ __launch_bounds__(256) void swin_mlp_fused(
    float* x, const float* __restrict__ n2s, const float* __restrict__ n2b,
    const unsigned short* __restrict__ w1_ld, const float* __restrict__ f1b,
    const unsigned short* __restrict__ w2_ld, const float* __restrict__ f2b)
{
  const int tbase = blockIdx.x * 64;
  const int tid  = threadIdx.x;
  const int wv   = tid >> 6;      // 0..3
  const int lane = tid & 63;
  __shared__ unsigned short a[64][104];    // LN2 out bf16
  __shared__ unsigned short hbuf[64][392]; // fc1 out bf16

  for (int t = wv; t < 64; t += 4) {
    const float* xp = x + (size_t)(tbase + t) * CC;
    const float v0 = xp[lane];
    const float v1 = (lane < 32) ? xp[64 + lane] : 0.f;
    float s = v0 + v1, s2 = v0 * v0 + v1 * v1;
    #pragma unroll
    for (int off = 32; off; off >>= 1) {
      s  += __shfl_xor(s,  off);
      s2 += __shfl_xor(s2, off);
    }
    const float mean = s * (1.f / 96.f);
    const float var  = s2 * (1.f / 96.f) - mean * mean;
    const float inv  = rsqrtf(var + 1e-5f);
    a[t][lane] = f2bf((v0 - mean) * inv * n2s[lane] + n2b[lane]);
    if (lane < 32)
      a[t][64 + lane] = f2bf((v1 - mean) * inv * n2s[64 + lane] + n2b[64 + lane]);
  }
  __syncthreads();

  // fc1 + GELU: wave wv computes hidden cols [wv*96, wv*96+96)
  {
    const int row = lane & 15;
    const int ko  = (lane >> 4) * 8;
    const int cc  = lane & 15;
    const int cr0 = (lane >> 4) * 4;
    #pragma unroll
    for (int nt = 0; nt < 6; ++nt) {
      const int n0 = wv * 96 + nt * 16;
      const unsigned short* bp = w1_ld + (size_t)(n0 + row) * 96 + ko;
      const float bz = f1b[n0 + cc];
      #pragma unroll
      for (int rt = 0; rt < 4; ++rt) {
        f32x4 acc = {0.f, 0.f, 0.f, 0.f};
        const unsigned short* ap = &a[rt * 16 + row][ko];
        #pragma unroll
        for (int k0 = 0; k0 < 96; k0 += 32) {
          const short8 af = *(const short8*)(ap + k0);
          const short8 bf = *(const short8*)(bp + k0);
          acc = __builtin_amdgcn_mfma_f32_16x16x32_bf16(af, bf, acc, 0, 0, 0);
        }
        #pragma unroll
        for (int r = 0; r < 4; ++r) {
          float v = acc[r] + bz;
          v = 0.5f * v * (1.f + erff(v * 0.70710678118f));
          hbuf[rt * 16 + cr0 + r][n0 + cc] = f2bf(v);
        }
      }
    }
  }
  __syncthreads();

  // fc2 + residual: wave wv computes rows [wv*16, wv*16+16)
  {
    const int row = lane & 15;
    const int ko  = (lane >> 4) * 8;
    const int cc  = lane & 15;
    const int cr0 = (lane >> 4) * 4;
    #pragma unroll
    for (int nt = 0; nt < 6; ++nt) {
      const int n0 = nt * 16;
      const unsigned short* bp = w2_ld + (size_t)(n0 + row) * 384 + ko;
      const float bz = f2b[n0 + cc];
      f32x4 acc = {0.f, 0.f, 0.f, 0.f};
      const unsigned short* ap = &hbuf[wv * 16 + row][ko];
      #pragma unroll
      for (int k0 = 0; k0 < 384; k0 += 32) {
        const short8 af = *(const short8*)(ap + k0);
        const short8 bf = *(const short8*)(bp + k0);
        acc = __builtin_amdgcn_mfma_f32_16x16x32_bf16(af, bf, acc, 0, 0, 0);
      }
      #pragma unroll
      for (int r = 0; r < 4; ++r) {
        const int tok = tbase + wv * 16 + cr0 + r;
        x[(size_t)tok * CC + n0 + cc] += acc[r] + bz;
      }
    }
  }
}

// ---------------------------------------------------------------- copy
__global__ __launch_bounds__(256) void copy_kernel(
    float* __restrict__ dst, const float* __restrict__ src)
{
  const int idx = blockIdx.x * 256 + threadIdx.x;
  dst[idx] = src[idx];
}

// ---------------------------------------------------------------- conv 3x3 96->96, MFMA implicit GEMM
__global__ __launch_bounds__(256) void conv96m_kernel(
    const float* __restrict__ x, const unsigned short* __restrict__ wt,
    const float* __restrict__ bias, const float* resid, float* out)
{
  const int blk = blockIdx.x;
  const int b = blk >> 4, th = (blk >> 2) & 3, tw = blk & 3;
  const int h0 = th * 8, w0 = tw * 8;
  __shared__ unsigned short patch[100][104];
  for (int idx = threadIdx.x; idx < 100 * 24; idx += 256) {
    const int pp = idx / 24, c4 = (idx % 24) * 4;
    const int ph = pp / 10, pw = pp % 10;
    const int hh = h0 + ph - 1, ww = w0 + pw - 1;
    float4 v = {0.f, 0.f, 0.f, 0.f};
    if ((unsigned)hh < 32u && (unsigned)ww < 32u)
      v = *(const float4*)&x[(((size_t)b * 32 + hh) * 32 + ww) * 96 + c4];
    ushort4v o;
    o.x = f2bf(v.x); o.y = f2bf(v.y); o.z = f2bf(v.z); o.w = f2bf(v.w);
    *(ushort4v*)&patch[pp][c4] = o;
  }
  __syncthreads();
  const int wv = threadIdx.x >> 6, lane = threadIdx.x & 63;
  const int m0 = wv * 16;
  const int arow = lane & 15;
  const int ko  = (lane >> 4) * 8;
  const int px = m0 + arow;
  const int ph_ = px >> 3, pw_ = px & 7;
  f32x4 acc[6];
  #pragma unroll
  for (int i = 0; i < 6; ++i) acc[i] = (f32x4){0.f, 0.f, 0.f, 0.f};
  #pragma unroll
  for (int kh = 0; kh < 3; ++kh)
    #pragma unroll
    for (int kw = 0; kw < 3; ++kw) {
      const unsigned short* wbase = wt + (size_t)(kh * 3 + kw) * 9216;
      const unsigned short* prow = &patch[(ph_ + kh) * 10 + (pw_ + kw)][ko];
      #pragma unroll
      for (int k0 = 0; k0 < 96; k0 += 32) {
        const short8 af = *(const short8*)(prow + k0);
        #pragma unroll
        for (int nt = 0; nt < 6; ++nt) {
          const short8 bf = *(const short8*)(wbase + (size_t)(nt * 16 + arow) * 96 + ko + k0);
          acc[nt] = __builtin_amdgcn_mfma_f32_16x16x32_bf16(af, bf, acc[nt], 0, 0, 0);
        }
      }
    }
  const int cc = lane & 15;
  const int cr0 = (lane >> 4) * 4;
  #pragma unroll
  for (int nt = 0; nt < 6; ++nt) {
    const int oc = nt * 16 + cc;
    const float bz = bias[oc];
    #pragma unroll
    for (int r = 0; r < 4; ++r) {
      const int p = m0 + cr0 + r;
      const int h = p >> 3, w = p & 7;
      const size_t t = (((size_t)b * 32 + h0 + h) * 32 + (w0 + w));
      float v = acc[nt][r] + bz;
      if (resid) v += resid[t * 96 + oc];
      out[t * 96 + oc] = v;
    }
  }
}

// ---------------------------------------------------------------- conv stem 4->96
__global__ __launch_bounds__(256) void conv_first_kernel(
    const float* __restrict__ es, const float* __restrict__ jp,
    const float* __restrict__ wgt, const float* __restrict__ bias,
    float* __restrict__ xf)
{
  const int idx = blockIdx.x * 256 + threadIdx.x;
  const int oc = idx % 96;
  const int pos = idx / 96;
  const int w = pos % 32, hp = (pos / 32) % 32, b = pos / 1024;
  float acc = bias[oc];
  for (int kh = 0; kh < 3; ++kh) {
    const int hh = hp + kh - 1;
    if ((unsigned)hh >= 32u) continue;
    for (int kw = 0; kw < 3; ++kw) {
      const int ww = w + kw - 1;
      if ((unsigned)ww >= 32u) continue;
      const size_t sp = ((size_t)b * 2 * 32 + hh) * 32 + ww;
      const float i0 = es[sp];
      const float i1 = es[sp + 1024];
      const float i2 = jp[sp];
      const float i3 = jp[sp + 1024];
      const float* wr = wgt + (size_t)((kh * 3 + kw) * 4) * 96 + oc;
      acc = fmaf(i0, wr[0], acc);
      acc = fmaf(i1, wr[96], acc);
      acc = fmaf(i2, wr[192], acc);
      acc = fmaf(i3, wr[288], acc);
    }
  }
  xf[idx] = acc;
}

// ---------------------------------------------------------------- conv tail 96->2
__global__ __launch_bounds__(256) void conv_last_kernel(
    const float* __restrict__ res, const float* __restrict__ wgt,
    const float* __restrict__ bias, float* __restrict__ out)
{
  const int idx = blockIdx.x * 256 + threadIdx.x;
  const int oc = idx % 2;
  const int pos = idx / 2;
  const int w = pos % 32, hp = (pos / 32) % 32, b = pos / 1024;
  float acc = bias[oc];
  for (int kh = 0; kh < 3; ++kh) {
    const int hh = hp + kh - 1;
    if ((unsigned)hh >= 32u) continue;
    for (int kw = 0; kw < 3; ++kw) {
      const int ww = w + kw - 1;
      if ((unsigned)ww >= 32u) continue;
      const float* pr = res + (((size_t)b * 32 + hh) * 32 + ww) * 96;
      const float* wr = wgt + (size_t)((kh * 3 + kw) * 96) * 2 + oc;
      #pragma unroll 8
      for (int ic = 0; ic < 96; ++ic)
        acc = fmaf(pr[ic], wr[ic * 2], acc);
    }
  }
  out[(((size_t)b * 2 + oc) * 32 + hp) * 32 + w] = acc;
}

// ---------------------------------------------------------------- host
extern "C" void kernel_launch(void* const* d_in, const int* in_sizes, int n_in,
                              void* d_out, int out_size, void* d_ws, size_t ws_size,
                              hipStream_t stream)
{
  const int fill_grid = (out_size + 255) / 256;

  if (n_in != 27) {
    fill_kernel<<<fill_grid, 256, 0, stream>>>((float*)d_out, 200.0f + (float)n_in, out_size);
    return;
  }
  static const int expected_sizes[27] = {
    131072, 131072, 3456, 96, 96, 96, 2304, 2304, 663552, 6912,
    221184, 2304, 32400, 2304, 2304, 884736, 9216, 884736, 2304,
    331776, 384, 96, 96, 82944, 96, 1728, 2
  };
  for (int i = 0; i < 27; ++i) {
    if (in_sizes[i] != expected_sizes[i]) {
      fill_kernel<<<fill_grid, 256, 0, stream>>>((float*)d_out, 300.0f + (float)i, out_size);
      return;
    }
  }
  if (out_size != 131072) {
    fill_kernel<<<fill_grid, 256, 0, stream>>>((float*)d_out, 400.0f, out_size);
    return;
  }
  const uintptr_t raw = (uintptr_t)d_ws;
  const uintptr_t alignedp = (raw + 255) & ~(uintptr_t)255;
  const size_t ws_avail_bytes = (ws_size > (alignedp - raw)) ? ws_size - (alignedp - raw) : 0;
  const size_t avail = ws_avail_bytes / 4;   // floats
  const size_t WBUF_F = 1534464;             // all bf16 weights, float units
  const size_t floor_need = 2 * TC + WBUF_F;
  if (avail < floor_need) {
    fill_kernel<<<fill_grid, 256, 0, stream>>>((float*)d_out,
        100.0f + (float)(ws_size >> 20), out_size);
    return;
  }

  const float* es      = (const float*)d_in[0];
  const float* jp      = (const float*)d_in[1];
  const float* cf_w    = (const float*)d_in[2];
  const float* cf_b    = (const float*)d_in[3];
  const float* pe_s    = (const float*)d_in[4];
  const float* pe_b    = (const float*)d_in[5];
  const float* n1_s    = (const float*)d_in[6];
  const float* n1_b    = (const float*)d_in[7];
  const float* qkv_w   = (const float*)d_in[8];
  const float* qkv_b   = (const float*)d_in[9];
  const float* proj_w  = (const float*)d_in[10];
  const float* proj_b  = (const float*)d_in[11];
  const float* rpb     = (const float*)d_in[12];
  const float* n2_s    = (const float*)d_in[13];
  const float* n2_b    = (const float*)d_in[14];
  const float* fc1_w   = (const float*)d_in[15];
  const float* fc1_b   = (const float*)d_in[16];
  const float* fc2_w   = (const float*)d_in[17];
  const float* fc2_b   = (const float*)d_in[18];
  const float* rstb_w  = (const float*)d_in[19];
  const float* rstb_b  = (const float*)d_in[20];
  const float* nf_s    = (const float*)d_in[21];
  const float* nf_b    = (const float*)d_in[22];
  const float* body_w  = (const float*)d_in[23];
  const float* body_b  = (const float*)d_in[24];
  const float* last_w  = (const float*)d_in[25];
  const float* last_b  = (const float*)d_in[26];

  float* x = (float*)alignedp;
  float* r = x + TC;
  unsigned short* wq  = (unsigned short*)(r + TC);   // [24][288][96] bf16
  unsigned short* wp  = wq + 663552;                 // [24][96][96]
  unsigned short* w1  = wp + 221184;                 // [24][384][96]
  unsigned short* w2  = w1 + 884736;                 // [24][96][384]
  unsigned short* wcr = w2 + 884736;                 // [4][9][96][96]
  unsigned short* wcb = wcr + 331776;                // [9][96][96]

  const int grid_tc = (int)(TC / 256);
  const int grid_lf = T_TOK / 4;
  const int nwin = T_TOK / 64;                       // 1024

  // weight convert+transpose
  wconv_kernel<<<dim3((96 * 288 + 255) / 256, 24), 256, 0, stream>>>(qkv_w, wq, 96, 288);
  wconv_kernel<<<dim3((96 * 96 + 255) / 256, 24), 256, 0, stream>>>(proj_w, wp, 96, 96);
  wconv_kernel<<<dim3((96 * 384 + 255) / 256, 24), 256, 0, stream>>>(fc1_w, w1, 96, 384);
  wconv_kernel<<<dim3((384 * 96 + 255) / 256, 24), 256, 0, stream>>>(fc2_w, w2, 384, 96);
  wconv_conv_kernel<<<(331776 + 255) / 256, 256, 0, stream>>>(rstb_w, wcr, 331776);
  wconv_conv_kernel<<<(82944 + 255) / 256, 256, 0, stream>>>(body_w, wcb, 82944);

  // stem: x = LN_pe(conv_first(inputs)), LN in place
  conv_first_kernel<<<grid_tc, 256, 0, stream>>>(es, jp, cf_w, cf_b, x);
  ln_fp32_kernel<<<grid_lf, 256, 0, stream>>>(x, pe_s, pe_b, x);

  float* xb = x;
  float* rb = r;
  for (int l = 0; l < NL; ++l) {
    copy_kernel<<<grid_tc, 256, 0, stream>>>(rb, xb);
    for (int d = 0; d < ND; ++d) {
      const int ld = l * ND + d;
      const int shift = (d & 1) ? 4 : 0;
      swin_attn_fused<<<nwin, 384, 0, stream>>>(
          xb, n1_s + ld * CC, n1_b + ld * CC,
          wq + (size_t)ld * 288 * 96, qkv_b + (size_t)ld * 288,
          rpb + (size_t)ld * 225 * NH,
          wp + (size_t)ld * 96 * 96, proj_b + (size_t)ld * 96, shift);
      swin_mlp_fused<<<nwin, 256, 0, stream>>>(
          xb, n2_s + ld * CC, n2_b + ld * CC,
          w1 + (size_t)ld * 384 * 96, fc1_b + (size_t)ld * 384,
          w2 + (size_t)ld * 96 * 384, fc2_b + (size_t)ld * 96);
    }
    conv96m_kernel<<<1024, 256, 0, stream>>>(xb, wcr + (size_t)l * 9 * 9216,
                                             rstb_b + (size_t)l * CC, rb, rb);
    float* sw = xb; xb = rb; rb = sw;
  }
  // tail
  ln_fp32_kernel<<<grid_lf, 256, 0, stream>>>(xb, nf_s, nf_b, rb);
  conv_first_kernel<<<grid_tc, 256, 0, stream>>>(es, jp, cf_w, cf_b, xb);
  conv96m_kernel<<<1024, 256, 0, stream>>>(rb, wcb, body_b, xb, xb);
  conv_last_kernel<<<(BB * 32 * 32 * 2) / 256, 256, 0, stream>>>(xb, last_w, last_b, (float*)d_out);
}

// Round 14
// 4114.454 us; speedup vs baseline: 2.4869x; 1.1703x over previous
//
#include <hip/hip_runtime.h>
#include <hip/hip_bf16.h>
#include <cstddef>
#include <cstdint>

#define BB 64
#define HH 32
#define WW_ 32
#define CC 96
#define WS 8
#define NH 6
#define NL 4
#define ND 6
#define T_TOK (BB*HH*WW_)      // 65536 tokens
#define TC ((size_t)T_TOK*CC)  // 6291456 floats

typedef long long ll;
typedef __attribute__((ext_vector_type(8))) short short8;
typedef __attribute__((ext_vector_type(4))) float f32x4;
typedef __attribute__((ext_vector_type(4))) unsigned short ushort4v;

// Harness-named kernel symbol.
__global__ void JNetSwinIR_41034117546277_kernel() {}

__device__ __forceinline__ unsigned short f2bf(float f) {
  unsigned u = __float_as_uint(f);
  unsigned r = (u + 0x7FFF + ((u >> 16) & 1)) >> 16;
  return (unsigned short)r;
}
__device__ __forceinline__ float bf2f(unsigned short h) {
  return __uint_as_float(((unsigned)h) << 16);
}

// ---------------------------------------------------------------- diagnostic fill
__global__ __launch_bounds__(256) void fill_kernel(float* p, float v, int n)
{
  const int idx = blockIdx.x * 256 + threadIdx.x;
  if (idx < n) p[idx] = v;
}

// ---------------------------------------------------------------- weight fp32->bf16 transpose
// W [24][K][N] fp32 -> Wt [24][N][K] bf16
__global__ __launch_bounds__(256) void wconv_kernel(
    const float* __restrict__ W, unsigned short* __restrict__ Wt, int K, int N)
{
  const int ld = blockIdx.y;
  const int idx = blockIdx.x * 256 + threadIdx.x;
  if (idx >= K * N) return;
  const int k = idx / N, n = idx % N;
  Wt[(size_t)ld * K * N + (size_t)n * K + k] = f2bf(W[(size_t)ld * K * N + idx]);
}

// conv weights [L][3][3][ic=96][oc=96] fp32 -> [L][9][oc][ic] bf16
__global__ __launch_bounds__(256) void wconv_conv_kernel(
    const float* __restrict__ W, unsigned short* __restrict__ Wt, int total)
{
  const int idx = blockIdx.x * 256 + threadIdx.x;
  if (idx >= total) return;
  const int l9 = idx / 9216;
  const int rest = idx % 9216;
  const int oc = rest / 96, ic = rest % 96;
  Wt[idx] = f2bf(W[(size_t)(l9 * 96 + ic) * 96 + oc]);
}

// ---------------------------------------------------------------- LayerNorm fp32 (stem/tail)
__global__ __launch_bounds__(256) void ln_fp32_kernel(
    const float* __restrict__ x, const float* __restrict__ gamma,
    const float* __restrict__ beta, float* __restrict__ out)
{
  const int wave = threadIdx.x >> 6;
  const int lane = threadIdx.x & 63;
  const int t = blockIdx.x * 4 + wave;
  const float* xp = x + (size_t)t * CC;
  const float v0 = xp[lane];
  const float v1 = (lane < 32) ? xp[64 + lane] : 0.f;
  float s = v0 + v1, s2 = v0 * v0 + v1 * v1;
  #pragma unroll
  for (int off = 32; off; off >>= 1) {
    s  += __shfl_xor(s,  off);
    s2 += __shfl_xor(s2, off);
  }
  const float mean = s * (1.f / 96.f);
  const float var  = s2 * (1.f / 96.f) - mean * mean;
  const float inv  = rsqrtf(var + 1e-5f);
  float* op = out + (size_t)t * CC;
  const float r0 = (v0 - mean) * inv * gamma[lane] + beta[lane];
  const float r1 = (v1 - mean) * inv * gamma[64 + lane] + beta[64 + lane];
  op[lane] = r0;
  if (lane < 32) op[64 + lane] = r1;
}

// ---------------------------------------------------------------- fully fused swin block
// one block per window, 384 thr = 6 waves (wave = head for attn).
// LN1 -> qkv -> attn -> proj(+x_old)->xacc(LDS) -> LN2 -> fc1+GELU -> fc2 -> x write
__global__ __launch_bounds__(384) void swin_block_fused(
    float* x, const float* __restrict__ n1s, const float* __restrict__ n1b,
    const unsigned short* __restrict__ wq_ld, const float* __restrict__ qkvb,
    const float* __restrict__ rpb_ld,
    const unsigned short* __restrict__ wp_ld, const float* __restrict__ projb,
    const float* __restrict__ n2s, const float* __restrict__ n2b,
    const unsigned short* __restrict__ w1_ld, const float* __restrict__ f1b,
    const unsigned short* __restrict__ w2_ld, const float* __restrict__ f2b,
    int shift)
{
  const int widx = blockIdx.x;
  const int tid  = threadIdx.x;
  const int wv   = tid >> 6;      // 0..5
  const int lane = tid & 63;

  // manually laid-out shared memory with phase overlays
  __shared__ __attribute__((aligned(16))) char smem[72472];
  auto a    = (unsigned short(*)[104])(smem);            // 13312 B: LN1/attn/LN2 out
  auto kk   = (float(*)[100])(smem + 13312);             // 25600 B: K fp32
  auto xacc = (float(*)[100])(smem + 13312);             //   overlay: x+proj residual
  auto vv   = (unsigned short(*)[104])(smem + 38912);    // 13312 B: V bf16
  auto hbuf = (unsigned short(*)[200])(smem + 38912);    //   overlay (25600B, spans qt)
  auto qt   = (unsigned short(*)[112])(smem + 52224);    // 14336 B: Q bf16
  float* bias_s = (float*)(smem + 66560);                // 5400 B
  int*   reg_s  = (int*)(smem + 71960);                  // 256 B
  int*   st_s   = (int*)(smem + 72216);                  // 256 B

  if (tid < 64) {
    const int wimg = widx & 15;
    const int h = (wimg >> 2) * 8 + (tid >> 3);
    const int w = (wimg & 3) * 8 + (tid & 7);
    reg_s[tid] = 3 * (h < 24 ? 0 : (h < 28 ? 1 : 2)) +
                     (w < 24 ? 0 : (w < 28 ? 1 : 2));
    const int b = widx >> 4;
    const int p = (h + shift) & 31, q = (w + shift) & 31;
    st_s[tid] = (b << 10) + (p << 5) + q;
  }
  for (int i = tid; i < NH * 225; i += 384) {
    const int hh = i / 225, ii = i % 225;
    bias_s[i] = rpb_ld[ii * NH + hh];
  }
  __syncthreads();

  // phase 1: LN1
  for (int t = wv; t < 64; t += 6) {
    const float* xp = x + (size_t)st_s[t] * CC;
    const float v0 = xp[lane];
    const float v1 = (lane < 32) ? xp[64 + lane] : 0.f;
    float s = v0 + v1, s2 = v0 * v0 + v1 * v1;
    #pragma unroll
    for (int off = 32; off; off >>= 1) {
      s  += __shfl_xor(s,  off);
      s2 += __shfl_xor(s2, off);
    }
    const float mean = s * (1.f / 96.f);
    const float var  = s2 * (1.f / 96.f) - mean * mean;
    const float inv  = rsqrtf(var + 1e-5f);
    a[t][lane] = f2bf((v0 - mean) * inv * n1s[lane] + n1b[lane]);
    if (lane < 32)
      a[t][64 + lane] = f2bf((v1 - mean) * inv * n1s[64 + lane] + n1b[64 + lane]);
  }
  __syncthreads();

  // phase 2: qkv MFMA — wave = head
  {
    const int row = lane & 15;
    const int ko  = (lane >> 4) * 8;
    const int cc  = lane & 15;
    const int cr0 = (lane >> 4) * 4;
    #pragma unroll
    for (int out3 = 0; out3 < 3; ++out3) {
      const int n0 = out3 * 96 + wv * 16;
      const unsigned short* bp = wq_ld + (size_t)(n0 + row) * 96 + ko;
      const float bz = qkvb[n0 + cc];
      #pragma unroll
      for (int rt = 0; rt < 4; ++rt) {
        f32x4 acc = {0.f, 0.f, 0.f, 0.f};
        const unsigned short* ap = &a[rt * 16 + row][ko];
        #pragma unroll
        for (int k0 = 0; k0 < 96; k0 += 32) {
          const short8 af = *(const short8*)(ap + k0);
          const short8 bf = *(const short8*)(bp + k0);
          acc = __builtin_amdgcn_mfma_f32_16x16x32_bf16(af, bf, acc, 0, 0, 0);
        }
        #pragma unroll
        for (int r = 0; r < 4; ++r) {
          const int tok = rt * 16 + cr0 + r;
          const float v = acc[r] + bz;
          if (out3 == 0)      qt[tok][wv * 16 + cc] = f2bf(v);
          else if (out3 == 1) kk[tok][wv * 16 + cc] = v;
          else                vv[tok][wv * 16 + cc] = f2bf(v);
        }
      }
    }
  }
  __syncthreads();

  // phase 3: attention — wave = head, lane = query token
  const int head = wv;
  {
    float q[16];
    {
      const short8 q0 = *(const short8*)&qt[lane][head * 16];
      const short8 q1 = *(const short8*)&qt[lane][head * 16 + 8];
      #pragma unroll
      for (int i = 0; i < 8; ++i) {
        q[i]     = bf2f((unsigned short)q0[i]);
        q[8 + i] = bf2f((unsigned short)q1[i]);
      }
    }
    const float* bias_h = bias_s + head * 225;
    const int ih = lane >> 3, iw = lane & 7;
    const int myreg = reg_s[lane];
    float s[64];
    #pragma unroll
    for (int j = 0; j < 64; ++j) {
      const float4 k0 = *(const float4*)&kk[j][head * 16];
      const float4 k1 = *(const float4*)&kk[j][head * 16 + 4];
      const float4 k2 = *(const float4*)&kk[j][head * 16 + 8];
      const float4 k3 = *(const float4*)&kk[j][head * 16 + 12];
      float acc = 0.f;
      acc = fmaf(q[0],  k0.x, acc); acc = fmaf(q[1],  k0.y, acc);
      acc = fmaf(q[2],  k0.z, acc); acc = fmaf(q[3],  k0.w, acc);
      acc = fmaf(q[4],  k1.x, acc); acc = fmaf(q[5],  k1.y, acc);
      acc = fmaf(q[6],  k1.z, acc); acc = fmaf(q[7],  k1.w, acc);
      acc = fmaf(q[8],  k2.x, acc); acc = fmaf(q[9],  k2.y, acc);
      acc = fmaf(q[10], k2.z, acc); acc = fmaf(q[11], k2.w, acc);
      acc = fmaf(q[12], k3.x, acc); acc = fmaf(q[13], k3.y, acc);
      acc = fmaf(q[14], k3.z, acc); acc = fmaf(q[15], k3.w, acc);
      const int idx = (ih - (j >> 3) + 7) * 15 + (iw - (j & 7) + 7);
      acc = acc * 0.25f + bias_h[idx];
      if (shift && reg_s[j] != myreg) acc -= 100.f;
      s[j] = acc;
    }
    float m = s[0];
    #pragma unroll
    for (int j = 1; j < 64; ++j) m = fmaxf(m, s[j]);
    float sum = 0.f;
    #pragma unroll
    for (int j = 0; j < 64; ++j) { const float p = __expf(s[j] - m); s[j] = p; sum += p; }
    const float inv = 1.f / sum;
    float o[16] = {};
    #pragma unroll
    for (int j = 0; j < 64; ++j) {
      const float p = s[j] * inv;
      const short8 v0 = *(const short8*)&vv[j][head * 16];
      const short8 v1 = *(const short8*)&vv[j][head * 16 + 8];
      #pragma unroll
      for (int i = 0; i < 8; ++i) {
        o[i]     = fmaf(p, bf2f((unsigned short)v0[i]), o[i]);
        o[8 + i] = fmaf(p, bf2f((unsigned short)v1[i]), o[8 + i]);
      }
    }
    short8 o0, o1;
    #pragma unroll
    for (int i = 0; i < 8; ++i) {
      o0[i] = (short)f2bf(o[i]);
      o1[i] = (short)f2bf(o[8 + i]);
    }
    *(short8*)&a[lane][head * 16]     = o0;
    *(short8*)&a[lane][head * 16 + 8] = o1;
  }
  __syncthreads();   // attn out in a; kk/vv/qt reads complete

  // phase 4: proj MFMA; xacc = x_old + proj + bias  (LDS only)
  {
    const int row = lane & 15;
    const int ko  = (lane >> 4) * 8;
    const int cc  = lane & 15;
    const int cr0 = (lane >> 4) * 4;
    const int n0 = wv * 16;
    const unsigned short* bp = wp_ld + (size_t)(n0 + row) * 96 + ko;
    const float bz = projb[n0 + cc];
    #pragma unroll
    for (int rt = 0; rt < 4; ++rt) {
      f32x4 acc = {0.f, 0.f, 0.f, 0.f};
      const unsigned short* ap = &a[rt * 16 + row][ko];
      #pragma unroll
      for (int k0 = 0; k0 < 96; k0 += 32) {
        const short8 af = *(const short8*)(ap + k0);
        const short8 bf = *(const short8*)(bp + k0);
        acc = __builtin_amdgcn_mfma_f32_16x16x32_bf16(af, bf, acc, 0, 0, 0);
      }
      #pragma unroll
      for (int r = 0; r < 4; ++r) {
        const int tok = rt * 16 + cr0 + r;
        const float xo = x[(size_t)st_s[tok] * CC + n0 + cc];
        xacc[tok][n0 + cc] = xo + acc[r] + bz;
      }
    }
  }
  __syncthreads();

  // phase 5: LN2 from xacc -> a
  for (int t = wv; t < 64; t += 6) {
    const float v0 = xacc[t][lane];
    const float v1 = (lane < 32) ? xacc[t][64 + lane] : 0.f;
    float s = v0 + v1, s2 = v0 * v0 + v1 * v1;
    #pragma unroll
    for (int off = 32; off; off >>= 1) {
      s  += __shfl_xor(s,  off);
      s2 += __shfl_xor(s2, off);
    }
    const float mean = s * (1.f / 96.f);
    const float var  = s2 * (1.f / 96.f) - mean * mean;
    const float inv  = rsqrtf(var + 1e-5f);
    a[t][lane] = f2bf((v0 - mean) * inv * n2s[lane] + n2b[lane]);
    if (lane < 32)
      a[t][64 + lane] = f2bf((v1 - mean) * inv * n2s[64 + lane] + n2b[64 + lane]);
  }
  __syncthreads();

  // phase 6: MLP in two K-passes (hidden cols [p*192, p*192+192) in hbuf)
  const int row = lane & 15;
  const int ko  = (lane >> 4) * 8;
  const int cc  = lane & 15;
  const int cr0 = (lane >> 4) * 4;
  f32x4 acc2[4];
  #pragma unroll
  for (int i = 0; i < 4; ++i) acc2[i] = (f32x4){0.f, 0.f, 0.f, 0.f};
  #pragma unroll
  for (int p = 0; p < 2; ++p) {
    // fc1 + GELU: wave wv -> hidden cols [p*192 + wv*32, +32)
    #pragma unroll
    for (int ct = 0; ct < 2; ++ct) {
      const int n0g = p * 192 + wv * 32 + ct * 16;   // global hidden col
      const int n0l = wv * 32 + ct * 16;             // local col in hbuf
      const unsigned short* bp = w1_ld + (size_t)(n0g + row) * 96 + ko;
      const float bz = f1b[n0g + cc];
      #pragma unroll
      for (int rt = 0; rt < 4; ++rt) {
        f32x4 acc = {0.f, 0.f, 0.f, 0.f};
        const unsigned short* ap = &a[rt * 16 + row][ko];
        #pragma unroll
        for (int k0 = 0; k0 < 96; k0 += 32) {
          const short8 af = *(const short8*)(ap + k0);
          const short8 bf = *(const short8*)(bp + k0);
          acc = __builtin_amdgcn_mfma_f32_16x16x32_bf16(af, bf, acc, 0, 0, 0);
        }
        #pragma unroll
        for (int r = 0; r < 4; ++r) {
          float v = acc[r] + bz;
          v = 0.5f * v * (1.f + erff(v * 0.70710678118f));
          hbuf[rt * 16 + cr0 + r][n0l + cc] = f2bf(v);
        }
      }
    }
    __syncthreads();
    // fc2 partial: wave wv -> out cols [wv*16, +16), K-slice [p*192, p*192+192)
    {
      const int n0 = wv * 16;
      const unsigned short* bp = w2_ld + (size_t)(n0 + row) * 384 + p * 192 + ko;
      #pragma unroll
      for (int rt = 0; rt < 4; ++rt) {
        const unsigned short* ap = &hbuf[rt * 16 + row][ko];
        #pragma unroll
        for (int k0 = 0; k0 < 192; k0 += 32) {
          const short8 af = *(const short8*)(ap + k0);
          const short8 bf = *(const short8*)(bp + k0);
          acc2[rt] = __builtin_amdgcn_mfma_f32_16x16x32_bf16(af, bf, acc2[rt], 0, 0, 0);
        }
      }
    }
    __syncthreads();
  }

  // phase 7: final write  x = xacc + fc2 + bias
  {
    const int n0 = wv * 16;
    const float bz = f2b[n0 + cc];
    #pragma unroll
    for (int rt = 0; rt < 4; ++rt) {
      #pragma unroll
      for (int r = 0; r < 4; ++r) {
        const int tok = rt * 16 + cr0 + r;
        x[(size_t)st_s[tok] * CC + n0 + cc] = xacc[tok][n0 + cc] + acc2[rt][r] + bz;
      }
    }
  }
}

// ---------------------------------------------------------------- copy
__global__ __launch_bounds__(256) void copy_kernel(
    float* __restrict__ dst, const float* __restrict__ src)
{
  const int idx = blockIdx.x * 256 + threadIdx.x;
  dst[idx] = src[idx];
}

// ---------------------------------------------------------------- conv 3x3 96->96, MFMA implicit GEMM
__global__ __launch_bounds__(256) void conv96m_kernel(
    const float* __restrict__ x, const unsigned short* __restrict__ wt,
    const float* __restrict__ bias, const float* resid, float* out)
{
  const int blk = blockIdx.x;
  const int b = blk >> 4, th = (blk >> 2) & 3, tw = blk & 3;
  const int h0 = th * 8, w0 = tw * 8;
  __shared__ unsigned short patch[100][104];
  for (int idx = threadIdx.x; idx < 100 * 24; idx += 256) {
    const int pp = idx / 24, c4 = (idx % 24) * 4;
    const int ph = pp / 10, pw = pp % 10;
    const int hh = h0 + ph - 1, ww = w0 + pw - 1;
    float4 v = {0.f, 0.f, 0.f, 0.f};
    if ((unsigned)hh < 32u && (unsigned)ww < 32u)
      v = *(const float4*)&x[(((size_t)b * 32 + hh) * 32 + ww) * 96 + c4];
    ushort4v o;
    o.x = f2bf(v.x); o.y = f2bf(v.y); o.z = f2bf(v.z); o.w = f2bf(v.w);
    *(ushort4v*)&patch[pp][c4] = o;
  }
  __syncthreads();
  const int wv = threadIdx.x >> 6, lane = threadIdx.x & 63;
  const int m0 = wv * 16;
  const int arow = lane & 15;
  const int ko  = (lane >> 4) * 8;
  const int px = m0 + arow;
  const int ph_ = px >> 3, pw_ = px & 7;
  f32x4 acc[6];
  #pragma unroll
  for (int i = 0; i < 6; ++i) acc[i] = (f32x4){0.f, 0.f, 0.f, 0.f};
  #pragma unroll
  for (int kh = 0; kh < 3; ++kh)
    #pragma unroll
    for (int kw = 0; kw < 3; ++kw) {
      const unsigned short* wbase = wt + (size_t)(kh * 3 + kw) * 9216;
      const unsigned short* prow = &patch[(ph_ + kh) * 10 + (pw_ + kw)][ko];
      #pragma unroll
      for (int k0 = 0; k0 < 96; k0 += 32) {
        const short8 af = *(const short8*)(prow + k0);
        #pragma unroll
        for (int nt = 0; nt < 6; ++nt) {
          const short8 bf = *(const short8*)(wbase + (size_t)(nt * 16 + arow) * 96 + ko + k0);
          acc[nt] = __builtin_amdgcn_mfma_f32_16x16x32_bf16(af, bf, acc[nt], 0, 0, 0);
        }
      }
    }
  const int cc = lane & 15;
  const int cr0 = (lane >> 4) * 4;
  #pragma unroll
  for (int nt = 0; nt < 6; ++nt) {
    const int oc = nt * 16 + cc;
    const float bz = bias[oc];
    #pragma unroll
    for (int r = 0; r < 4; ++r) {
      const int p = m0 + cr0 + r;
      const int h = p >> 3, w = p & 7;
      const size_t t = (((size_t)b * 32 + h0 + h) * 32 + (w0 + w));
      float v = acc[nt][r] + bz;
      if (resid) v += resid[t * 96 + oc];
      out[t * 96 + oc] = v;
    }
  }
}

// ---------------------------------------------------------------- conv stem 4->96
__global__ __launch_bounds__(256) void conv_first_kernel(
    const float* __restrict__ es, const float* __restrict__ jp,
    const float* __restrict__ wgt, const float* __restrict__ bias,
    float* __restrict__ xf)
{
  const int idx = blockIdx.x * 256 + threadIdx.x;
  const int oc = idx % 96;
  const int pos = idx / 96;
  const int w = pos % 32, hp = (pos / 32) % 32, b = pos / 1024;
  float acc = bias[oc];
  for (int kh = 0; kh < 3; ++kh) {
    const int hh = hp + kh - 1;
    if ((unsigned)hh >= 32u) continue;
    for (int kw = 0; kw < 3; ++kw) {
      const int ww = w + kw - 1;
      if ((unsigned)ww >= 32u) continue;
      const size_t sp = ((size_t)b * 2 * 32 + hh) * 32 + ww;
      const float i0 = es[sp];
      const float i1 = es[sp + 1024];
      const float i2 = jp[sp];
      const float i3 = jp[sp + 1024];
      const float* wr = wgt + (size_t)((kh * 3 + kw) * 4) * 96 + oc;
      acc = fmaf(i0, wr[0], acc);
      acc = fmaf(i1, wr[96], acc);
      acc = fmaf(i2, wr[192], acc);
      acc = fmaf(i3, wr[288], acc);
    }
  }
  xf[idx] = acc;
}

// ---------------------------------------------------------------- conv tail 96->2
__global__ __launch_bounds__(256) void conv_last_kernel(
    const float* __restrict__ res, const float* __restrict__ wgt,
    const float* __restrict__ bias, float* __restrict__ out)
{
  const int idx = blockIdx.x * 256 + threadIdx.x;
  const int oc = idx % 2;
  const int pos = idx / 2;
  const int w = pos % 32, hp = (pos / 32) % 32, b = pos / 1024;
  float acc = bias[oc];
  for (int kh = 0; kh < 3; ++kh) {
    const int hh = hp + kh - 1;
    if ((unsigned)hh >= 32u) continue;
    for (int kw = 0; kw < 3; ++kw) {
      const int ww = w + kw - 1;
      if ((unsigned)ww >= 32u) continue;
      const float* pr = res + (((size_t)b * 32 + hh) * 32 + ww) * 96;
      const float* wr = wgt + (size_t)((kh * 3 + kw) * 96) * 2 + oc;
      #pragma unroll 8
      for (int ic = 0; ic < 96; ++ic)
        acc = fmaf(pr[ic], wr[ic * 2], acc);
    }
  }
  out[(((size_t)b * 2 + oc) * 32 + hp) * 32 + w] = acc;
}

// ---------------------------------------------------------------- host
extern "C" void kernel_launch(void* const* d_in, const int* in_sizes, int n_in,
                              void* d_out, int out_size, void* d_ws, size_t ws_size,
                              hipStream_t stream)
{
  const int fill_grid = (out_size + 255) / 256;

  if (n_in != 27) {
    fill_kernel<<<fill_grid, 256, 0, stream>>>((float*)d_out, 200.0f + (float)n_in, out_size);
    return;
  }
  static const int expected_sizes[27] = {
    131072, 131072, 3456, 96, 96, 96, 2304, 2304, 663552, 6912,
    221184, 2304, 32400, 2304, 2304, 884736, 9216, 884736, 2304,
    331776, 384, 96, 96, 82944, 96, 1728, 2
  };
  for (int i = 0; i < 27; ++i) {
    if (in_sizes[i] != expected_sizes[i]) {
      fill_kernel<<<fill_grid, 256, 0, stream>>>((float*)d_out, 300.0f + (float)i, out_size);
      return;
    }
  }
  if (out_size != 131072) {
    fill_kernel<<<fill_grid, 256, 0, stream>>>((float*)d_out, 400.0f, out_size);
    return;
  }
  const uintptr_t raw = (uintptr_t)d_ws;
  const uintptr_t alignedp = (raw + 255) & ~(uintptr_t)255;
  const size_t ws_avail_bytes = (ws_size > (alignedp - raw)) ? ws_size - (alignedp - raw) : 0;
  const size_t avail = ws_avail_bytes / 4;   // floats
  const size_t WBUF_F = 1534464;             // all bf16 weights, float units
  const size_t floor_need = 2 * TC + WBUF_F;
  if (avail < floor_need) {
    fill_kernel<<<fill_grid, 256, 0, stream>>>((float*)d_out,
        100.0f + (float)(ws_size >> 20), out_size);
    return;
  }

  const float* es      = (const float*)d_in[0];
  const float* jp      = (const float*)d_in[1];
  const float* cf_w    = (const float*)d_in[2];
  const float* cf_b    = (const float*)d_in[3];
  const float* pe_s    = (const float*)d_in[4];
  const float* pe_b    = (const float*)d_in[5];
  const float* n1_s    = (const float*)d_in[6];
  const float* n1_b    = (const float*)d_in[7];
  const float* qkv_w   = (const float*)d_in[8];
  const float* qkv_b   = (const float*)d_in[9];
  const float* proj_w  = (const float*)d_in[10];
  const float* proj_b  = (const float*)d_in[11];
  const float* rpb     = (const float*)d_in[12];
  const float* n2_s    = (const float*)d_in[13];
  const float* n2_b    = (const float*)d_in[14];
  const float* fc1_w   = (const float*)d_in[15];
  const float* fc1_b   = (const float*)d_in[16];
  const float* fc2_w   = (const float*)d_in[17];
  const float* fc2_b   = (const float*)d_in[18];
  const float* rstb_w  = (const float*)d_in[19];
  const float* rstb_b  = (const float*)d_in[20];
  const float* nf_s    = (const float*)d_in[21];
  const float* nf_b    = (const float*)d_in[22];
  const float* body_w  = (const float*)d_in[23];
  const float* body_b  = (const float*)d_in[24];
  const float* last_w  = (const float*)d_in[25];
  const float* last_b  = (const float*)d_in[26];

  float* x = (float*)alignedp;
  float* r = x + TC;
  unsigned short* wq  = (unsigned short*)(r + TC);   // [24][288][96] bf16
  unsigned short* wp  = wq + 663552;                 // [24][96][96]
  unsigned short* w1  = wp + 221184;                 // [24][384][96]
  unsigned short* w2  = w1 + 884736;                 // [24][96][384]
  unsigned short* wcr = w2 + 884736;                 // [4][9][96][96]
  unsigned short* wcb = wcr + 331776;                // [9][96][96]

  const int grid_tc = (int)(TC / 256);
  const int grid_lf = T_TOK / 4;
  const int nwin = T_TOK / 64;                       // 1024

  // weight convert+transpose
  wconv_kernel<<<dim3((96 * 288 + 255) / 256, 24), 256, 0, stream>>>(qkv_w, wq, 96, 288);
  wconv_kernel<<<dim3((96 * 96 + 255) / 256, 24), 256, 0, stream>>>(proj_w, wp, 96, 96);
  wconv_kernel<<<dim3((96 * 384 + 255) / 256, 24), 256, 0, stream>>>(fc1_w, w1, 96, 384);
  wconv_kernel<<<dim3((384 * 96 + 255) / 256, 24), 256, 0, stream>>>(fc2_w, w2, 384, 96);
  wconv_conv_kernel<<<(331776 + 255) / 256, 256, 0, stream>>>(rstb_w, wcr, 331776);
  wconv_conv_kernel<<<(82944 + 255) / 256, 256, 0, stream>>>(body_w, wcb, 82944);

  // stem: x = LN_pe(conv_first(inputs)), LN in place
  conv_first_kernel<<<grid_tc, 256, 0, stream>>>(es, jp, cf_w, cf_b, x);
  ln_fp32_kernel<<<grid_lf, 256, 0, stream>>>(x, pe_s, pe_b, x);

  float* xb = x;
  float* rb = r;
  for (int l = 0; l < NL; ++l) {
    copy_kernel<<<grid_tc, 256, 0, stream>>>(rb, xb);
    for (int d = 0; d < ND; ++d) {
      const int ld = l * ND + d;
      const int shift = (d & 1) ? 4 : 0;
      swin_block_fused<<<nwin, 384, 0, stream>>>(
          xb, n1_s + ld * CC, n1_b + ld * CC,
          wq + (size_t)ld * 288 * 96, qkv_b + (size_t)ld * 288,
          rpb + (size_t)ld * 225 * NH,
          wp + (size_t)ld * 96 * 96, proj_b + (size_t)ld * 96,
          n2_s + ld * CC, n2_b + ld * CC,
          w1 + (size_t)ld * 384 * 96, fc1_b + (size_t)ld * 384,
          w2 + (size_t)ld * 96 * 384, fc2_b + (size_t)ld * 96, shift);
    }
    conv96m_kernel<<<1024, 256, 0, stream>>>(xb, wcr + (size_t)l * 9 * 9216,
                                             rstb_b + (size_t)l * CC, rb, rb);
    float* sw = xb; xb = rb; rb = sw;
  }
  // tail
  ln_fp32_kernel<<<grid_lf, 256, 0, stream>>>(xb, nf_s, nf_b, rb);
  conv_first_kernel<<<grid_tc, 256, 0, stream>>>(es, jp, cf_w, cf_b, xb);
  conv96m_kernel<<<1024, 256, 0, stream>>>(rb, wcb, body_b, xb, xb);
  conv_last_kernel<<<(BB * 32 * 32 * 2) / 256, 256, 0, stream>>>(xb, last_w, last_b, (float*)d_out);
}

// Round 15
// 3889.766 us; speedup vs baseline: 2.6306x; 1.0578x over previous
//
#include <hip/hip_runtime.h>
#include <hip/hip_bf16.h>
#include <cstddef>
#include <cstdint>

#define BB 64
#define HH 32
#define WW_ 32
#define CC 96
#define WS 8
#define NH 6
#define NL 4
#define ND 6
#define T_TOK (BB*HH*WW_)      // 65536 tokens
#define TC ((size_t)T_TOK*CC)  // 6291456 floats

typedef long long ll;
typedef __attribute__((ext_vector_type(8))) short short8;
typedef __attribute__((ext_vector_type(4))) float f32x4;
typedef __attribute__((ext_vector_type(4))) unsigned short ushort4v;

// Harness-named kernel symbol.
__global__ void JNetSwinIR_41034117546277_kernel() {}

__device__ __forceinline__ unsigned short f2bf(float f) {
  unsigned u = __float_as_uint(f);
  unsigned r = (u + 0x7FFF + ((u >> 16) & 1)) >> 16;
  return (unsigned short)r;
}
__device__ __forceinline__ float bf2f(unsigned short h) {
  return __uint_as_float(((unsigned)h) << 16);
}

// ---------------------------------------------------------------- diagnostic fill
__global__ __launch_bounds__(256) void fill_kernel(float* p, float v, int n)
{
  const int idx = blockIdx.x * 256 + threadIdx.x;
  if (idx < n) p[idx] = v;
}

// ---------------------------------------------------------------- weight fp32->bf16 transpose
__global__ __launch_bounds__(256) void wconv_kernel(
    const float* __restrict__ W, unsigned short* __restrict__ Wt, int K, int N)
{
  const int ld = blockIdx.y;
  const int idx = blockIdx.x * 256 + threadIdx.x;
  if (idx >= K * N) return;
  const int k = idx / N, n = idx % N;
  Wt[(size_t)ld * K * N + (size_t)n * K + k] = f2bf(W[(size_t)ld * K * N + idx]);
}

// conv weights [L][3][3][ic][oc] fp32 -> [L][9][oc][ic] bf16
__global__ __launch_bounds__(256) void wconv_conv_kernel(
    const float* __restrict__ W, unsigned short* __restrict__ Wt, int total)
{
  const int idx = blockIdx.x * 256 + threadIdx.x;
  if (idx >= total) return;
  const int l9 = idx / 9216;
  const int rest = idx % 9216;
  const int oc = rest / 96, ic = rest % 96;
  Wt[idx] = f2bf(W[(size_t)(l9 * 96 + ic) * 96 + oc]);
}

// ---------------------------------------------------------------- LayerNorm fp32 (stem/tail), optional dual write
__global__ __launch_bounds__(256) void ln_fp32_kernel(
    const float* __restrict__ x, const float* __restrict__ gamma,
    const float* __restrict__ beta, float* __restrict__ out, float* out2)
{
  const int wave = threadIdx.x >> 6;
  const int lane = threadIdx.x & 63;
  const int t = blockIdx.x * 4 + wave;
  const float* xp = x + (size_t)t * CC;
  const float v0 = xp[lane];
  const float v1 = (lane < 32) ? xp[64 + lane] : 0.f;
  float s = v0 + v1, s2 = v0 * v0 + v1 * v1;
  #pragma unroll
  for (int off = 32; off; off >>= 1) {
    s  += __shfl_xor(s,  off);
    s2 += __shfl_xor(s2, off);
  }
  const float mean = s * (1.f / 96.f);
  const float var  = s2 * (1.f / 96.f) - mean * mean;
  const float inv  = rsqrtf(var + 1e-5f);
  const float r0 = (v0 - mean) * inv * gamma[lane] + beta[lane];
  const float r1 = (v1 - mean) * inv * gamma[64 + lane] + beta[64 + lane];
  out[(size_t)t * CC + lane] = r0;
  if (lane < 32) out[(size_t)t * CC + 64 + lane] = r1;
  if (out2) {
    out2[(size_t)t * CC + lane] = r0;
    if (lane < 32) out2[(size_t)t * CC + 64 + lane] = r1;
  }
}

// ---------------------------------------------------------------- fully fused swin block (MFMA attention)
// one block per window, 384 thr = 6 waves (wave = head).
__global__ __launch_bounds__(384) void swin_block_fused(
    float* x, const float* __restrict__ n1s, const float* __restrict__ n1b,
    const unsigned short* __restrict__ wq_ld, const float* __restrict__ qkvb,
    const float* __restrict__ rpb_ld,
    const unsigned short* __restrict__ wp_ld, const float* __restrict__ projb,
    const float* __restrict__ n2s, const float* __restrict__ n2b,
    const unsigned short* __restrict__ w1_ld, const float* __restrict__ f1b,
    const unsigned short* __restrict__ w2_ld, const float* __restrict__ f2b,
    int shift)
{
  const int widx = blockIdx.x;
  const int tid  = threadIdx.x;
  const int wv   = tid >> 6;      // 0..5 (= head)
  const int lane = tid & 63;

  // LDS layout with phase overlays (total 73496 B):
  //  0      a     [64][104] u16  13312   (all phases)
  //  13312  kk    [64][104] u16  13312 | xacc [64][100] f32 25600 (13312..38912)
  //  26624  vvT   [96][72]  u16  13824   (ends 40448)
  //  40448  qt    [64][104] u16  13312 | hbuf [64][200] u16 25600 (40448..66048)
  //  53760  pbuf  [6][16][72]u16 13824   (ends 67584)
  //  67584  bias  [1350]    f32   5400
  //  72984  reg_s [64]      i32    256
  //  73240  st_s  [64]      i32    256
  __shared__ __attribute__((aligned(16))) char smem[73496];
  auto a    = (unsigned short(*)[104])(smem);
  auto kk   = (unsigned short(*)[104])(smem + 13312);
  auto xacc = (float(*)[100])(smem + 13312);
  unsigned short* vvT = (unsigned short*)(smem + 26624);
  auto qt   = (unsigned short(*)[104])(smem + 40448);
  auto hbuf = (unsigned short(*)[200])(smem + 40448);
  unsigned short* pbuf = (unsigned short*)(smem + 53760);
  float* bias_s = (float*)(smem + 67584);
  int*   reg_s  = (int*)(smem + 72984);
  int*   st_s   = (int*)(smem + 73240);

  if (tid < 64) {
    const int wimg = widx & 15;
    const int h = (wimg >> 2) * 8 + (tid >> 3);
    const int w = (wimg & 3) * 8 + (tid & 7);
    reg_s[tid] = 3 * (h < 24 ? 0 : (h < 28 ? 1 : 2)) +
                     (w < 24 ? 0 : (w < 28 ? 1 : 2));
    const int b = widx >> 4;
    const int p = (h + shift) & 31, q = (w + shift) & 31;
    st_s[tid] = (b << 10) + (p << 5) + q;
  }
  for (int i = tid; i < NH * 225; i += 384) {
    const int hh = i / 225, ii = i % 225;
    bias_s[i] = rpb_ld[ii * NH + hh];
  }
  __syncthreads();

  // phase 1: LN1
  for (int t = wv; t < 64; t += 6) {
    const float* xp = x + (size_t)st_s[t] * CC;
    const float v0 = xp[lane];
    const float v1 = (lane < 32) ? xp[64 + lane] : 0.f;
    float s = v0 + v1, s2 = v0 * v0 + v1 * v1;
    #pragma unroll
    for (int off = 32; off; off >>= 1) {
      s  += __shfl_xor(s,  off);
      s2 += __shfl_xor(s2, off);
    }
    const float mean = s * (1.f / 96.f);
    const float var  = s2 * (1.f / 96.f) - mean * mean;
    const float inv  = rsqrtf(var + 1e-5f);
    a[t][lane] = f2bf((v0 - mean) * inv * n1s[lane] + n1b[lane]);
    if (lane < 32)
      a[t][64 + lane] = f2bf((v1 - mean) * inv * n1s[64 + lane] + n1b[64 + lane]);
  }
  __syncthreads();

  // phase 2: qkv MFMA — wave = head; q->qt, k->kk (bf16), v->vvT (transposed)
  {
    const int row = lane & 15;
    const int ko  = (lane >> 4) * 8;
    const int cc  = lane & 15;
    const int cr0 = (lane >> 4) * 4;
    #pragma unroll
    for (int out3 = 0; out3 < 3; ++out3) {
      const int n0 = out3 * 96 + wv * 16;
      const unsigned short* bp = wq_ld + (size_t)(n0 + row) * 96 + ko;
      const float bz = qkvb[n0 + cc];
      #pragma unroll
      for (int rt = 0; rt < 4; ++rt) {
        f32x4 acc = {0.f, 0.f, 0.f, 0.f};
        const unsigned short* ap = &a[rt * 16 + row][ko];
        #pragma unroll
        for (int k0 = 0; k0 < 96; k0 += 32) {
          const short8 af = *(const short8*)(ap + k0);
          const short8 bf = *(const short8*)(bp + k0);
          acc = __builtin_amdgcn_mfma_f32_16x16x32_bf16(af, bf, acc, 0, 0, 0);
        }
        #pragma unroll
        for (int r = 0; r < 4; ++r) {
          const int tok = rt * 16 + cr0 + r;
          const float v = acc[r] + bz;
          if (out3 == 0)      qt[tok][wv * 16 + cc] = f2bf(v);
          else if (out3 == 1) kk[tok][wv * 16 + cc] = f2bf(v);
          else                vvT[(wv * 16 + cc) * 72 + tok] = f2bf(v);
        }
      }
    }
  }
  __syncthreads();

  // phase 3: MFMA attention — wave = head
  {
    const int head = wv;
    const int g  = lane >> 4;       // 0..3
    const int cc = lane & 15;
    const bool lo = (lane < 32);
    const float* bias_h = bias_s + head * 225;
    unsigned short* pb = pbuf + head * (16 * 72);
    const short8 z8 = {0, 0, 0, 0, 0, 0, 0, 0};
    // V fragments (loop-invariant): B-frag row = dim-within-head, k = key
    short8 vf0, vf1;
    {
      const unsigned short* vp = vvT + (size_t)(head * 16 + cc) * 72 + g * 8;
      vf0 = *(const short8*)(vp);
      vf1 = *(const short8*)(vp + 32);
    }
    #pragma unroll
    for (int qtile = 0; qtile < 4; ++qtile) {
      // S tiles: zero-masked K=16 via lane<32 predicate
      short8 af = z8;
      if (lo) af = *(const short8*)&qt[qtile * 16 + cc][head * 16 + g * 8];
      f32x4 sa[4];
      #pragma unroll
      for (int kt = 0; kt < 4; ++kt) {
        short8 bf = z8;
        if (lo) bf = *(const short8*)&kk[kt * 16 + cc][head * 16 + g * 8];
        const f32x4 zero = {0.f, 0.f, 0.f, 0.f};
        sa[kt] = __builtin_amdgcn_mfma_f32_16x16x32_bf16(af, bf, zero, 0, 0, 0);
      }
      // bias + mask + softmax (C-layout: row=g*4+r (query), col=cc (key))
      float p[4][4];
      #pragma unroll
      for (int r = 0; r < 4; ++r) {
        const int i = qtile * 16 + g * 4 + r;
        const int ih = i >> 3, iw = i & 7;
        const int ri = reg_s[i];
        float mx = -1e30f;
        #pragma unroll
        for (int kt = 0; kt < 4; ++kt) {
          const int j = kt * 16 + cc;
          const int idx = (ih - (j >> 3) + 7) * 15 + (iw - (j & 7) + 7);
          float v = sa[kt][r] * 0.25f + bias_h[idx];
          if (shift && reg_s[j] != ri) v -= 100.f;
          p[kt][r] = v;
          mx = fmaxf(mx, v);
        }
        mx = fmaxf(mx, __shfl_xor(mx, 1));
        mx = fmaxf(mx, __shfl_xor(mx, 2));
        mx = fmaxf(mx, __shfl_xor(mx, 4));
        mx = fmaxf(mx, __shfl_xor(mx, 8));
        float sum = 0.f;
        #pragma unroll
        for (int kt = 0; kt < 4; ++kt) {
          p[kt][r] = __expf(p[kt][r] - mx);
          sum += p[kt][r];
        }
        sum += __shfl_xor(sum, 1);
        sum += __shfl_xor(sum, 2);
        sum += __shfl_xor(sum, 4);
        sum += __shfl_xor(sum, 8);
        const float is = 1.f / sum;
        #pragma unroll
        for (int kt = 0; kt < 4; ++kt)
          pb[(g * 4 + r) * 72 + kt * 16 + cc] = f2bf(p[kt][r] * is);
      }
      // PV: A = P (rows=query, k=key), B = vvT (rows=dim, k=key); wave-local pbuf
      f32x4 oa = {0.f, 0.f, 0.f, 0.f};
      {
        const unsigned short* pp = pb + cc * 72 + g * 8;
        const short8 pf0 = *(const short8*)(pp);
        const short8 pf1 = *(const short8*)(pp + 32);
        oa = __builtin_amdgcn_mfma_f32_16x16x32_bf16(pf0, vf0, oa, 0, 0, 0);
        oa = __builtin_amdgcn_mfma_f32_16x16x32_bf16(pf1, vf1, oa, 0, 0, 0);
      }
      #pragma unroll
      for (int r = 0; r < 4; ++r)
        a[qtile * 16 + g * 4 + r][head * 16 + cc] = f2bf(oa[r]);
    }
  }
  __syncthreads();

  // phase 4: proj MFMA; xacc = x_old + proj + bias (LDS)
  {
    const int row = lane & 15;
    const int ko  = (lane >> 4) * 8;
    const int cc  = lane & 15;
    const int cr0 = (lane >> 4) * 4;
    const int n0 = wv * 16;
    const unsigned short* bp = wp_ld + (size_t)(n0 + row) * 96 + ko;
    const float bz = projb[n0 + cc];
    #pragma unroll
    for (int rt = 0; rt < 4; ++rt) {
      f32x4 acc = {0.f, 0.f, 0.f, 0.f};
      const unsigned short* ap = &a[rt * 16 + row][ko];
      #pragma unroll
      for (int k0 = 0; k0 < 96; k0 += 32) {
        const short8 af = *(const short8*)(ap + k0);
        const short8 bf = *(const short8*)(bp + k0);
        acc = __builtin_amdgcn_mfma_f32_16x16x32_bf16(af, bf, acc, 0, 0, 0);
      }
      #pragma unroll
      for (int r = 0; r < 4; ++r) {
        const int tok = rt * 16 + cr0 + r;
        const float xo = x[(size_t)st_s[tok] * CC + n0 + cc];
        xacc[tok][n0 + cc] = xo + acc[r] + bz;
      }
    }
  }
  __syncthreads();

  // phase 5: LN2 from xacc -> a
  for (int t = wv; t < 64; t += 6) {
    const float v0 = xacc[t][lane];
    const float v1 = (lane < 32) ? xacc[t][64 + lane] : 0.f;
    float s = v0 + v1, s2 = v0 * v0 + v1 * v1;
    #pragma unroll
    for (int off = 32; off; off >>= 1) {
      s  += __shfl_xor(s,  off);
      s2 += __shfl_xor(s2, off);
    }
    const float mean = s * (1.f / 96.f);
    const float var  = s2 * (1.f / 96.f) - mean * mean;
    const float inv  = rsqrtf(var + 1e-5f);
    a[t][lane] = f2bf((v0 - mean) * inv * n2s[lane] + n2b[lane]);
    if (lane < 32)
      a[t][64 + lane] = f2bf((v1 - mean) * inv * n2s[64 + lane] + n2b[64 + lane]);
  }
  __syncthreads();

  // phase 6: MLP in two K-passes
  const int row = lane & 15;
  const int ko  = (lane >> 4) * 8;
  const int cc  = lane & 15;
  const int cr0 = (lane >> 4) * 4;
  f32x4 acc2[4];
  #pragma unroll
  for (int i = 0; i < 4; ++i) acc2[i] = (f32x4){0.f, 0.f, 0.f, 0.f};
  #pragma unroll
  for (int p = 0; p < 2; ++p) {
    #pragma unroll
    for (int ct = 0; ct < 2; ++ct) {
      const int n0g = p * 192 + wv * 32 + ct * 16;
      const int n0l = wv * 32 + ct * 16;
      const unsigned short* bp = w1_ld + (size_t)(n0g + row) * 96 + ko;
      const float bz = f1b[n0g + cc];
      #pragma unroll
      for (int rt = 0; rt < 4; ++rt) {
        f32x4 acc = {0.f, 0.f, 0.f, 0.f};
        const unsigned short* ap = &a[rt * 16 + row][ko];
        #pragma unroll
        for (int k0 = 0; k0 < 96; k0 += 32) {
          const short8 af = *(const short8*)(ap + k0);
          const short8 bf = *(const short8*)(bp + k0);
          acc = __builtin_amdgcn_mfma_f32_16x16x32_bf16(af, bf, acc, 0, 0, 0);
        }
        #pragma unroll
        for (int r = 0; r < 4; ++r) {
          float v = acc[r] + bz;
          v = 0.5f * v * (1.f + erff(v * 0.70710678118f));
          hbuf[rt * 16 + cr0 + r][n0l + cc] = f2bf(v);
        }
      }
    }
    __syncthreads();
    {
      const int n0 = wv * 16;
      const unsigned short* bp = w2_ld + (size_t)(n0 + row) * 384 + p * 192 + ko;
      #pragma unroll
      for (int rt = 0; rt < 4; ++rt) {
        const unsigned short* ap = &hbuf[rt * 16 + row][ko];
        #pragma unroll
        for (int k0 = 0; k0 < 192; k0 += 32) {
          const short8 af = *(const short8*)(ap + k0);
          const short8 bf = *(const short8*)(bp + k0);
          acc2[rt] = __builtin_amdgcn_mfma_f32_16x16x32_bf16(af, bf, acc2[rt], 0, 0, 0);
        }
      }
    }
    __syncthreads();
  }

  // phase 7: final write x = xacc + fc2 + bias
  {
    const int n0 = wv * 16;
    const float bz = f2b[n0 + cc];
    #pragma unroll
    for (int rt = 0; rt < 4; ++rt) {
      #pragma unroll
      for (int r = 0; r < 4; ++r) {
        const int tok = rt * 16 + cr0 + r;
        x[(size_t)st_s[tok] * CC + n0 + cc] = xacc[tok][n0 + cc] + acc2[rt][r] + bz;
      }
    }
  }
}

// ---------------------------------------------------------------- copy
__global__ __launch_bounds__(256) void copy_kernel(
    float* __restrict__ dst, const float* __restrict__ src)
{
  const int idx = blockIdx.x * 256 + threadIdx.x;
  dst[idx] = src[idx];
}

// ---------------------------------------------------------------- conv 3x3 96->96, MFMA implicit GEMM, optional dual write
__global__ __launch_bounds__(256) void conv96m_kernel(
    const float* __restrict__ x, const unsigned short* __restrict__ wt,
    const float* __restrict__ bias, const float* resid, float* out, float* out2)
{
  const int blk = blockIdx.x;
  const int b = blk >> 4, th = (blk >> 2) & 3, tw = blk & 3;
  const int h0 = th * 8, w0 = tw * 8;
  __shared__ unsigned short patch[100][104];
  for (int idx = threadIdx.x; idx < 100 * 24; idx += 256) {
    const int pp = idx / 24, c4 = (idx % 24) * 4;
    const int ph = pp / 10, pw = pp % 10;
    const int hh = h0 + ph - 1, ww = w0 + pw - 1;
    float4 v = {0.f, 0.f, 0.f, 0.f};
    if ((unsigned)hh < 32u && (unsigned)ww < 32u)
      v = *(const float4*)&x[(((size_t)b * 32 + hh) * 32 + ww) * 96 + c4];
    ushort4v o;
    o.x = f2bf(v.x); o.y = f2bf(v.y); o.z = f2bf(v.z); o.w = f2bf(v.w);
    *(ushort4v*)&patch[pp][c4] = o;
  }
  __syncthreads();
  const int wv = threadIdx.x >> 6, lane = threadIdx.x & 63;
  const int m0 = wv * 16;
  const int arow = lane & 15;
  const int ko  = (lane >> 4) * 8;
  const int px = m0 + arow;
  const int ph_ = px >> 3, pw_ = px & 7;
  f32x4 acc[6];
  #pragma unroll
  for (int i = 0; i < 6; ++i) acc[i] = (f32x4){0.f, 0.f, 0.f, 0.f};
  #pragma unroll
  for (int kh = 0; kh < 3; ++kh)
    #pragma unroll
    for (int kw = 0; kw < 3; ++kw) {
      const unsigned short* wbase = wt + (size_t)(kh * 3 + kw) * 9216;
      const unsigned short* prow = &patch[(ph_ + kh) * 10 + (pw_ + kw)][ko];
      #pragma unroll
      for (int k0 = 0; k0 < 96; k0 += 32) {
        const short8 af = *(const short8*)(prow + k0);
        #pragma unroll
        for (int nt = 0; nt < 6; ++nt) {
          const short8 bf = *(const short8*)(wbase + (size_t)(nt * 16 + arow) * 96 + ko + k0);
          acc[nt] = __builtin_amdgcn_mfma_f32_16x16x32_bf16(af, bf, acc[nt], 0, 0, 0);
        }
      }
    }
  const int cc = lane & 15;
  const int cr0 = (lane >> 4) * 4;
  #pragma unroll
  for (int nt = 0; nt < 6; ++nt) {
    const int oc = nt * 16 + cc;
    const float bz = bias[oc];
    #pragma unroll
    for (int r = 0; r < 4; ++r) {
      const int p = m0 + cr0 + r;
      const int h = p >> 3, w = p & 7;
      const size_t t = (((size_t)b * 32 + h0 + h) * 32 + (w0 + w));
      float v = acc[nt][r] + bz;
      if (resid) v += resid[t * 96 + oc];
      out[t * 96 + oc] = v;
      if (out2) out2[t * 96 + oc] = v;
    }
  }
}

// ---------------------------------------------------------------- conv stem 4->96
__global__ __launch_bounds__(256) void conv_first_kernel(
    const float* __restrict__ es, const float* __restrict__ jp,
    const float* __restrict__ wgt, const float* __restrict__ bias,
    float* __restrict__ xf)
{
  const int idx = blockIdx.x * 256 + threadIdx.x;
  const int oc = idx % 96;
  const int pos = idx / 96;
  const int w = pos % 32, hp = (pos / 32) % 32, b = pos / 1024;
  float acc = bias[oc];
  for (int kh = 0; kh < 3; ++kh) {
    const int hh = hp + kh - 1;
    if ((unsigned)hh >= 32u) continue;
    for (int kw = 0; kw < 3; ++kw) {
      const int ww = w + kw - 1;
      if ((unsigned)ww >= 32u) continue;
      const size_t sp = ((size_t)b * 2 * 32 + hh) * 32 + ww;
      const float i0 = es[sp];
      const float i1 = es[sp + 1024];
      const float i2 = jp[sp];
      const float i3 = jp[sp + 1024];
      const float* wr = wgt + (size_t)((kh * 3 + kw) * 4) * 96 + oc;
      acc = fmaf(i0, wr[0], acc);
      acc = fmaf(i1, wr[96], acc);
      acc = fmaf(i2, wr[192], acc);
      acc = fmaf(i3, wr[288], acc);
    }
  }
  xf[idx] = acc;
}

// ---------------------------------------------------------------- conv tail 96->2
__global__ __launch_bounds__(256) void conv_last_kernel(
    const float* __restrict__ res, const float* __restrict__ wgt,
    const float* __restrict__ bias, float* __restrict__ out)
{
  const int idx = blockIdx.x * 256 + threadIdx.x;
  const int oc = idx % 2;
  const int pos = idx / 2;
  const int w = pos % 32, hp = (pos / 32) % 32, b = pos / 1024;
  float acc = bias[oc];
  for (int kh = 0; kh < 3; ++kh) {
    const int hh = hp + kh - 1;
    if ((unsigned)hh >= 32u) continue;
    for (int kw = 0; kw < 3; ++kw) {
      const int ww = w + kw - 1;
      if ((unsigned)ww >= 32u) continue;
      const float* pr = res + (((size_t)b * 32 + hh) * 32 + ww) * 96;
      const float* wr = wgt + (size_t)((kh * 3 + kw) * 96) * 2 + oc;
      #pragma unroll 8
      for (int ic = 0; ic < 96; ++ic)
        acc = fmaf(pr[ic], wr[ic * 2], acc);
    }
  }
  out[(((size_t)b * 2 + oc) * 32 + hp) * 32 + w] = acc;
}

// ---------------------------------------------------------------- host
extern "C" void kernel_launch(void* const* d_in, const int* in_sizes, int n_in,
                              void* d_out, int out_size, void* d_ws, size_t ws_size,
                              hipStream_t stream)
{
  const int fill_grid = (out_size + 255) / 256;

  if (n_in != 27) {
    fill_kernel<<<fill_grid, 256, 0, stream>>>((float*)d_out, 200.0f + (float)n_in, out_size);
    return;
  }
  static const int expected_sizes[27] = {
    131072, 131072, 3456, 96, 96, 96, 2304, 2304, 663552, 6912,
    221184, 2304, 32400, 2304, 2304, 884736, 9216, 884736, 2304,
    331776, 384, 96, 96, 82944, 96, 1728, 2
  };
  for (int i = 0; i < 27; ++i) {
    if (in_sizes[i] != expected_sizes[i]) {
      fill_kernel<<<fill_grid, 256, 0, stream>>>((float*)d_out, 300.0f + (float)i, out_size);
      return;
    }
  }
  if (out_size != 131072) {
    fill_kernel<<<fill_grid, 256, 0, stream>>>((float*)d_out, 400.0f, out_size);
    return;
  }
  const uintptr_t raw = (uintptr_t)d_ws;
  const uintptr_t alignedp = (raw + 255) & ~(uintptr_t)255;
  const size_t ws_avail_bytes = (ws_size > (alignedp - raw)) ? ws_size - (alignedp - raw) : 0;
  const size_t avail = ws_avail_bytes / 4;   // floats
  const size_t WBUF_F = 1534464;             // all bf16 weights, float units
  if (avail < 2 * TC + WBUF_F) {
    fill_kernel<<<fill_grid, 256, 0, stream>>>((float*)d_out,
        100.0f + (float)(ws_size >> 20), out_size);
    return;
  }
  const bool rot = (avail >= 3 * TC + WBUF_F);   // 3-buffer rotation (no copies)

  const float* es      = (const float*)d_in[0];
  const float* jp      = (const float*)d_in[1];
  const float* cf_w    = (const float*)d_in[2];
  const float* cf_b    = (const float*)d_in[3];
  const float* pe_s    = (const float*)d_in[4];
  const float* pe_b    = (const float*)d_in[5];
  const float* n1_s    = (const float*)d_in[6];
  const float* n1_b    = (const float*)d_in[7];
  const float* qkv_w   = (const float*)d_in[8];
  const float* qkv_b   = (const float*)d_in[9];
  const float* proj_w  = (const float*)d_in[10];
  const float* proj_b  = (const float*)d_in[11];
  const float* rpb     = (const float*)d_in[12];
  const float* n2_s    = (const float*)d_in[13];
  const float* n2_b    = (const float*)d_in[14];
  const float* fc1_w   = (const float*)d_in[15];
  const float* fc1_b   = (const float*)d_in[16];
  const float* fc2_w   = (const float*)d_in[17];
  const float* fc2_b   = (const float*)d_in[18];
  const float* rstb_w  = (const float*)d_in[19];
  const float* rstb_b  = (const float*)d_in[20];
  const float* nf_s    = (const float*)d_in[21];
  const float* nf_b    = (const float*)d_in[22];
  const float* body_w  = (const float*)d_in[23];
  const float* body_b  = (const float*)d_in[24];
  const float* last_w  = (const float*)d_in[25];
  const float* last_b  = (const float*)d_in[26];

  float* base = (float*)alignedp;
  float* x  = base;
  float* r  = base + TC;
  float* sp = rot ? base + 2 * TC : nullptr;
  unsigned short* wq  = (unsigned short*)(base + (rot ? 3 : 2) * TC);
  unsigned short* wpj = wq + 663552;
  unsigned short* w1  = wpj + 221184;
  unsigned short* w2  = w1 + 884736;
  unsigned short* wcr = w2 + 884736;
  unsigned short* wcb = wcr + 331776;

  const int grid_tc = (int)(TC / 256);
  const int grid_lf = T_TOK / 4;
  const int nwin = T_TOK / 64;                       // 1024

  // weight convert+transpose
  wconv_kernel<<<dim3((96 * 288 + 255) / 256, 24), 256, 0, stream>>>(qkv_w, wq, 96, 288);
  wconv_kernel<<<dim3((96 * 96 + 255) / 256, 24), 256, 0, stream>>>(proj_w, wpj, 96, 96);
  wconv_kernel<<<dim3((96 * 384 + 255) / 256, 24), 256, 0, stream>>>(fc1_w, w1, 96, 384);
  wconv_kernel<<<dim3((384 * 96 + 255) / 256, 24), 256, 0, stream>>>(fc2_w, w2, 384, 96);
  wconv_conv_kernel<<<(331776 + 255) / 256, 256, 0, stream>>>(rstb_w, wcr, 331776);
  wconv_conv_kernel<<<(82944 + 255) / 256, 256, 0, stream>>>(body_w, wcb, 82944);

  // stem
  conv_first_kernel<<<grid_tc, 256, 0, stream>>>(es, jp, cf_w, cf_b, x);
  ln_fp32_kernel<<<grid_lf, 256, 0, stream>>>(x, pe_s, pe_b, x, rot ? r : nullptr);

  float* xb = x;
  float* rb = r;
  float* sb = sp;
  for (int l = 0; l < NL; ++l) {
    if (!rot) copy_kernel<<<grid_tc, 256, 0, stream>>>(rb, xb);
    for (int d = 0; d < ND; ++d) {
      const int ld = l * ND + d;
      const int shift = (d & 1) ? 4 : 0;
      swin_block_fused<<<nwin, 384, 0, stream>>>(
          xb, n1_s + ld * CC, n1_b + ld * CC,
          wq + (size_t)ld * 288 * 96, qkv_b + (size_t)ld * 288,
          rpb + (size_t)ld * 225 * NH,
          wpj + (size_t)ld * 96 * 96, proj_b + (size_t)ld * 96,
          n2_s + ld * CC, n2_b + ld * CC,
          w1 + (size_t)ld * 384 * 96, fc1_b + (size_t)ld * 384,
          w2 + (size_t)ld * 96 * 384, fc2_b + (size_t)ld * 96, shift);
    }
    if (rot) {
      // rb <- conv(xb)+rb; sb <- same value; next x = sb, spare = old xb
      conv96m_kernel<<<1024, 256, 0, stream>>>(xb, wcr + (size_t)l * 9 * 9216,
                                               rstb_b + (size_t)l * CC, rb, rb, sb);
      float* t = xb; xb = sb; sb = t;
    } else {
      conv96m_kernel<<<1024, 256, 0, stream>>>(xb, wcr + (size_t)l * 9 * 9216,
                                               rstb_b + (size_t)l * CC, rb, rb, nullptr);
      float* t = xb; xb = rb; rb = t;
    }
  }
  // tail
  ln_fp32_kernel<<<grid_lf, 256, 0, stream>>>(xb, nf_s, nf_b, rb, nullptr);
  conv_first_kernel<<<grid_tc, 256, 0, stream>>>(es, jp, cf_w, cf_b, xb);
  conv96m_kernel<<<1024, 256, 0, stream>>>(rb, wcb, body_b, xb, xb, nullptr);
  conv_last_kernel<<<(BB * 32 * 32 * 2) / 256, 256, 0, stream>>>(xb, last_w, last_b, (float*)d_out);
}

// Round 16
// 3324.467 us; speedup vs baseline: 3.0779x; 1.1700x over previous
//
#include <hip/hip_runtime.h>
#include <hip/hip_bf16.h>
#include <cstddef>
#include <cstdint>

#define BB 64
#define HH 32
#define WW_ 32
#define CC 96
#define WS 8
#define NH 6
#define NL 4
#define ND 6
#define T_TOK (BB*HH*WW_)      // 65536 tokens
#define TC ((size_t)T_TOK*CC)  // 6291456 floats

typedef long long ll;
typedef __attribute__((ext_vector_type(8))) short short8;
typedef __attribute__((ext_vector_type(4))) float f32x4;
typedef __attribute__((ext_vector_type(4))) unsigned short ushort4v;

// Harness-named kernel symbol.
__global__ void JNetSwinIR_41034117546277_kernel() {}

__device__ __forceinline__ unsigned short f2bf(float f) {
  unsigned u = __float_as_uint(f);
  unsigned r = (u + 0x7FFF + ((u >> 16) & 1)) >> 16;
  return (unsigned short)r;
}
__device__ __forceinline__ float bf2f(unsigned short h) {
  return __uint_as_float(((unsigned)h) << 16);
}

// ---------------------------------------------------------------- diagnostic fill
__global__ __launch_bounds__(256) void fill_kernel(float* p, float v, int n)
{
  const int idx = blockIdx.x * 256 + threadIdx.x;
  if (idx < n) p[idx] = v;
}

// ---------------------------------------------------------------- weight fp32->bf16 transpose
__global__ __launch_bounds__(256) void wconv_kernel(
    const float* __restrict__ W, unsigned short* __restrict__ Wt, int K, int N)
{
  const int ld = blockIdx.y;
  const int idx = blockIdx.x * 256 + threadIdx.x;
  if (idx >= K * N) return;
  const int k = idx / N, n = idx % N;
  Wt[(size_t)ld * K * N + (size_t)n * K + k] = f2bf(W[(size_t)ld * K * N + idx]);
}

// conv weights [L][3][3][ic][oc] fp32 -> [L][9][oc][ic] bf16
__global__ __launch_bounds__(256) void wconv_conv_kernel(
    const float* __restrict__ W, unsigned short* __restrict__ Wt, int total)
{
  const int idx = blockIdx.x * 256 + threadIdx.x;
  if (idx >= total) return;
  const int l9 = idx / 9216;
  const int rest = idx % 9216;
  const int oc = rest / 96, ic = rest % 96;
  Wt[idx] = f2bf(W[(size_t)(l9 * 96 + ic) * 96 + oc]);
}

// rpb [24][225][6] fp32 -> rpbT [24][6][225] fp32
__global__ __launch_bounds__(256) void rpbt_kernel(
    const float* __restrict__ R, float* __restrict__ Rt)
{
  const int idx = blockIdx.x * 256 + threadIdx.x;
  if (idx >= 24 * 1350) return;
  const int ld = idx / 1350, rest = idx % 1350;
  const int h = rest / 225, ii = rest % 225;
  Rt[idx] = R[(size_t)ld * 1350 + ii * 6 + h];
}

// ---------------------------------------------------------------- LayerNorm fp32 (stem/tail), optional dual write
__global__ __launch_bounds__(256) void ln_fp32_kernel(
    const float* __restrict__ x, const float* __restrict__ gamma,
    const float* __restrict__ beta, float* __restrict__ out, float* out2)
{
  const int wave = threadIdx.x >> 6;
  const int lane = threadIdx.x & 63;
  const int t = blockIdx.x * 4 + wave;
  const float* xp = x + (size_t)t * CC;
  const float v0 = xp[lane];
  const float v1 = (lane < 32) ? xp[64 + lane] : 0.f;
  float s = v0 + v1, s2 = v0 * v0 + v1 * v1;
  #pragma unroll
  for (int off = 32; off; off >>= 1) {
    s  += __shfl_xor(s,  off);
    s2 += __shfl_xor(s2, off);
  }
  const float mean = s * (1.f / 96.f);
  const float var  = s2 * (1.f / 96.f) - mean * mean;
  const float inv  = rsqrtf(var + 1e-5f);
  const float r0 = (v0 - mean) * inv * gamma[lane] + beta[lane];
  const float r1 = (v1 - mean) * inv * gamma[64 + lane] + beta[64 + lane];
  out[(size_t)t * CC + lane] = r0;
  if (lane < 32) out[(size_t)t * CC + 64 + lane] = r1;
  if (out2) {
    out2[(size_t)t * CC + lane] = r0;
    if (lane < 32) out2[(size_t)t * CC + 64 + lane] = r1;
  }
}

// ---------------------------------------------------------------- fully fused swin block
// one block per window, 512 thr = 8 waves. LDS 54016 B -> 3 blocks/CU.
__global__ __launch_bounds__(512) void swin_block_fused(
    float* x, const float* __restrict__ n1s, const float* __restrict__ n1b,
    const unsigned short* __restrict__ wq_ld, const float* __restrict__ qkvb,
    const float* __restrict__ rpbt_ld,
    const unsigned short* __restrict__ wp_ld, const float* __restrict__ projb,
    const float* __restrict__ n2s, const float* __restrict__ n2b,
    const unsigned short* __restrict__ w1_ld, const float* __restrict__ f1b,
    const unsigned short* __restrict__ w2_ld, const float* __restrict__ f2b,
    int shift)
{
  const int widx = blockIdx.x;
  const int tid  = threadIdx.x;
  const int wv   = tid >> 6;      // 0..7
  const int lane = tid & 63;

  // LDS layout (54016 B total):
  //  0      a    [64][104] u16 13312   (LN1/attn-out/LN2-out)
  //  13312  kk   [64][104] u16 13312 (ph2-3) | xacc [64][100] f32 25600 (ph4+, 13312..38912)
  //  26624  vvT  [96][72]  u16 13824 (ph2-3; per-head pbuf overlay in ph3)
  //  40448  qt   [64][104] u16 13312 (ph2-3) | hbuf [64][104] u16 (ph6)
  //  53760  st_s u16[64] 128 ; reg_s i16[64] 128  -> 54016
  __shared__ __attribute__((aligned(16))) char smem[54016];
  auto a    = (unsigned short(*)[104])(smem);
  auto kk   = (unsigned short(*)[104])(smem + 13312);
  auto xacc = (float(*)[100])(smem + 13312);
  unsigned short* vvT = (unsigned short*)(smem + 26624);
  auto qt   = (unsigned short(*)[104])(smem + 40448);
  auto hbuf = (unsigned short(*)[104])(smem + 40448);
  unsigned short* st_s = (unsigned short*)(smem + 53760);
  short*          reg_s = (short*)(smem + 53888);

  if (tid < 64) {
    const int wimg = widx & 15;
    const int h = (wimg >> 2) * 8 + (tid >> 3);
    const int w = (wimg & 3) * 8 + (tid & 7);
    reg_s[tid] = (short)(3 * (h < 24 ? 0 : (h < 28 ? 1 : 2)) +
                             (w < 24 ? 0 : (w < 28 ? 1 : 2)));
    const int b = widx >> 4;
    const int p = (h + shift) & 31, q = (w + shift) & 31;
    st_s[tid] = (unsigned short)((b << 10) + (p << 5) + q);
  }
  __syncthreads();

  const int row = lane & 15;
  const int ko  = (lane >> 4) * 8;
  const int cc  = lane & 15;
  const int cr0 = (lane >> 4) * 4;

  // phase 1: LN1 (8 tokens per wave)
  for (int t = wv; t < 64; t += 8) {
    const float* xp = x + (size_t)st_s[t] * CC;
    const float v0 = xp[lane];
    const float v1 = (lane < 32) ? xp[64 + lane] : 0.f;
    float s = v0 + v1, s2 = v0 * v0 + v1 * v1;
    #pragma unroll
    for (int off = 32; off; off >>= 1) {
      s  += __shfl_xor(s,  off);
      s2 += __shfl_xor(s2, off);
    }
    const float mean = s * (1.f / 96.f);
    const float var  = s2 * (1.f / 96.f) - mean * mean;
    const float inv  = rsqrtf(var + 1e-5f);
    a[t][lane] = f2bf((v0 - mean) * inv * n1s[lane] + n1b[lane]);
    if (lane < 32)
      a[t][64 + lane] = f2bf((v1 - mean) * inv * n1s[64 + lane] + n1b[64 + lane]);
  }
  __syncthreads();

  // phase 2: qkv MFMA — 72 output tiles (4 row x 18 col) over 8 waves
  for (int tt = wv; tt < 72; tt += 8) {
    const int rt = tt / 18, ct = tt % 18;
    const int n0g = ct * 16;
    const unsigned short* bp = wq_ld + (size_t)(n0g + row) * 96 + ko;
    const float bz = qkvb[n0g + cc];
    f32x4 acc = {0.f, 0.f, 0.f, 0.f};
    const unsigned short* ap = &a[rt * 16 + row][ko];
    #pragma unroll
    for (int k0 = 0; k0 < 96; k0 += 32) {
      const short8 af = *(const short8*)(ap + k0);
      const short8 bf = *(const short8*)(bp + k0);
      acc = __builtin_amdgcn_mfma_f32_16x16x32_bf16(af, bf, acc, 0, 0, 0);
    }
    #pragma unroll
    for (int r = 0; r < 4; ++r) {
      const int tok = rt * 16 + cr0 + r;
      const float v = acc[r] + bz;
      if (ct < 6)       qt[tok][ct * 16 + cc] = f2bf(v);
      else if (ct < 12) kk[tok][(ct - 6) * 16 + cc] = f2bf(v);
      else              vvT[((ct - 12) * 16 + cc) * 72 + tok] = f2bf(v);
    }
  }
  __syncthreads();

  // phase 3: MFMA attention — waves 0..5 (wave = head); 6,7 idle
  if (wv < 6) {
    const int head = wv;
    const int g  = lane >> 4;
    const bool lo = (lane < 32);
    const float* bias_h = rpbt_ld + head * 225;
    unsigned short* pb = vvT + head * (16 * 72);   // overlay own head's vvT rows
    const short8 z8 = {0, 0, 0, 0, 0, 0, 0, 0};
    short8 vf0, vf1;
    {
      const unsigned short* vp = vvT + (size_t)(head * 16 + cc) * 72 + g * 8;
      vf0 = *(const short8*)(vp);
      vf1 = *(const short8*)(vp + 32);
    }
    #pragma unroll
    for (int qtile = 0; qtile < 4; ++qtile) {
      short8 af = z8;
      if (lo) af = *(const short8*)&qt[qtile * 16 + cc][head * 16 + g * 8];
      f32x4 sa[4];
      #pragma unroll
      for (int kt = 0; kt < 4; ++kt) {
        short8 bf = z8;
        if (lo) bf = *(const short8*)&kk[kt * 16 + cc][head * 16 + g * 8];
        const f32x4 zero = {0.f, 0.f, 0.f, 0.f};
        sa[kt] = __builtin_amdgcn_mfma_f32_16x16x32_bf16(af, bf, zero, 0, 0, 0);
      }
      float p[4][4];
      #pragma unroll
      for (int r = 0; r < 4; ++r) {
        const int i = qtile * 16 + g * 4 + r;
        const int ih = i >> 3, iw = i & 7;
        const int ri = reg_s[i];
        float mx = -1e30f;
        #pragma unroll
        for (int kt = 0; kt < 4; ++kt) {
          const int j = kt * 16 + cc;
          const int idx = (ih - (j >> 3) + 7) * 15 + (iw - (j & 7) + 7);
          float v = sa[kt][r] * 0.25f + bias_h[idx];
          if (shift && reg_s[j] != ri) v -= 100.f;
          p[kt][r] = v;
          mx = fmaxf(mx, v);
        }
        mx = fmaxf(mx, __shfl_xor(mx, 1));
        mx = fmaxf(mx, __shfl_xor(mx, 2));
        mx = fmaxf(mx, __shfl_xor(mx, 4));
        mx = fmaxf(mx, __shfl_xor(mx, 8));
        float sum = 0.f;
        #pragma unroll
        for (int kt = 0; kt < 4; ++kt) {
          p[kt][r] = __expf(p[kt][r] - mx);
          sum += p[kt][r];
        }
        sum += __shfl_xor(sum, 1);
        sum += __shfl_xor(sum, 2);
        sum += __shfl_xor(sum, 4);
        sum += __shfl_xor(sum, 8);
        const float is = 1.f / sum;
        #pragma unroll
        for (int kt = 0; kt < 4; ++kt)
          pb[(g * 4 + r) * 72 + kt * 16 + cc] = f2bf(p[kt][r] * is);
      }
      f32x4 oa = {0.f, 0.f, 0.f, 0.f};
      {
        const unsigned short* pp = pb + cc * 72 + g * 8;
        const short8 pf0 = *(const short8*)(pp);
        const short8 pf1 = *(const short8*)(pp + 32);
        oa = __builtin_amdgcn_mfma_f32_16x16x32_bf16(pf0, vf0, oa, 0, 0, 0);
        oa = __builtin_amdgcn_mfma_f32_16x16x32_bf16(pf1, vf1, oa, 0, 0, 0);
      }
      #pragma unroll
      for (int r = 0; r < 4; ++r)
        a[qtile * 16 + g * 4 + r][head * 16 + cc] = f2bf(oa[r]);
    }
  }
  __syncthreads();

  // phase 4: proj MFMA; xacc = x_old + proj + bias — 24 tiles over 8 waves
  for (int tt = wv; tt < 24; tt += 8) {
    const int rt = tt / 6, ct = tt % 6;
    const int n0 = ct * 16;
    const unsigned short* bp = wp_ld + (size_t)(n0 + row) * 96 + ko;
    const float bz = projb[n0 + cc];
    f32x4 acc = {0.f, 0.f, 0.f, 0.f};
    const unsigned short* ap = &a[rt * 16 + row][ko];
    #pragma unroll
    for (int k0 = 0; k0 < 96; k0 += 32) {
      const short8 af = *(const short8*)(ap + k0);
      const short8 bf = *(const short8*)(bp + k0);
      acc = __builtin_amdgcn_mfma_f32_16x16x32_bf16(af, bf, acc, 0, 0, 0);
    }
    #pragma unroll
    for (int r = 0; r < 4; ++r) {
      const int tok = rt * 16 + cr0 + r;
      const float xo = x[(size_t)st_s[tok] * CC + n0 + cc];
      xacc[tok][n0 + cc] = xo + acc[r] + bz;
    }
  }
  __syncthreads();

  // phase 5: LN2 from xacc -> a
  for (int t = wv; t < 64; t += 8) {
    const float v0 = xacc[t][lane];
    const float v1 = (lane < 32) ? xacc[t][64 + lane] : 0.f;
    float s = v0 + v1, s2 = v0 * v0 + v1 * v1;
    #pragma unroll
    for (int off = 32; off; off >>= 1) {
      s  += __shfl_xor(s,  off);
      s2 += __shfl_xor(s2, off);
    }
    const float mean = s * (1.f / 96.f);
    const float var  = s2 * (1.f / 96.f) - mean * mean;
    const float inv  = rsqrtf(var + 1e-5f);
    a[t][lane] = f2bf((v0 - mean) * inv * n2s[lane] + n2b[lane]);
    if (lane < 32)
      a[t][64 + lane] = f2bf((v1 - mean) * inv * n2s[64 + lane] + n2b[64 + lane]);
  }
  __syncthreads();

  // phase 6: MLP in 4 K-passes of 96 hidden cols; fc2 tiles fixed per wave
  f32x4 acc2[3];
  #pragma unroll
  for (int i = 0; i < 3; ++i) acc2[i] = (f32x4){0.f, 0.f, 0.f, 0.f};
  for (int p = 0; p < 4; ++p) {
    // fc1 + GELU: 24 tiles over 8 waves
    for (int tt = wv; tt < 24; tt += 8) {
      const int rt = tt / 6, ct = tt % 6;
      const int n0g = p * 96 + ct * 16;
      const unsigned short* bp = w1_ld + (size_t)(n0g + row) * 96 + ko;
      const float bz = f1b[n0g + cc];
      f32x4 acc = {0.f, 0.f, 0.f, 0.f};
      const unsigned short* ap = &a[rt * 16 + row][ko];
      #pragma unroll
      for (int k0 = 0; k0 < 96; k0 += 32) {
        const short8 af = *(const short8*)(ap + k0);
        const short8 bf = *(const short8*)(bp + k0);
        acc = __builtin_amdgcn_mfma_f32_16x16x32_bf16(af, bf, acc, 0, 0, 0);
      }
      #pragma unroll
      for (int r = 0; r < 4; ++r) {
        float v = acc[r] + bz;
        v = 0.5f * v * (1.f + erff(v * 0.70710678118f));
        hbuf[rt * 16 + cr0 + r][ct * 16 + cc] = f2bf(v);
      }
    }
    __syncthreads();
    // fc2 partial: 24 out tiles, 3 fixed per wave; K-slice [p*96, p*96+96)
    #pragma unroll
    for (int i = 0; i < 3; ++i) {
      const int tt2 = wv * 3 + i;
      const int rt = tt2 / 6, ct = tt2 % 6;
      const unsigned short* bp = w2_ld + (size_t)(ct * 16 + row) * 384 + p * 96 + ko;
      const unsigned short* ap = &hbuf[rt * 16 + row][ko];
      #pragma unroll
      for (int k0 = 0; k0 < 96; k0 += 32) {
        const short8 af = *(const short8*)(ap + k0);
        const short8 bf = *(const short8*)(bp + k0);
        acc2[i] = __builtin_amdgcn_mfma_f32_16x16x32_bf16(af, bf, acc2[i], 0, 0, 0);
      }
    }
    __syncthreads();
  }

  // phase 7: final write x = xacc + fc2 + bias
  #pragma unroll
  for (int i = 0; i < 3; ++i) {
    const int tt2 = wv * 3 + i;
    const int rt = tt2 / 6, ct = tt2 % 6;
    const int n0 = ct * 16;
    const float bz = f2b[n0 + cc];
    #pragma unroll
    for (int r = 0; r < 4; ++r) {
      const int tok = rt * 16 + cr0 + r;
      x[(size_t)st_s[tok] * CC + n0 + cc] = xacc[tok][n0 + cc] + acc2[i][r] + bz;
    }
  }
}

// ---------------------------------------------------------------- copy
__global__ __launch_bounds__(256) void copy_kernel(
    float* __restrict__ dst, const float* __restrict__ src)
{
  const int idx = blockIdx.x * 256 + threadIdx.x;
  dst[idx] = src[idx];
}

// ---------------------------------------------------------------- conv 3x3 96->96, MFMA implicit GEMM, optional dual write
__global__ __launch_bounds__(256) void conv96m_kernel(
    const float* __restrict__ x, const unsigned short* __restrict__ wt,
    const float* __restrict__ bias, const float* resid, float* out, float* out2)
{
  const int blk = blockIdx.x;
  const int b = blk >> 4, th = (blk >> 2) & 3, tw = blk & 3;
  const int h0 = th * 8, w0 = tw * 8;
  __shared__ unsigned short patch[100][104];
  for (int idx = threadIdx.x; idx < 100 * 24; idx += 256) {
    const int pp = idx / 24, c4 = (idx % 24) * 4;
    const int ph = pp / 10, pw = pp % 10;
    const int hh = h0 + ph - 1, ww = w0 + pw - 1;
    float4 v = {0.f, 0.f, 0.f, 0.f};
    if ((unsigned)hh < 32u && (unsigned)ww < 32u)
      v = *(const float4*)&x[(((size_t)b * 32 + hh) * 32 + ww) * 96 + c4];
    ushort4v o;
    o.x = f2bf(v.x); o.y = f2bf(v.y); o.z = f2bf(v.z); o.w = f2bf(v.w);
    *(ushort4v*)&patch[pp][c4] = o;
  }
  __syncthreads();
  const int wv = threadIdx.x >> 6, lane = threadIdx.x & 63;
  const int m0 = wv * 16;
  const int arow = lane & 15;
  const int ko  = (lane >> 4) * 8;
  const int px = m0 + arow;
  const int ph_ = px >> 3, pw_ = px & 7;
  f32x4 acc[6];
  #pragma unroll
  for (int i = 0; i < 6; ++i) acc[i] = (f32x4){0.f, 0.f, 0.f, 0.f};
  #pragma unroll
  for (int kh = 0; kh < 3; ++kh)
    #pragma unroll
    for (int kw = 0; kw < 3; ++kw) {
      const unsigned short* wbase = wt + (size_t)(kh * 3 + kw) * 9216;
      const unsigned short* prow = &patch[(ph_ + kh) * 10 + (pw_ + kw)][ko];
      #pragma unroll
      for (int k0 = 0; k0 < 96; k0 += 32) {
        const short8 af = *(const short8*)(prow + k0);
        #pragma unroll
        for (int nt = 0; nt < 6; ++nt) {
          const short8 bf = *(const short8*)(wbase + (size_t)(nt * 16 + arow) * 96 + ko + k0);
          acc[nt] = __builtin_amdgcn_mfma_f32_16x16x32_bf16(af, bf, acc[nt], 0, 0, 0);
        }
      }
    }
  const int cc = lane & 15;
  const int cr0 = (lane >> 4) * 4;
  #pragma unroll
  for (int nt = 0; nt < 6; ++nt) {
    const int oc = nt * 16 + cc;
    const float bz = bias[oc];
    #pragma unroll
    for (int r = 0; r < 4; ++r) {
      const int p = m0 + cr0 + r;
      const int h = p >> 3, w = p & 7;
      const size_t t = (((size_t)b * 32 + h0 + h) * 32 + (w0 + w));
      float v = acc[nt][r] + bz;
      if (resid) v += resid[t * 96 + oc];
      out[t * 96 + oc] = v;
      if (out2) out2[t * 96 + oc] = v;
    }
  }
}

// ---------------------------------------------------------------- conv stem 4->96
__global__ __launch_bounds__(256) void conv_first_kernel(
    const float* __restrict__ es, const float* __restrict__ jp,
    const float* __restrict__ wgt, const float* __restrict__ bias,
    float* __restrict__ xf)
{
  const int idx = blockIdx.x * 256 + threadIdx.x;
  const int oc = idx % 96;
  const int pos = idx / 96;
  const int w = pos % 32, hp = (pos / 32) % 32, b = pos / 1024;
  float acc = bias[oc];
  for (int kh = 0; kh < 3; ++kh) {
    const int hh = hp + kh - 1;
    if ((unsigned)hh >= 32u) continue;
    for (int kw = 0; kw < 3; ++kw) {
      const int ww = w + kw - 1;
      if ((unsigned)ww >= 32u) continue;
      const size_t sp = ((size_t)b * 2 * 32 + hh) * 32 + ww;
      const float i0 = es[sp];
      const float i1 = es[sp + 1024];
      const float i2 = jp[sp];
      const float i3 = jp[sp + 1024];
      const float* wr = wgt + (size_t)((kh * 3 + kw) * 4) * 96 + oc;
      acc = fmaf(i0, wr[0], acc);
      acc = fmaf(i1, wr[96], acc);
      acc = fmaf(i2, wr[192], acc);
      acc = fmaf(i3, wr[288], acc);
    }
  }
  xf[idx] = acc;
}

// ---------------------------------------------------------------- conv tail 96->2
__global__ __launch_bounds__(256) void conv_last_kernel(
    const float* __restrict__ res, const float* __restrict__ wgt,
    const float* __restrict__ bias, float* __restrict__ out)
{
  const int idx = blockIdx.x * 256 + threadIdx.x;
  const int oc = idx % 2;
  const int pos = idx / 2;
  const int w = pos % 32, hp = (pos / 32) % 32, b = pos / 1024;
  float acc = bias[oc];
  for (int kh = 0; kh < 3; ++kh) {
    const int hh = hp + kh - 1;
    if ((unsigned)hh >= 32u) continue;
    for (int kw = 0; kw < 3; ++kw) {
      const int ww = w + kw - 1;
      if ((unsigned)ww >= 32u) continue;
      const float* pr = res + (((size_t)b * 32 + hh) * 32 + ww) * 96;
      const float* wr = wgt + (size_t)((kh * 3 + kw) * 96) * 2 + oc;
      #pragma unroll 8
      for (int ic = 0; ic < 96; ++ic)
        acc = fmaf(pr[ic], wr[ic * 2], acc);
    }
  }
  out[(((size_t)b * 2 + oc) * 32 + hp) * 32 + w] = acc;
}

// ---------------------------------------------------------------- host
extern "C" void kernel_launch(void* const* d_in, const int* in_sizes, int n_in,
                              void* d_out, int out_size, void* d_ws, size_t ws_size,
                              hipStream_t stream)
{
  const int fill_grid = (out_size + 255) / 256;

  if (n_in != 27) {
    fill_kernel<<<fill_grid, 256, 0, stream>>>((float*)d_out, 200.0f + (float)n_in, out_size);
    return;
  }
  static const int expected_sizes[27] = {
    131072, 131072, 3456, 96, 96, 96, 2304, 2304, 663552, 6912,
    221184, 2304, 32400, 2304, 2304, 884736, 9216, 884736, 2304,
    331776, 384, 96, 96, 82944, 96, 1728, 2
  };
  for (int i = 0; i < 27; ++i) {
    if (in_sizes[i] != expected_sizes[i]) {
      fill_kernel<<<fill_grid, 256, 0, stream>>>((float*)d_out, 300.0f + (float)i, out_size);
      return;
    }
  }
  if (out_size != 131072) {
    fill_kernel<<<fill_grid, 256, 0, stream>>>((float*)d_out, 400.0f, out_size);
    return;
  }
  const uintptr_t raw = (uintptr_t)d_ws;
  const uintptr_t alignedp = (raw + 255) & ~(uintptr_t)255;
  const size_t ws_avail_bytes = (ws_size > (alignedp - raw)) ? ws_size - (alignedp - raw) : 0;
  const size_t avail = ws_avail_bytes / 4;   // floats
  const size_t WBUF_F = 1534464 + 32400;     // bf16 weights + rpbT(f32), float units
  if (avail < 2 * TC + WBUF_F) {
    fill_kernel<<<fill_grid, 256, 0, stream>>>((float*)d_out,
        100.0f + (float)(ws_size >> 20), out_size);
    return;
  }
  const bool rot = (avail >= 3 * TC + WBUF_F);   // 3-buffer rotation (no copies)

  const float* es      = (const float*)d_in[0];
  const float* jp      = (const float*)d_in[1];
  const float* cf_w    = (const float*)d_in[2];
  const float* cf_b    = (const float*)d_in[3];
  const float* pe_s    = (const float*)d_in[4];
  const float* pe_b    = (const float*)d_in[5];
  const float* n1_s    = (const float*)d_in[6];
  const float* n1_b    = (const float*)d_in[7];
  const float* qkv_w   = (const float*)d_in[8];
  const float* qkv_b   = (const float*)d_in[9];
  const float* proj_w  = (const float*)d_in[10];
  const float* proj_b  = (const float*)d_in[11];
  const float* rpb     = (const float*)d_in[12];
  const float* n2_s    = (const float*)d_in[13];
  const float* n2_b    = (const float*)d_in[14];
  const float* fc1_w   = (const float*)d_in[15];
  const float* fc1_b   = (const float*)d_in[16];
  const float* fc2_w   = (const float*)d_in[17];
  const float* fc2_b   = (const float*)d_in[18];
  const float* rstb_w  = (const float*)d_in[19];
  const float* rstb_b  = (const float*)d_in[20];
  const float* nf_s    = (const float*)d_in[21];
  const float* nf_b    = (const float*)d_in[22];
  const float* body_w  = (const float*)d_in[23];
  const float* body_b  = (const float*)d_in[24];
  const float* last_w  = (const float*)d_in[25];
  const float* last_b  = (const float*)d_in[26];

  float* base = (float*)alignedp;
  float* x  = base;
  float* r  = base + TC;
  float* sp = rot ? base + 2 * TC : nullptr;
  unsigned short* wq  = (unsigned short*)(base + (rot ? 3 : 2) * TC);
  unsigned short* wpj = wq + 663552;
  unsigned short* w1  = wpj + 221184;
  unsigned short* w2  = w1 + 884736;
  unsigned short* wcr = w2 + 884736;
  unsigned short* wcb = wcr + 331776;
  float* rpbt = (float*)(wcb + 82944);          // [24][6][225] f32

  const int grid_tc = (int)(TC / 256);
  const int grid_lf = T_TOK / 4;
  const int nwin = T_TOK / 64;                       // 1024

  // weight convert+transpose
  wconv_kernel<<<dim3((96 * 288 + 255) / 256, 24), 256, 0, stream>>>(qkv_w, wq, 96, 288);
  wconv_kernel<<<dim3((96 * 96 + 255) / 256, 24), 256, 0, stream>>>(proj_w, wpj, 96, 96);
  wconv_kernel<<<dim3((96 * 384 + 255) / 256, 24), 256, 0, stream>>>(fc1_w, w1, 96, 384);
  wconv_kernel<<<dim3((384 * 96 + 255) / 256, 24), 256, 0, stream>>>(fc2_w, w2, 384, 96);
  wconv_conv_kernel<<<(331776 + 255) / 256, 256, 0, stream>>>(rstb_w, wcr, 331776);
  wconv_conv_kernel<<<(82944 + 255) / 256, 256, 0, stream>>>(body_w, wcb, 82944);
  rpbt_kernel<<<(24 * 1350 + 255) / 256, 256, 0, stream>>>(rpb, rpbt);

  // stem
  conv_first_kernel<<<grid_tc, 256, 0, stream>>>(es, jp, cf_w, cf_b, x);
  ln_fp32_kernel<<<grid_lf, 256, 0, stream>>>(x, pe_s, pe_b, x, rot ? r : nullptr);

  float* xb = x;
  float* rb = r;
  float* sb = sp;
  for (int l = 0; l < NL; ++l) {
    if (!rot) copy_kernel<<<grid_tc, 256, 0, stream>>>(rb, xb);
    for (int d = 0; d < ND; ++d) {
      const int ld = l * ND + d;
      const int shift = (d & 1) ? 4 : 0;
      swin_block_fused<<<nwin, 512, 0, stream>>>(
          xb, n1_s + ld * CC, n1_b + ld * CC,
          wq + (size_t)ld * 288 * 96, qkv_b + (size_t)ld * 288,
          rpbt + (size_t)ld * 1350,
          wpj + (size_t)ld * 96 * 96, proj_b + (size_t)ld * 96,
          n2_s + ld * CC, n2_b + ld * CC,
          w1 + (size_t)ld * 384 * 96, fc1_b + (size_t)ld * 384,
          w2 + (size_t)ld * 96 * 384, fc2_b + (size_t)ld * 96, shift);
    }
    if (rot) {
      conv96m_kernel<<<1024, 256, 0, stream>>>(xb, wcr + (size_t)l * 9 * 9216,
                                               rstb_b + (size_t)l * CC, rb, rb, sb);
      float* t = xb; xb = sb; sb = t;
    } else {
      conv96m_kernel<<<1024, 256, 0, stream>>>(xb, wcr + (size_t)l * 9 * 9216,
                                               rstb_b + (size_t)l * CC, rb, rb, nullptr);
      float* t = xb; xb = rb; rb = t;
    }
  }
  // tail
  ln_fp32_kernel<<<grid_lf, 256, 0, stream>>>(xb, nf_s, nf_b, rb, nullptr);
  conv_first_kernel<<<grid_tc, 256, 0, stream>>>(es, jp, cf_w, cf_b, xb);
  conv96m_kernel<<<1024, 256, 0, stream>>>(rb, wcb, body_b, xb, xb, nullptr);
  conv_last_kernel<<<(BB * 32 * 32 * 2) / 256, 256, 0, stream>>>(xb, last_w, last_b, (float*)d_out);
}